// Round 2
// baseline (830.732 us; speedup 1.0000x reference)
//
#include <hip/hip_runtime.h>
#include <hip/hip_bf16.h>
#include <cstddef>
#include <math.h>

// ---------------------------------------------------------------------------
// GAT 3-layer forward on MI355X.
// Pipeline per call:
//   CSR build: zero -> histogram(dst) -> scan -> fill -> per-node sort
//   per layer: fp32 tiled GEMM -> attn coefs (e_s,e_d) -> wave-per-node
//              segment softmax + gather-aggregate (+ELU / head-mean)
// ---------------------------------------------------------------------------

static __device__ __forceinline__ float lrelu(float x){ return x > 0.f ? x : 0.2f * x; }
static __device__ __forceinline__ float elu_f(float x){ return x > 0.f ? x : expm1f(x); }

__global__ void zero_int_kernel(int* __restrict__ p, int n){
  int i = blockIdx.x * blockDim.x + threadIdx.x;
  if (i < n) p[i] = 0;
}

__global__ void hist_kernel(const int* __restrict__ dst, int* __restrict__ deg, int E){
  int e = blockIdx.x * blockDim.x + threadIdx.x;
  if (e < E) atomicAdd(&deg[dst[e]], 1);
}

// single-block scan over N degrees -> row_start (exclusive), copy to cursor
__global__ __launch_bounds__(1024) void scan_kernel(const int* __restrict__ deg,
    int* __restrict__ row_start, int* __restrict__ cursor, int N){
  __shared__ int wsum[16];
  __shared__ int s_carry;
  const int tid = threadIdx.x, lane = tid & 63, wid = tid >> 6;
  if (tid == 0) s_carry = 0;
  __syncthreads();
  for (int base = 0; base < N; base += 1024){
    int i = base + tid;
    int v = (i < N) ? deg[i] : 0;
    int incl = v;
    #pragma unroll
    for (int off = 1; off < 64; off <<= 1){
      int t = __shfl_up(incl, off);
      if (lane >= off) incl += t;
    }
    if (lane == 63) wsum[wid] = incl;
    __syncthreads();
    if (tid == 0){
      int run = 0;
      #pragma unroll
      for (int w = 0; w < 16; w++){ int t = wsum[w]; wsum[w] = run; run += t; }
    }
    __syncthreads();
    int excl = s_carry + wsum[wid] + incl - v;
    if (i < N){ row_start[i] = excl; cursor[i] = excl; }
    __syncthreads();
    if (tid == 1023) s_carry = excl + v;   // running total incl. this tile
    __syncthreads();
  }
  if (tid == 0) row_start[N] = s_carry;
}

__global__ void fill_kernel(const int* __restrict__ src, const int* __restrict__ dst,
    int* __restrict__ cursor, int* __restrict__ edge_src, int E){
  int e = blockIdx.x * blockDim.x + threadIdx.x;
  if (e < E){
    int p = atomicAdd(&cursor[dst[e]], 1);
    edge_src[p] = src[e];
  }
}

// deterministic accumulation order: sort each node's src list ascending
__global__ void sort_kernel(const int* __restrict__ row_start, int* __restrict__ edge_src, int N){
  int n = blockIdx.x * blockDim.x + threadIdx.x;
  if (n >= N) return;
  const int s = row_start[n], e = row_start[n + 1];
  for (int i = s + 1; i < e; i++){
    int key = edge_src[i];
    int j = i - 1;
    while (j >= s && edge_src[j] > key){ edge_src[j + 1] = edge_src[j]; j--; }
    edge_src[j + 1] = key;
  }
}

// fp32 tiled GEMM: C[M,Nout] = A[M,K] @ W[K,Nout]. BM=BN=64, BK=16, 256 thr, 4x4/thr.
__global__ __launch_bounds__(256) void gemm_kernel(
    const float* __restrict__ A, const float* __restrict__ W, float* __restrict__ C,
    int M, int K, int Nout)
{
  constexpr int LDT = 72;              // padded LDS stride (16B-aligned rows, conflict-light)
  __shared__ float As[16 * LDT];       // As[k][m]
  __shared__ float Bs[16 * LDT];       // Bs[k][n]
  const int bm = blockIdx.x * 64;
  const int bn = blockIdx.y * 64;
  const int tid = threadIdx.x;
  const int tx = tid & 15;             // output col group
  const int ty = tid >> 4;             // output row group
  const int arow = tid >> 2;           // 0..63
  const int acol = (tid & 3) * 4;      // 0,4,8,12
  const int brow = tid >> 4;           // 0..15
  const int bcol = (tid & 15) * 4;     // 0..60
  float acc[4][4] = {};
  const bool avalid = (bm + arow) < M;
  const float* Aptr = A + (size_t)(bm + arow) * K + acol;
  const float* Wptr = W + (size_t)brow * Nout + bn + bcol;

  for (int kt = 0; kt < K; kt += 16){
    float4 av = make_float4(0.f, 0.f, 0.f, 0.f);
    if (avalid) av = *reinterpret_cast<const float4*>(Aptr + kt);
    float4 bv = *reinterpret_cast<const float4*>(Wptr + (size_t)kt * Nout);
    __syncthreads();
    As[(acol + 0) * LDT + arow] = av.x;
    As[(acol + 1) * LDT + arow] = av.y;
    As[(acol + 2) * LDT + arow] = av.z;
    As[(acol + 3) * LDT + arow] = av.w;
    *reinterpret_cast<float4*>(&Bs[brow * LDT + bcol]) = bv;
    __syncthreads();
    #pragma unroll
    for (int kk = 0; kk < 16; kk++){
      float4 a = *reinterpret_cast<const float4*>(&As[kk * LDT + ty * 4]);
      float4 b = *reinterpret_cast<const float4*>(&Bs[kk * LDT + tx * 4]);
      acc[0][0] = fmaf(a.x, b.x, acc[0][0]);
      acc[0][1] = fmaf(a.x, b.y, acc[0][1]);
      acc[0][2] = fmaf(a.x, b.z, acc[0][2]);
      acc[0][3] = fmaf(a.x, b.w, acc[0][3]);
      acc[1][0] = fmaf(a.y, b.x, acc[1][0]);
      acc[1][1] = fmaf(a.y, b.y, acc[1][1]);
      acc[1][2] = fmaf(a.y, b.z, acc[1][2]);
      acc[1][3] = fmaf(a.y, b.w, acc[1][3]);
      acc[2][0] = fmaf(a.z, b.x, acc[2][0]);
      acc[2][1] = fmaf(a.z, b.y, acc[2][1]);
      acc[2][2] = fmaf(a.z, b.z, acc[2][2]);
      acc[2][3] = fmaf(a.z, b.w, acc[2][3]);
      acc[3][0] = fmaf(a.w, b.x, acc[3][0]);
      acc[3][1] = fmaf(a.w, b.y, acc[3][1]);
      acc[3][2] = fmaf(a.w, b.z, acc[3][2]);
      acc[3][3] = fmaf(a.w, b.w, acc[3][3]);
    }
  }
  #pragma unroll
  for (int i = 0; i < 4; i++){
    int row = bm + ty * 4 + i;
    if (row < M){
      float4 o = make_float4(acc[i][0], acc[i][1], acc[i][2], acc[i][3]);
      *reinterpret_cast<float4*>(&C[(size_t)row * Nout + bn + tx * 4]) = o;
    }
  }
}

// e_s[n,h] = dot(h[n,h,:], a_s[h,:]); one thread per (n,h)
template<int D>
__global__ __launch_bounds__(256) void attn_kernel(
    const float* __restrict__ h, const float* __restrict__ a_s, const float* __restrict__ a_d,
    float* __restrict__ es, float* __restrict__ ed, int N)
{
  int gid = blockIdx.x * blockDim.x + threadIdx.x;
  int n = gid >> 2, hh = gid & 3;
  if (n >= N) return;
  const float* hp = h + (size_t)n * (4 * D) + hh * D;
  const float* sp = a_s + hh * D;
  const float* dp = a_d + hh * D;
  float ss = 0.f, sd = 0.f;
  #pragma unroll 4
  for (int d = 0; d < D; d += 4){
    float4 hv = *reinterpret_cast<const float4*>(hp + d);
    float4 sv = *reinterpret_cast<const float4*>(sp + d);
    float4 dv = *reinterpret_cast<const float4*>(dp + d);
    ss += hv.x * sv.x + hv.y * sv.y + hv.z * sv.z + hv.w * sv.w;
    sd += hv.x * dv.x + hv.y * dv.y + hv.z * dv.z + hv.w * dv.w;
  }
  es[n * 4 + hh] = ss;
  ed[n * 4 + hh] = sd;
}

// One wave per dst node: segment-softmax over incoming edges + gather-aggregate.
// MODE 0: concat output [N,4*D] with ELU (D=32). MODE 1: head-mean [N,D] (D=128).
template<int D, int MODE>
__global__ __launch_bounds__(256) void aggregate_kernel(
    const int* __restrict__ row_start, const int* __restrict__ edge_src,
    const float* __restrict__ hbuf, const float* __restrict__ es, const float* __restrict__ ed,
    float* __restrict__ out, int N)
{
  const int lane = threadIdx.x & 63;
  const int n = blockIdx.x * 4 + (threadIdx.x >> 6);
  if (n >= N) return;
  const int rs = row_start[n];
  const int deg = row_start[n + 1] - rs;
  const float4 ed4 = *reinterpret_cast<const float4*>(&ed[n * 4]);

  // phase 1: per-head max over edges
  float mx0 = -INFINITY, mx1 = -INFINITY, mx2 = -INFINITY, mx3 = -INFINITY;
  for (int i = lane; i < deg; i += 64){
    int s = edge_src[rs + i];
    float4 e4 = *reinterpret_cast<const float4*>(&es[s * 4]);
    mx0 = fmaxf(mx0, lrelu(e4.x + ed4.x));
    mx1 = fmaxf(mx1, lrelu(e4.y + ed4.y));
    mx2 = fmaxf(mx2, lrelu(e4.z + ed4.z));
    mx3 = fmaxf(mx3, lrelu(e4.w + ed4.w));
  }
  #pragma unroll
  for (int off = 1; off < 64; off <<= 1){
    mx0 = fmaxf(mx0, __shfl_xor(mx0, off));
    mx1 = fmaxf(mx1, __shfl_xor(mx1, off));
    mx2 = fmaxf(mx2, __shfl_xor(mx2, off));
    mx3 = fmaxf(mx3, __shfl_xor(mx3, off));
  }
  // phase 2: per-head sum of exp
  float sm0 = 0.f, sm1 = 0.f, sm2 = 0.f, sm3 = 0.f;
  for (int i = lane; i < deg; i += 64){
    int s = edge_src[rs + i];
    float4 e4 = *reinterpret_cast<const float4*>(&es[s * 4]);
    sm0 += __expf(lrelu(e4.x + ed4.x) - mx0);
    sm1 += __expf(lrelu(e4.y + ed4.y) - mx1);
    sm2 += __expf(lrelu(e4.z + ed4.z) - mx2);
    sm3 += __expf(lrelu(e4.w + ed4.w) - mx3);
  }
  #pragma unroll
  for (int off = 1; off < 64; off <<= 1){
    sm0 += __shfl_xor(sm0, off);
    sm1 += __shfl_xor(sm1, off);
    sm2 += __shfl_xor(sm2, off);
    sm3 += __shfl_xor(sm3, off);
  }
  const float inv0 = 1.f / (sm0 + 1e-16f);
  const float inv1 = 1.f / (sm1 + 1e-16f);
  const float inv2 = 1.f / (sm2 + 1e-16f);
  const float inv3 = 1.f / (sm3 + 1e-16f);

  // phase 3: chunk edges by 64; each lane computes alphas for ONE edge,
  // inner loop broadcasts via shfl (kills the 64x redundant expf work).
  if (MODE == 0){
    float acc0 = 0.f, acc1 = 0.f;
    const bool hi = (lane >> 5) & 1;          // output lane    -> head 0/1
                                              // output lane+64 -> head 2/3
    for (int base = 0; base < deg; base += 64){
      const int cnt = min(64, deg - base);
      int   sm = 0;
      float a0 = 0.f, a1 = 0.f, a2 = 0.f, a3 = 0.f;
      if (lane < cnt){
        sm = edge_src[rs + base + lane];
        float4 e4 = *reinterpret_cast<const float4*>(&es[sm * 4]);
        a0 = __expf(lrelu(e4.x + ed4.x) - mx0) * inv0;
        a1 = __expf(lrelu(e4.y + ed4.y) - mx1) * inv1;
        a2 = __expf(lrelu(e4.z + ed4.z) - mx2) * inv2;
        a3 = __expf(lrelu(e4.w + ed4.w) - mx3) * inv3;
      }
      for (int j = 0; j < cnt; j++){
        const int   s  = __shfl(sm, j);
        const float b0 = __shfl(a0, j);
        const float b1 = __shfl(a1, j);
        const float b2 = __shfl(a2, j);
        const float b3 = __shfl(a3, j);
        const float wA = hi ? b1 : b0;
        const float wB = hi ? b3 : b2;
        const float* hr = hbuf + (size_t)s * 128;
        acc0 = fmaf(hr[lane], wA, acc0);
        acc1 = fmaf(hr[lane + 64], wB, acc1);
      }
    }
    out[(size_t)n * 128 + lane]      = elu_f(acc0);
    out[(size_t)n * 128 + lane + 64] = elu_f(acc1);
  } else {
    float acc[8] = {0.f, 0.f, 0.f, 0.f, 0.f, 0.f, 0.f, 0.f};
    for (int base = 0; base < deg; base += 64){
      const int cnt = min(64, deg - base);
      int   sm = 0;
      float a0 = 0.f, a1 = 0.f, a2 = 0.f, a3 = 0.f;
      if (lane < cnt){
        sm = edge_src[rs + base + lane];
        float4 e4 = *reinterpret_cast<const float4*>(&es[sm * 4]);
        a0 = __expf(lrelu(e4.x + ed4.x) - mx0) * inv0;
        a1 = __expf(lrelu(e4.y + ed4.y) - mx1) * inv1;
        a2 = __expf(lrelu(e4.z + ed4.z) - mx2) * inv2;
        a3 = __expf(lrelu(e4.w + ed4.w) - mx3) * inv3;
      }
      for (int j = 0; j < cnt; j++){
        const int   s  = __shfl(sm, j);
        float al[4];
        al[0] = __shfl(a0, j);
        al[1] = __shfl(a1, j);
        al[2] = __shfl(a2, j);
        al[3] = __shfl(a3, j);
        const float* hr = hbuf + (size_t)s * 512;
        #pragma unroll
        for (int jj = 0; jj < 8; jj++){
          acc[jj] = fmaf(hr[lane + jj * 64], al[jj >> 1], acc[jj]);  // o=lane+jj*64, head=jj>>1
        }
      }
    }
    out[(size_t)n * 128 + lane]      = (acc[0] + acc[2] + acc[4] + acc[6]) * 0.25f;
    out[(size_t)n * 128 + lane + 64] = (acc[1] + acc[3] + acc[5] + acc[7]) * 0.25f;
  }
}

extern "C" void kernel_launch(void* const* d_in, const int* in_sizes, int n_in,
                              void* d_out, int out_size, void* d_ws, size_t ws_size,
                              hipStream_t stream) {
  const float* x   = (const float*)d_in[0];
  const int*   src = (const int*)  d_in[1];
  const int*   dst = (const int*)  d_in[2];
  const float* W1  = (const float*)d_in[3];
  const float* a1s = (const float*)d_in[4];
  const float* a1d = (const float*)d_in[5];
  const float* W2  = (const float*)d_in[6];
  const float* a2s = (const float*)d_in[7];
  const float* a2d = (const float*)d_in[8];
  const float* W3  = (const float*)d_in[9];
  const float* a3s = (const float*)d_in[10];
  const float* a3d = (const float*)d_in[11];

  const int N = in_sizes[0] / 96;
  const int E = in_sizes[1];

  // workspace layout (256B aligned)
  char* ws = (char*)d_ws;
  auto alloc = [&](size_t bytes) -> void* {
    void* p = (void*)ws;
    ws += (bytes + 255) & ~(size_t)255;
    return p;
  };
  int*   row_start = (int*)  alloc((size_t)(N + 1) * 4);
  int*   cursor    = (int*)  alloc((size_t)N * 4);
  int*   edge_src  = (int*)  alloc((size_t)E * 4);
  float* es        = (float*)alloc((size_t)N * 4 * 4);
  float* ed        = (float*)alloc((size_t)N * 4 * 4);
  float* hbuf      = (float*)alloc((size_t)N * 512 * 4);
  float* actA      = (float*)alloc((size_t)N * 128 * 4);
  float* actB      = (float*)alloc((size_t)N * 128 * 4);

  // ---- CSR build ----
  zero_int_kernel<<<(N + 255) / 256, 256, 0, stream>>>(cursor, N);
  hist_kernel<<<(E + 255) / 256, 256, 0, stream>>>(dst, cursor, E);
  scan_kernel<<<1, 1024, 0, stream>>>(cursor, row_start, cursor, N);
  fill_kernel<<<(E + 255) / 256, 256, 0, stream>>>(src, dst, cursor, edge_src, E);
  sort_kernel<<<(N + 255) / 256, 256, 0, stream>>>(row_start, edge_src, N);

  const int aggGrid  = (N + 3) / 4;
  const int attnGrid = (N * 4 + 255) / 256;

  // ---- layer 1: [N,96] @ [96,128] ----
  gemm_kernel<<<dim3((N + 63) / 64, 128 / 64), 256, 0, stream>>>(x, W1, hbuf, N, 96, 128);
  attn_kernel<32><<<attnGrid, 256, 0, stream>>>(hbuf, a1s, a1d, es, ed, N);
  aggregate_kernel<32, 0><<<aggGrid, 256, 0, stream>>>(row_start, edge_src, hbuf, es, ed, actA, N);

  // ---- layer 2: [N,128] @ [128,128] ----
  gemm_kernel<<<dim3((N + 63) / 64, 128 / 64), 256, 0, stream>>>(actA, W2, hbuf, N, 128, 128);
  attn_kernel<32><<<attnGrid, 256, 0, stream>>>(hbuf, a2s, a2d, es, ed, N);
  aggregate_kernel<32, 0><<<aggGrid, 256, 0, stream>>>(row_start, edge_src, hbuf, es, ed, actB, N);

  // ---- layer 3: [N,128] @ [128,512], head-mean ----
  gemm_kernel<<<dim3((N + 63) / 64, 512 / 64), 256, 0, stream>>>(actB, W3, hbuf, N, 128, 512);
  attn_kernel<128><<<attnGrid, 256, 0, stream>>>(hbuf, a3s, a3d, es, ed, N);
  aggregate_kernel<128, 1><<<aggGrid, 256, 0, stream>>>(row_start, edge_src, hbuf, es, ed, (float*)d_out, N);
}

// Round 3
// 806.780 us; speedup vs baseline: 1.0297x; 1.0297x over previous
//
#include <hip/hip_runtime.h>
#include <hip/hip_bf16.h>
#include <cstddef>
#include <math.h>

// ---------------------------------------------------------------------------
// GAT 3-layer forward on MI355X.
//   CSR build: zero -> histogram(dst) -> scan -> fill -> per-node sort
//   per layer: fp32 128x128 tiled GEMM -> attn coefs -> wave-per-node fused
//              segment softmax + vectorized gather-aggregate (+ELU/head-mean)
// ---------------------------------------------------------------------------

static __device__ __forceinline__ float lrelu(float x){ return x > 0.f ? x : 0.2f * x; }
static __device__ __forceinline__ float elu_f(float x){ return x > 0.f ? x : expm1f(x); }

__global__ void zero_int_kernel(int* __restrict__ p, int n){
  int i = blockIdx.x * blockDim.x + threadIdx.x;
  if (i < n) p[i] = 0;
}

__global__ void hist_kernel(const int* __restrict__ dst, int* __restrict__ deg, int E){
  int e = blockIdx.x * blockDim.x + threadIdx.x;
  if (e < E) atomicAdd(&deg[dst[e]], 1);
}

// single-block scan over N degrees -> row_start (exclusive), copy to cursor
__global__ __launch_bounds__(1024) void scan_kernel(const int* __restrict__ deg,
    int* __restrict__ row_start, int* __restrict__ cursor, int N){
  __shared__ int wsum[16];
  __shared__ int s_carry;
  const int tid = threadIdx.x, lane = tid & 63, wid = tid >> 6;
  if (tid == 0) s_carry = 0;
  __syncthreads();
  for (int base = 0; base < N; base += 1024){
    int i = base + tid;
    int v = (i < N) ? deg[i] : 0;
    int incl = v;
    #pragma unroll
    for (int off = 1; off < 64; off <<= 1){
      int t = __shfl_up(incl, off);
      if (lane >= off) incl += t;
    }
    if (lane == 63) wsum[wid] = incl;
    __syncthreads();
    if (tid == 0){
      int run = 0;
      #pragma unroll
      for (int w = 0; w < 16; w++){ int t = wsum[w]; wsum[w] = run; run += t; }
    }
    __syncthreads();
    int excl = s_carry + wsum[wid] + incl - v;
    if (i < N){ row_start[i] = excl; cursor[i] = excl; }
    __syncthreads();
    if (tid == 1023) s_carry = excl + v;
    __syncthreads();
  }
  if (tid == 0) row_start[N] = s_carry;
}

__global__ void fill_kernel(const int* __restrict__ src, const int* __restrict__ dst,
    int* __restrict__ cursor, int* __restrict__ edge_src, int E){
  int e = blockIdx.x * blockDim.x + threadIdx.x;
  if (e < E){
    int p = atomicAdd(&cursor[dst[e]], 1);
    edge_src[p] = src[e];
  }
}

// deterministic accumulation order: sort each node's src list ascending
__global__ void sort_kernel(const int* __restrict__ row_start, int* __restrict__ edge_src, int N){
  int n = blockIdx.x * blockDim.x + threadIdx.x;
  if (n >= N) return;
  const int s = row_start[n], e = row_start[n + 1];
  for (int i = s + 1; i < e; i++){
    int key = edge_src[i];
    int j = i - 1;
    while (j >= s && edge_src[j] > key){ edge_src[j + 1] = edge_src[j]; j--; }
    edge_src[j + 1] = key;
  }
}

// fp32 tiled GEMM: C[M,Nout] = A[M,K] @ W[K,Nout]. BM=BN=128, BK=16, 256 thr, 8x8/thr.
// Thread (tx,ty): rows {ty*4+i, 64+ty*4+i}, cols {tx*4+j, 64+tx*4+j} (2-way-free LDS banks).
__global__ __launch_bounds__(256) void gemm_kernel(
    const float* __restrict__ A, const float* __restrict__ W, float* __restrict__ C,
    int M, int K, int Nout)
{
  constexpr int LDT = 132;
  __shared__ float As[16 * LDT];   // As[k][m]
  __shared__ float Bs[16 * LDT];   // Bs[k][n]
  const int bm = blockIdx.x * 128;
  const int bn = blockIdx.y * 128;
  const int tid = threadIdx.x;
  const int tx = tid & 15;
  const int ty = tid >> 4;
  // A staging: thread -> rows (tid>>2) and (tid>>2)+64, k-chunk (tid&3)*4
  const int ar0 = tid >> 2;
  const int ak  = (tid & 3) * 4;
  // B staging: thread -> k rows (tid>>5) and (tid>>5)+8, n-chunk (tid&31)*4
  const int bk  = tid >> 5;
  const int bnc = (tid & 31) * 4;

  float acc[8][8] = {};
  const bool av0 = (bm + ar0) < M;
  const bool av1 = (bm + ar0 + 64) < M;
  const float* A0 = A + (size_t)(bm + ar0) * K + ak;
  const float* A1 = A + (size_t)(bm + ar0 + 64) * K + ak;
  const float* W0 = W + (size_t)bk * Nout + bn + bnc;
  const float* W1p = W + (size_t)(bk + 8) * Nout + bn + bnc;

  for (int kt = 0; kt < K; kt += 16){
    float4 a0v = av0 ? *reinterpret_cast<const float4*>(A0 + kt) : make_float4(0,0,0,0);
    float4 a1v = av1 ? *reinterpret_cast<const float4*>(A1 + kt) : make_float4(0,0,0,0);
    float4 b0v = *reinterpret_cast<const float4*>(W0 + (size_t)kt * Nout);
    float4 b1v = *reinterpret_cast<const float4*>(W1p + (size_t)kt * Nout);
    __syncthreads();
    As[(ak + 0) * LDT + ar0] = a0v.x;
    As[(ak + 1) * LDT + ar0] = a0v.y;
    As[(ak + 2) * LDT + ar0] = a0v.z;
    As[(ak + 3) * LDT + ar0] = a0v.w;
    As[(ak + 0) * LDT + ar0 + 64] = a1v.x;
    As[(ak + 1) * LDT + ar0 + 64] = a1v.y;
    As[(ak + 2) * LDT + ar0 + 64] = a1v.z;
    As[(ak + 3) * LDT + ar0 + 64] = a1v.w;
    *reinterpret_cast<float4*>(&Bs[bk * LDT + bnc]) = b0v;
    *reinterpret_cast<float4*>(&Bs[(bk + 8) * LDT + bnc]) = b1v;
    __syncthreads();
    #pragma unroll
    for (int kk = 0; kk < 16; kk++){
      const float4 aA = *reinterpret_cast<const float4*>(&As[kk * LDT + ty * 4]);
      const float4 aB = *reinterpret_cast<const float4*>(&As[kk * LDT + ty * 4 + 64]);
      const float4 bA = *reinterpret_cast<const float4*>(&Bs[kk * LDT + tx * 4]);
      const float4 bB = *reinterpret_cast<const float4*>(&Bs[kk * LDT + tx * 4 + 64]);
      const float a_[8] = {aA.x, aA.y, aA.z, aA.w, aB.x, aB.y, aB.z, aB.w};
      const float b_[8] = {bA.x, bA.y, bA.z, bA.w, bB.x, bB.y, bB.z, bB.w};
      #pragma unroll
      for (int i = 0; i < 8; i++)
        #pragma unroll
        for (int j = 0; j < 8; j++)
          acc[i][j] = fmaf(a_[i], b_[j], acc[i][j]);
    }
  }
  #pragma unroll
  for (int i = 0; i < 8; i++){
    const int row = bm + ((i < 4) ? (ty * 4 + i) : (64 + ty * 4 + i - 4));
    if (row < M){
      *reinterpret_cast<float4*>(&C[(size_t)row * Nout + bn + tx * 4]) =
          make_float4(acc[i][0], acc[i][1], acc[i][2], acc[i][3]);
      *reinterpret_cast<float4*>(&C[(size_t)row * Nout + bn + tx * 4 + 64]) =
          make_float4(acc[i][4], acc[i][5], acc[i][6], acc[i][7]);
    }
  }
}

// e_s[n,h] = dot(h[n,h,:], a_s[h,:]); one thread per (n,h)
template<int D>
__global__ __launch_bounds__(256) void attn_kernel(
    const float* __restrict__ h, const float* __restrict__ a_s, const float* __restrict__ a_d,
    float* __restrict__ es, float* __restrict__ ed, int N)
{
  int gid = blockIdx.x * blockDim.x + threadIdx.x;
  int n = gid >> 2, hh = gid & 3;
  if (n >= N) return;
  const float* hp = h + (size_t)n * (4 * D) + hh * D;
  const float* sp = a_s + hh * D;
  const float* dp = a_d + hh * D;
  float ss = 0.f, sd = 0.f;
  #pragma unroll 4
  for (int d = 0; d < D; d += 4){
    float4 hv = *reinterpret_cast<const float4*>(hp + d);
    float4 sv = *reinterpret_cast<const float4*>(sp + d);
    float4 dv = *reinterpret_cast<const float4*>(dp + d);
    ss += hv.x * sv.x + hv.y * sv.y + hv.z * sv.z + hv.w * sv.w;
    sd += hv.x * dv.x + hv.y * dv.y + hv.z * dv.z + hv.w * dv.w;
  }
  es[n * 4 + hh] = ss;
  ed[n * 4 + hh] = sd;
}

// Gather over one chunk of <=64 edges. Alphas for edge (chunk_base+l) live on lane l.
// MODE 1: lane accumulates cols {4*lane, 256+4*lane} (float4 each) of the [*,512] table.
// MODE 0: two edges per iteration; lane handles edge j+(lane>>5), cols 4*(lane&31) of [*,128].
template<int MODE>
static __device__ __forceinline__ void gather_chunk(int cnt, int lane,
    int s_reg, float a0, float a1, float a2, float a3,
    const float* __restrict__ hbuf, float4& accA, float4& accB)
{
  if (MODE == 1){
    const int c0 = lane * 4, c1 = 256 + lane * 4;
    const bool hiHalf = lane >= 32;
    for (int j = 0; j < cnt; j++){
      const int   s  = __shfl(s_reg, j);
      const float b0 = __shfl(a0, j), b1 = __shfl(a1, j);
      const float b2 = __shfl(a2, j), b3 = __shfl(a3, j);
      const float alA = hiHalf ? b1 : b0;
      const float alB = hiHalf ? b3 : b2;
      const float* hr = hbuf + (size_t)s * 512;
      const float4 v0 = *reinterpret_cast<const float4*>(hr + c0);
      const float4 v1 = *reinterpret_cast<const float4*>(hr + c1);
      accA.x = fmaf(v0.x, alA, accA.x); accA.y = fmaf(v0.y, alA, accA.y);
      accA.z = fmaf(v0.z, alA, accA.z); accA.w = fmaf(v0.w, alA, accA.w);
      accB.x = fmaf(v1.x, alB, accB.x); accB.y = fmaf(v1.y, alB, accB.y);
      accB.z = fmaf(v1.z, alB, accB.z); accB.w = fmaf(v1.w, alB, accB.w);
    }
  } else {
    const int colg = (lane & 31) * 4;
    const int hsel = colg >> 5;
    for (int j = 0; j < cnt; j += 2){
      const int  el    = j + (lane >> 5);
      const bool valid = el < cnt;
      const int  ei    = valid ? el : 0;
      const int  s     = __shfl(s_reg, ei);
      const float b0 = __shfl(a0, ei), b1 = __shfl(a1, ei);
      const float b2 = __shfl(a2, ei), b3 = __shfl(a3, ei);
      float al = (hsel == 0) ? b0 : (hsel == 1) ? b1 : (hsel == 2) ? b2 : b3;
      if (!valid) al = 0.f;
      const float* hr = hbuf + (size_t)s * 128;
      const float4 v = *reinterpret_cast<const float4*>(hr + colg);
      accA.x = fmaf(v.x, al, accA.x); accA.y = fmaf(v.y, al, accA.y);
      accA.z = fmaf(v.z, al, accA.z); accA.w = fmaf(v.w, al, accA.w);
    }
  }
}

// One wave per dst node: fused segment-softmax (register path for deg<=64) +
// vectorized gather-aggregate. MODE 0: concat [N,128]+ELU. MODE 1: head-mean [N,128].
template<int MODE>
__global__ __launch_bounds__(256) void aggregate_kernel(
    const int* __restrict__ row_start, const int* __restrict__ edge_src,
    const float* __restrict__ hbuf, const float* __restrict__ es, const float* __restrict__ ed,
    float* __restrict__ out, int N)
{
  const int lane = threadIdx.x & 63;
  const int n = blockIdx.x * 4 + (threadIdx.x >> 6);
  if (n >= N) return;
  const int rs  = row_start[n];
  const int deg = row_start[n + 1] - rs;
  const float4 ed4 = *reinterpret_cast<const float4*>(&ed[n * 4]);

  float4 accA = make_float4(0,0,0,0), accB = make_float4(0,0,0,0);

  if (deg <= 64){
    // fast path: one es load + one exp per edge, all in registers
    int   s_reg = 0;
    float e0 = -INFINITY, e1 = -INFINITY, e2 = -INFINITY, e3 = -INFINITY;
    if (lane < deg){
      s_reg = edge_src[rs + lane];
      const float4 e4 = *reinterpret_cast<const float4*>(&es[s_reg * 4]);
      e0 = lrelu(e4.x + ed4.x); e1 = lrelu(e4.y + ed4.y);
      e2 = lrelu(e4.z + ed4.z); e3 = lrelu(e4.w + ed4.w);
    }
    float mx0 = e0, mx1 = e1, mx2 = e2, mx3 = e3;
    #pragma unroll
    for (int off = 1; off < 64; off <<= 1){
      mx0 = fmaxf(mx0, __shfl_xor(mx0, off)); mx1 = fmaxf(mx1, __shfl_xor(mx1, off));
      mx2 = fmaxf(mx2, __shfl_xor(mx2, off)); mx3 = fmaxf(mx3, __shfl_xor(mx3, off));
    }
    float p0 = 0.f, p1 = 0.f, p2 = 0.f, p3 = 0.f;
    if (lane < deg){
      p0 = __expf(e0 - mx0); p1 = __expf(e1 - mx1);
      p2 = __expf(e2 - mx2); p3 = __expf(e3 - mx3);
    }
    float s0 = p0, s1 = p1, s2 = p2, s3 = p3;
    #pragma unroll
    for (int off = 1; off < 64; off <<= 1){
      s0 += __shfl_xor(s0, off); s1 += __shfl_xor(s1, off);
      s2 += __shfl_xor(s2, off); s3 += __shfl_xor(s3, off);
    }
    const float inv0 = 1.f / (s0 + 1e-16f), inv1 = 1.f / (s1 + 1e-16f);
    const float inv2 = 1.f / (s2 + 1e-16f), inv3 = 1.f / (s3 + 1e-16f);
    gather_chunk<MODE>(deg, lane, s_reg, p0 * inv0, p1 * inv1, p2 * inv2, p3 * inv3,
                       hbuf, accA, accB);
  } else {
    // generic path (deg>64): 2-pass softmax stats, then chunked gather
    float mx0 = -INFINITY, mx1 = -INFINITY, mx2 = -INFINITY, mx3 = -INFINITY;
    for (int i = lane; i < deg; i += 64){
      int s = edge_src[rs + i];
      float4 e4 = *reinterpret_cast<const float4*>(&es[s * 4]);
      mx0 = fmaxf(mx0, lrelu(e4.x + ed4.x)); mx1 = fmaxf(mx1, lrelu(e4.y + ed4.y));
      mx2 = fmaxf(mx2, lrelu(e4.z + ed4.z)); mx3 = fmaxf(mx3, lrelu(e4.w + ed4.w));
    }
    #pragma unroll
    for (int off = 1; off < 64; off <<= 1){
      mx0 = fmaxf(mx0, __shfl_xor(mx0, off)); mx1 = fmaxf(mx1, __shfl_xor(mx1, off));
      mx2 = fmaxf(mx2, __shfl_xor(mx2, off)); mx3 = fmaxf(mx3, __shfl_xor(mx3, off));
    }
    float s0 = 0.f, s1 = 0.f, s2 = 0.f, s3 = 0.f;
    for (int i = lane; i < deg; i += 64){
      int s = edge_src[rs + i];
      float4 e4 = *reinterpret_cast<const float4*>(&es[s * 4]);
      s0 += __expf(lrelu(e4.x + ed4.x) - mx0); s1 += __expf(lrelu(e4.y + ed4.y) - mx1);
      s2 += __expf(lrelu(e4.z + ed4.z) - mx2); s3 += __expf(lrelu(e4.w + ed4.w) - mx3);
    }
    #pragma unroll
    for (int off = 1; off < 64; off <<= 1){
      s0 += __shfl_xor(s0, off); s1 += __shfl_xor(s1, off);
      s2 += __shfl_xor(s2, off); s3 += __shfl_xor(s3, off);
    }
    const float inv0 = 1.f / (s0 + 1e-16f), inv1 = 1.f / (s1 + 1e-16f);
    const float inv2 = 1.f / (s2 + 1e-16f), inv3 = 1.f / (s3 + 1e-16f);
    for (int base = 0; base < deg; base += 64){
      const int cnt = min(64, deg - base);
      int s_reg = 0; float a0 = 0.f, a1 = 0.f, a2 = 0.f, a3 = 0.f;
      if (lane < cnt){
        s_reg = edge_src[rs + base + lane];
        const float4 e4 = *reinterpret_cast<const float4*>(&es[s_reg * 4]);
        a0 = __expf(lrelu(e4.x + ed4.x) - mx0) * inv0;
        a1 = __expf(lrelu(e4.y + ed4.y) - mx1) * inv1;
        a2 = __expf(lrelu(e4.z + ed4.z) - mx2) * inv2;
        a3 = __expf(lrelu(e4.w + ed4.w) - mx3) * inv3;
      }
      gather_chunk<MODE>(cnt, lane, s_reg, a0, a1, a2, a3, hbuf, accA, accB);
    }
  }

  if (MODE == 1){
    // lane l (<32): heads{0,2}@d=4l ; lane l+32: heads{1,3}@d=4l  -> xor-32 merge
    float4 t = make_float4(accA.x + accB.x, accA.y + accB.y,
                           accA.z + accB.z, accA.w + accB.w);
    t.x += __shfl_xor(t.x, 32); t.y += __shfl_xor(t.y, 32);
    t.z += __shfl_xor(t.z, 32); t.w += __shfl_xor(t.w, 32);
    if (lane < 32){
      *reinterpret_cast<float4*>(&out[(size_t)n * 128 + lane * 4]) =
          make_float4(t.x * 0.25f, t.y * 0.25f, t.z * 0.25f, t.w * 0.25f);
    }
  } else {
    accA.x += __shfl_xor(accA.x, 32); accA.y += __shfl_xor(accA.y, 32);
    accA.z += __shfl_xor(accA.z, 32); accA.w += __shfl_xor(accA.w, 32);
    if (lane < 32){
      *reinterpret_cast<float4*>(&out[(size_t)n * 128 + lane * 4]) =
          make_float4(elu_f(accA.x), elu_f(accA.y), elu_f(accA.z), elu_f(accA.w));
    }
  }
}

extern "C" void kernel_launch(void* const* d_in, const int* in_sizes, int n_in,
                              void* d_out, int out_size, void* d_ws, size_t ws_size,
                              hipStream_t stream) {
  const float* x   = (const float*)d_in[0];
  const int*   src = (const int*)  d_in[1];
  const int*   dst = (const int*)  d_in[2];
  const float* W1  = (const float*)d_in[3];
  const float* a1s = (const float*)d_in[4];
  const float* a1d = (const float*)d_in[5];
  const float* W2  = (const float*)d_in[6];
  const float* a2s = (const float*)d_in[7];
  const float* a2d = (const float*)d_in[8];
  const float* W3  = (const float*)d_in[9];
  const float* a3s = (const float*)d_in[10];
  const float* a3d = (const float*)d_in[11];

  const int N = in_sizes[0] / 96;
  const int E = in_sizes[1];

  char* ws = (char*)d_ws;
  auto alloc = [&](size_t bytes) -> void* {
    void* p = (void*)ws;
    ws += (bytes + 255) & ~(size_t)255;
    return p;
  };
  int*   row_start = (int*)  alloc((size_t)(N + 1) * 4);
  int*   cursor    = (int*)  alloc((size_t)N * 4);
  int*   edge_src  = (int*)  alloc((size_t)E * 4);
  float* es        = (float*)alloc((size_t)N * 4 * 4);
  float* ed        = (float*)alloc((size_t)N * 4 * 4);
  float* hbuf      = (float*)alloc((size_t)N * 512 * 4);
  float* actA      = (float*)alloc((size_t)N * 128 * 4);
  float* actB      = (float*)alloc((size_t)N * 128 * 4);

  // ---- CSR build ----
  zero_int_kernel<<<(N + 255) / 256, 256, 0, stream>>>(cursor, N);
  hist_kernel<<<(E + 255) / 256, 256, 0, stream>>>(dst, cursor, E);
  scan_kernel<<<1, 1024, 0, stream>>>(cursor, row_start, cursor, N);
  fill_kernel<<<(E + 255) / 256, 256, 0, stream>>>(src, dst, cursor, edge_src, E);
  sort_kernel<<<(N + 255) / 256, 256, 0, stream>>>(row_start, edge_src, N);

  const int aggGrid  = (N + 3) / 4;
  const int attnGrid = (N * 4 + 255) / 256;

  // ---- layer 1: [N,96] @ [96,128] ----
  gemm_kernel<<<dim3((N + 127) / 128, 1), 256, 0, stream>>>(x, W1, hbuf, N, 96, 128);
  attn_kernel<32><<<attnGrid, 256, 0, stream>>>(hbuf, a1s, a1d, es, ed, N);
  aggregate_kernel<0><<<aggGrid, 256, 0, stream>>>(row_start, edge_src, hbuf, es, ed, actA, N);

  // ---- layer 2: [N,128] @ [128,128] ----
  gemm_kernel<<<dim3((N + 127) / 128, 1), 256, 0, stream>>>(actA, W2, hbuf, N, 128, 128);
  attn_kernel<32><<<attnGrid, 256, 0, stream>>>(hbuf, a2s, a2d, es, ed, N);
  aggregate_kernel<0><<<aggGrid, 256, 0, stream>>>(row_start, edge_src, hbuf, es, ed, actB, N);

  // ---- layer 3: [N,128] @ [128,512], head-mean ----
  gemm_kernel<<<dim3((N + 127) / 128, 4), 256, 0, stream>>>(actB, W3, hbuf, N, 128, 512);
  attn_kernel<128><<<attnGrid, 256, 0, stream>>>(hbuf, a3s, a3d, es, ed, N);
  aggregate_kernel<1><<<aggGrid, 256, 0, stream>>>(row_start, edge_src, hbuf, es, ed, (float*)d_out, N);
}

// Round 4
// 736.745 us; speedup vs baseline: 1.1276x; 1.0951x over previous
//
#include <hip/hip_runtime.h>
#include <hip/hip_bf16.h>
#include <hip/hip_fp16.h>
#include <cstddef>
#include <stdint.h>
#include <math.h>

// ---------------------------------------------------------------------------
// GAT 3-layer forward on MI355X.
//   CSR build: zero -> histogram(dst) -> scan -> fill -> per-node sort
//   per layer: split-bf16 (hi/lo, 3x MFMA) GEMM -> attn coefs -> wave-per-node
//              fused segment softmax + gather-aggregate.
//   Layer 3 feature table stored fp16 (halves the dominant gather traffic).
// ---------------------------------------------------------------------------

static __device__ __forceinline__ float lrelu(float x){ return x > 0.f ? x : 0.2f * x; }
static __device__ __forceinline__ float elu_f(float x){ return x > 0.f ? x : expm1f(x); }

typedef __bf16 bf16x8 __attribute__((ext_vector_type(8)));
typedef float  f32x4  __attribute__((ext_vector_type(4)));

// ============================ CSR build ====================================
__global__ void zero_int_kernel(int* __restrict__ p, int n){
  int i = blockIdx.x * blockDim.x + threadIdx.x;
  if (i < n) p[i] = 0;
}

__global__ void hist_kernel(const int* __restrict__ dst, int* __restrict__ deg, int E){
  int e = blockIdx.x * blockDim.x + threadIdx.x;
  if (e < E) atomicAdd(&deg[dst[e]], 1);
}

__global__ __launch_bounds__(1024) void scan_kernel(const int* __restrict__ deg,
    int* __restrict__ row_start, int* __restrict__ cursor, int N){
  __shared__ int wsum[16];
  __shared__ int s_carry;
  const int tid = threadIdx.x, lane = tid & 63, wid = tid >> 6;
  if (tid == 0) s_carry = 0;
  __syncthreads();
  for (int base = 0; base < N; base += 1024){
    int i = base + tid;
    int v = (i < N) ? deg[i] : 0;
    int incl = v;
    #pragma unroll
    for (int off = 1; off < 64; off <<= 1){
      int t = __shfl_up(incl, off);
      if (lane >= off) incl += t;
    }
    if (lane == 63) wsum[wid] = incl;
    __syncthreads();
    if (tid == 0){
      int run = 0;
      #pragma unroll
      for (int w = 0; w < 16; w++){ int t = wsum[w]; wsum[w] = run; run += t; }
    }
    __syncthreads();
    int excl = s_carry + wsum[wid] + incl - v;
    if (i < N){ row_start[i] = excl; cursor[i] = excl; }
    __syncthreads();
    if (tid == 1023) s_carry = excl + v;
    __syncthreads();
  }
  if (tid == 0) row_start[N] = s_carry;
}

__global__ void fill_kernel(const int* __restrict__ src, const int* __restrict__ dst,
    int* __restrict__ cursor, int* __restrict__ edge_src, int E){
  int e = blockIdx.x * blockDim.x + threadIdx.x;
  if (e < E){
    int p = atomicAdd(&cursor[dst[e]], 1);
    edge_src[p] = src[e];
  }
}

__global__ void sort_kernel(const int* __restrict__ row_start, int* __restrict__ edge_src, int N){
  int n = blockIdx.x * blockDim.x + threadIdx.x;
  if (n >= N) return;
  const int s = row_start[n], e = row_start[n + 1];
  for (int i = s + 1; i < e; i++){
    int key = edge_src[i];
    int j = i - 1;
    while (j >= s && edge_src[j] > key){ edge_src[j + 1] = edge_src[j]; j--; }
    edge_src[j + 1] = key;
  }
}

// ====================== split-bf16 packing =================================
static __device__ __forceinline__ uint32_t pack_hi_lo(float a){
  uint32_t u  = __float_as_uint(a);
  uint32_t hb = (u + 0x7FFFu + ((u >> 16) & 1u)) & 0xFFFF0000u;  // bf16 RNE of a
  float lof   = a - __uint_as_float(hb);
  uint32_t ul = __float_as_uint(lof);
  uint32_t lb = (ul + 0x7FFFu + ((ul >> 16) & 1u)) >> 16;        // bf16 RNE of residual
  return (hb >> 16) | (lb << 16);
}

// A [M,K] fp32 -> P [Mp,K] u32 packed (pad rows zeroed). grid = Mp, block = K.
__global__ void split_pack_kernel(const float* __restrict__ A, uint32_t* __restrict__ P,
                                  int M, int K){
  const int r = blockIdx.x;
  const int c = threadIdx.x;
  float a = (r < M) ? A[(size_t)r * K + c] : 0.f;
  P[(size_t)r * K + c] = pack_hi_lo(a);
}

// W [K,N] fp32 -> P [N,K] u32 packed (transposed). grid = N, block = K.
__global__ void split_pack_w_kernel(const float* __restrict__ W, uint32_t* __restrict__ P,
                                    int K, int N){
  const int n = blockIdx.x;
  const int k = threadIdx.x;
  P[(size_t)n * K + k] = pack_hi_lo(W[(size_t)k * N + n]);
}

// ====================== MFMA GEMM (split-bf16, 3 mfma) =====================
union PKU { uint32_t u[4]; bf16x8 v; };

static __device__ __forceinline__ void unpack_frag(const uint4 q0, const uint4 q1,
                                                   bf16x8& hi, bf16x8& lo){
  PKU H, L;
  H.u[0] = (q0.x & 0xFFFFu) | (q0.y << 16);
  H.u[1] = (q0.z & 0xFFFFu) | (q0.w << 16);
  H.u[2] = (q1.x & 0xFFFFu) | (q1.y << 16);
  H.u[3] = (q1.z & 0xFFFFu) | (q1.w << 16);
  L.u[0] = (q0.x >> 16) | (q0.y & 0xFFFF0000u);
  L.u[1] = (q0.z >> 16) | (q0.w & 0xFFFF0000u);
  L.u[2] = (q1.x >> 16) | (q1.y & 0xFFFF0000u);
  L.u[3] = (q1.z >> 16) | (q1.w & 0xFFFF0000u);
  hi = H.v; lo = L.v;
}

static __device__ __forceinline__ void storeOut(float v, float* p){ *p = v; }
static __device__ __forceinline__ void storeOut(float v, __half* p){ *p = __float2half(v); }

// C[M,Nout] = A@W. Apk [Mp,K] packed, Wpk [Nout,K] packed (pre-transposed).
// 128x128 tile, 4 waves 2x2, each wave 64x64 via 4x4 frags of 16x16x32.
template<typename OutT>
__global__ __launch_bounds__(256) void gemm_mfma_kernel(
    const uint32_t* __restrict__ Apk, const uint32_t* __restrict__ Wpk,
    OutT* __restrict__ C, int M, int K, int Nout)
{
  __shared__ uint32_t Asl[4096];   // [128 rows][32 k] u32, XOR-swizzled
  __shared__ uint32_t Bsl[4096];
  const int tid  = threadIdx.x;
  const int lane = tid & 63;
  const int wid  = tid >> 6;
  const int wm   = (wid >> 1) * 64;
  const int wn   = (wid & 1) * 64;
  const int bm   = blockIdx.x * 128;
  const int bn   = blockIdx.y * 128;
  const int srow = tid >> 3;          // staging row 0..31
  const int skof = (tid & 7) * 4;     // staging k-offset (u32)
  const int fr   = lane & 15;         // frag row/col index
  const int kg   = (lane >> 4) * 8;   // frag k-group base

  f32x4 acc[4][4] = {};

  for (int kt = 0; kt < K; kt += 32){
    uint4 av[4], bv[4];
    #pragma unroll
    for (int it = 0; it < 4; it++){
      const int r = srow + it * 32;
      av[it] = *reinterpret_cast<const uint4*>(Apk + (size_t)(bm + r) * K + kt + skof);
      bv[it] = *reinterpret_cast<const uint4*>(Wpk + (size_t)(bn + r) * K + kt + skof);
    }
    __syncthreads();
    #pragma unroll
    for (int it = 0; it < 4; it++){
      const int r  = srow + it * 32;
      const int sw = (r * 32 + skof) ^ ((r & 7) << 2);
      *reinterpret_cast<uint4*>(&Asl[sw]) = av[it];
      *reinterpret_cast<uint4*>(&Bsl[sw]) = bv[it];
    }
    __syncthreads();

    bf16x8 Ah[4], Al[4];
    #pragma unroll
    for (int mf = 0; mf < 4; mf++){
      const int r  = wm + mf * 16 + fr;
      const int b  = r * 32 + kg;
      const int sx = (r & 7) << 2;
      const uint4 q0 = *reinterpret_cast<const uint4*>(&Asl[b ^ sx]);
      const uint4 q1 = *reinterpret_cast<const uint4*>(&Asl[(b + 4) ^ sx]);
      unpack_frag(q0, q1, Ah[mf], Al[mf]);
    }
    #pragma unroll
    for (int nf = 0; nf < 4; nf++){
      const int r  = wn + nf * 16 + fr;
      const int b  = r * 32 + kg;
      const int sx = (r & 7) << 2;
      const uint4 q0 = *reinterpret_cast<const uint4*>(&Bsl[b ^ sx]);
      const uint4 q1 = *reinterpret_cast<const uint4*>(&Bsl[(b + 4) ^ sx]);
      bf16x8 Bh, Bl;
      unpack_frag(q0, q1, Bh, Bl);
      #pragma unroll
      for (int mf = 0; mf < 4; mf++){
        acc[mf][nf] = __builtin_amdgcn_mfma_f32_16x16x32_bf16(Al[mf], Bh, acc[mf][nf], 0, 0, 0);
        acc[mf][nf] = __builtin_amdgcn_mfma_f32_16x16x32_bf16(Ah[mf], Bl, acc[mf][nf], 0, 0, 0);
        acc[mf][nf] = __builtin_amdgcn_mfma_f32_16x16x32_bf16(Ah[mf], Bh, acc[mf][nf], 0, 0, 0);
      }
    }
  }

  // epilogue: D row = (lane>>4)*4 + reg (1st operand = A), col = lane&15 (2nd = W)
  #pragma unroll
  for (int mf = 0; mf < 4; mf++){
    #pragma unroll
    for (int nf = 0; nf < 4; nf++){
      const int col = bn + wn + nf * 16 + fr;
      #pragma unroll
      for (int j = 0; j < 4; j++){
        const int row = bm + wm + mf * 16 + (lane >> 4) * 4 + j;
        if (row < M) storeOut(acc[mf][nf][j], &C[(size_t)row * Nout + col]);
      }
    }
  }
}

// =========================== attention coefs ===============================
template<int D>
__global__ __launch_bounds__(256) void attn_kernel(
    const float* __restrict__ h, const float* __restrict__ a_s, const float* __restrict__ a_d,
    float* __restrict__ es, float* __restrict__ ed, int N)
{
  int gid = blockIdx.x * blockDim.x + threadIdx.x;
  int n = gid >> 2, hh = gid & 3;
  if (n >= N) return;
  const float* hp = h + (size_t)n * (4 * D) + hh * D;
  const float* sp = a_s + hh * D;
  const float* dp = a_d + hh * D;
  float ss = 0.f, sd = 0.f;
  #pragma unroll 4
  for (int d = 0; d < D; d += 4){
    float4 hv = *reinterpret_cast<const float4*>(hp + d);
    float4 sv = *reinterpret_cast<const float4*>(sp + d);
    float4 dv = *reinterpret_cast<const float4*>(dp + d);
    ss += hv.x * sv.x + hv.y * sv.y + hv.z * sv.z + hv.w * sv.w;
    sd += hv.x * dv.x + hv.y * dv.y + hv.z * dv.z + hv.w * dv.w;
  }
  es[n * 4 + hh] = ss;
  ed[n * 4 + hh] = sd;
}

// fp16-table variant (layer 3, D=128)
__global__ __launch_bounds__(256) void attn_h_kernel(
    const __half* __restrict__ h, const float* __restrict__ a_s, const float* __restrict__ a_d,
    float* __restrict__ es, float* __restrict__ ed, int N)
{
  int gid = blockIdx.x * blockDim.x + threadIdx.x;
  int n = gid >> 2, hh = gid & 3;
  if (n >= N) return;
  const __half2* hp = reinterpret_cast<const __half2*>(h + (size_t)n * 512 + hh * 128);
  const float* sp = a_s + hh * 128;
  const float* dp = a_d + hh * 128;
  float ss = 0.f, sd = 0.f;
  #pragma unroll 8
  for (int d2 = 0; d2 < 64; d2++){
    float2 f = __half22float2(hp[d2]);
    ss += f.x * sp[2 * d2] + f.y * sp[2 * d2 + 1];
    sd += f.x * dp[2 * d2] + f.y * dp[2 * d2 + 1];
  }
  es[n * 4 + hh] = ss;
  ed[n * 4 + hh] = sd;
}

// ==================== aggregate: layers 1/2 (fp32, concat+ELU) =============
// Gather one chunk (<=64 edges): 2 edges/iter, 32 lanes each, float4 of [*,128].
static __device__ __forceinline__ void gather_chunk_f(int cnt, int lane,
    int s_reg, float a0, float a1, float a2, float a3,
    const float* __restrict__ hbuf, float4& accA)
{
  const int colg = (lane & 31) * 4;
  const int hsel = colg >> 5;
  for (int j = 0; j < cnt; j += 2){
    const int  el    = j + (lane >> 5);
    const bool valid = el < cnt;
    const int  ei    = valid ? el : 0;
    const int  s     = __shfl(s_reg, ei);
    const float b0 = __shfl(a0, ei), b1 = __shfl(a1, ei);
    const float b2 = __shfl(a2, ei), b3 = __shfl(a3, ei);
    float al = (hsel == 0) ? b0 : (hsel == 1) ? b1 : (hsel == 2) ? b2 : b3;
    if (!valid) al = 0.f;
    const float4 v = *reinterpret_cast<const float4*>(hbuf + (size_t)s * 128 + colg);
    accA.x = fmaf(v.x, al, accA.x); accA.y = fmaf(v.y, al, accA.y);
    accA.z = fmaf(v.z, al, accA.z); accA.w = fmaf(v.w, al, accA.w);
  }
}

__global__ __launch_bounds__(256) void aggregate12_kernel(
    const int* __restrict__ row_start, const int* __restrict__ edge_src,
    const float* __restrict__ hbuf, const float* __restrict__ es, const float* __restrict__ ed,
    float* __restrict__ out, int N)
{
  const int lane = threadIdx.x & 63;
  const int n = blockIdx.x * 4 + (threadIdx.x >> 6);
  if (n >= N) return;
  const int rs  = row_start[n];
  const int deg = row_start[n + 1] - rs;
  const float4 ed4 = *reinterpret_cast<const float4*>(&ed[n * 4]);
  float4 accA = make_float4(0, 0, 0, 0);

  if (deg <= 64){
    int   s_reg = 0;
    float e0 = -INFINITY, e1 = -INFINITY, e2 = -INFINITY, e3 = -INFINITY;
    if (lane < deg){
      s_reg = edge_src[rs + lane];
      const float4 e4 = *reinterpret_cast<const float4*>(&es[s_reg * 4]);
      e0 = lrelu(e4.x + ed4.x); e1 = lrelu(e4.y + ed4.y);
      e2 = lrelu(e4.z + ed4.z); e3 = lrelu(e4.w + ed4.w);
    }
    float mx0 = e0, mx1 = e1, mx2 = e2, mx3 = e3;
    #pragma unroll
    for (int off = 1; off < 64; off <<= 1){
      mx0 = fmaxf(mx0, __shfl_xor(mx0, off)); mx1 = fmaxf(mx1, __shfl_xor(mx1, off));
      mx2 = fmaxf(mx2, __shfl_xor(mx2, off)); mx3 = fmaxf(mx3, __shfl_xor(mx3, off));
    }
    float p0 = 0.f, p1 = 0.f, p2 = 0.f, p3 = 0.f;
    if (lane < deg){
      p0 = __expf(e0 - mx0); p1 = __expf(e1 - mx1);
      p2 = __expf(e2 - mx2); p3 = __expf(e3 - mx3);
    }
    float s0 = p0, s1 = p1, s2 = p2, s3 = p3;
    #pragma unroll
    for (int off = 1; off < 64; off <<= 1){
      s0 += __shfl_xor(s0, off); s1 += __shfl_xor(s1, off);
      s2 += __shfl_xor(s2, off); s3 += __shfl_xor(s3, off);
    }
    gather_chunk_f(deg, lane, s_reg,
                   p0 / (s0 + 1e-16f), p1 / (s1 + 1e-16f),
                   p2 / (s2 + 1e-16f), p3 / (s3 + 1e-16f), hbuf, accA);
  } else {
    float mx0 = -INFINITY, mx1 = -INFINITY, mx2 = -INFINITY, mx3 = -INFINITY;
    for (int i = lane; i < deg; i += 64){
      int s = edge_src[rs + i];
      float4 e4 = *reinterpret_cast<const float4*>(&es[s * 4]);
      mx0 = fmaxf(mx0, lrelu(e4.x + ed4.x)); mx1 = fmaxf(mx1, lrelu(e4.y + ed4.y));
      mx2 = fmaxf(mx2, lrelu(e4.z + ed4.z)); mx3 = fmaxf(mx3, lrelu(e4.w + ed4.w));
    }
    #pragma unroll
    for (int off = 1; off < 64; off <<= 1){
      mx0 = fmaxf(mx0, __shfl_xor(mx0, off)); mx1 = fmaxf(mx1, __shfl_xor(mx1, off));
      mx2 = fmaxf(mx2, __shfl_xor(mx2, off)); mx3 = fmaxf(mx3, __shfl_xor(mx3, off));
    }
    float s0 = 0.f, s1 = 0.f, s2 = 0.f, s3 = 0.f;
    for (int i = lane; i < deg; i += 64){
      int s = edge_src[rs + i];
      float4 e4 = *reinterpret_cast<const float4*>(&es[s * 4]);
      s0 += __expf(lrelu(e4.x + ed4.x) - mx0); s1 += __expf(lrelu(e4.y + ed4.y) - mx1);
      s2 += __expf(lrelu(e4.z + ed4.z) - mx2); s3 += __expf(lrelu(e4.w + ed4.w) - mx3);
    }
    #pragma unroll
    for (int off = 1; off < 64; off <<= 1){
      s0 += __shfl_xor(s0, off); s1 += __shfl_xor(s1, off);
      s2 += __shfl_xor(s2, off); s3 += __shfl_xor(s3, off);
    }
    const float inv0 = 1.f / (s0 + 1e-16f), inv1 = 1.f / (s1 + 1e-16f);
    const float inv2 = 1.f / (s2 + 1e-16f), inv3 = 1.f / (s3 + 1e-16f);
    for (int base = 0; base < deg; base += 64){
      const int cnt = min(64, deg - base);
      int s_reg = 0; float a0 = 0.f, a1 = 0.f, a2 = 0.f, a3 = 0.f;
      if (lane < cnt){
        s_reg = edge_src[rs + base + lane];
        const float4 e4 = *reinterpret_cast<const float4*>(&es[s_reg * 4]);
        a0 = __expf(lrelu(e4.x + ed4.x) - mx0) * inv0;
        a1 = __expf(lrelu(e4.y + ed4.y) - mx1) * inv1;
        a2 = __expf(lrelu(e4.z + ed4.z) - mx2) * inv2;
        a3 = __expf(lrelu(e4.w + ed4.w) - mx3) * inv3;
      }
      gather_chunk_f(cnt, lane, s_reg, a0, a1, a2, a3, hbuf, accA);
    }
  }

  accA.x += __shfl_xor(accA.x, 32); accA.y += __shfl_xor(accA.y, 32);
  accA.z += __shfl_xor(accA.z, 32); accA.w += __shfl_xor(accA.w, 32);
  if (lane < 32){
    *reinterpret_cast<float4*>(&out[(size_t)n * 128 + lane * 4]) =
        make_float4(elu_f(accA.x), elu_f(accA.y), elu_f(accA.z), elu_f(accA.w));
  }
}

// ==================== aggregate: layer 3 (fp16 table, head-mean) ===========
// Lane covers cols 8*lane..8*lane+7 of the [*,512] fp16 table; head = lane>>4.
__global__ __launch_bounds__(256) void aggregate3_kernel(
    const int* __restrict__ row_start, const int* __restrict__ edge_src,
    const __half* __restrict__ hbuf, const float* __restrict__ es, const float* __restrict__ ed,
    float* __restrict__ out, int N)
{
  const int lane = threadIdx.x & 63;
  const int n = blockIdx.x * 4 + (threadIdx.x >> 6);
  if (n >= N) return;
  const int rs  = row_start[n];
  const int deg = row_start[n + 1] - rs;
  const float4 ed4 = *reinterpret_cast<const float4*>(&ed[n * 4]);
  const int head = lane >> 4;
  float acc[8] = {0.f, 0.f, 0.f, 0.f, 0.f, 0.f, 0.f, 0.f};

  auto gather = [&](int cnt, int s_reg, float a0, float a1, float a2, float a3){
    for (int j = 0; j < cnt; j++){
      const int s = __shfl(s_reg, j);
      const float b0 = __shfl(a0, j), b1 = __shfl(a1, j);
      const float b2 = __shfl(a2, j), b3 = __shfl(a3, j);
      const float al = head == 0 ? b0 : head == 1 ? b1 : head == 2 ? b2 : b3;
      const uint4 raw = *reinterpret_cast<const uint4*>(hbuf + (size_t)s * 512 + lane * 8);
      const __half2* hp = reinterpret_cast<const __half2*>(&raw);
      #pragma unroll
      for (int q = 0; q < 4; q++){
        float2 f = __half22float2(hp[q]);
        acc[q * 2]     = fmaf(f.x, al, acc[q * 2]);
        acc[q * 2 + 1] = fmaf(f.y, al, acc[q * 2 + 1]);
      }
    }
  };

  if (deg <= 64){
    int   s_reg = 0;
    float e0 = -INFINITY, e1 = -INFINITY, e2 = -INFINITY, e3 = -INFINITY;
    if (lane < deg){
      s_reg = edge_src[rs + lane];
      const float4 e4 = *reinterpret_cast<const float4*>(&es[s_reg * 4]);
      e0 = lrelu(e4.x + ed4.x); e1 = lrelu(e4.y + ed4.y);
      e2 = lrelu(e4.z + ed4.z); e3 = lrelu(e4.w + ed4.w);
    }
    float mx0 = e0, mx1 = e1, mx2 = e2, mx3 = e3;
    #pragma unroll
    for (int off = 1; off < 64; off <<= 1){
      mx0 = fmaxf(mx0, __shfl_xor(mx0, off)); mx1 = fmaxf(mx1, __shfl_xor(mx1, off));
      mx2 = fmaxf(mx2, __shfl_xor(mx2, off)); mx3 = fmaxf(mx3, __shfl_xor(mx3, off));
    }
    float p0 = 0.f, p1 = 0.f, p2 = 0.f, p3 = 0.f;
    if (lane < deg){
      p0 = __expf(e0 - mx0); p1 = __expf(e1 - mx1);
      p2 = __expf(e2 - mx2); p3 = __expf(e3 - mx3);
    }
    float s0 = p0, s1 = p1, s2 = p2, s3 = p3;
    #pragma unroll
    for (int off = 1; off < 64; off <<= 1){
      s0 += __shfl_xor(s0, off); s1 += __shfl_xor(s1, off);
      s2 += __shfl_xor(s2, off); s3 += __shfl_xor(s3, off);
    }
    gather(deg, s_reg,
           p0 / (s0 + 1e-16f), p1 / (s1 + 1e-16f),
           p2 / (s2 + 1e-16f), p3 / (s3 + 1e-16f));
  } else {
    float mx0 = -INFINITY, mx1 = -INFINITY, mx2 = -INFINITY, mx3 = -INFINITY;
    for (int i = lane; i < deg; i += 64){
      int s = edge_src[rs + i];
      float4 e4 = *reinterpret_cast<const float4*>(&es[s * 4]);
      mx0 = fmaxf(mx0, lrelu(e4.x + ed4.x)); mx1 = fmaxf(mx1, lrelu(e4.y + ed4.y));
      mx2 = fmaxf(mx2, lrelu(e4.z + ed4.z)); mx3 = fmaxf(mx3, lrelu(e4.w + ed4.w));
    }
    #pragma unroll
    for (int off = 1; off < 64; off <<= 1){
      mx0 = fmaxf(mx0, __shfl_xor(mx0, off)); mx1 = fmaxf(mx1, __shfl_xor(mx1, off));
      mx2 = fmaxf(mx2, __shfl_xor(mx2, off)); mx3 = fmaxf(mx3, __shfl_xor(mx3, off));
    }
    float s0 = 0.f, s1 = 0.f, s2 = 0.f, s3 = 0.f;
    for (int i = lane; i < deg; i += 64){
      int s = edge_src[rs + i];
      float4 e4 = *reinterpret_cast<const float4*>(&es[s * 4]);
      s0 += __expf(lrelu(e4.x + ed4.x) - mx0); s1 += __expf(lrelu(e4.y + ed4.y) - mx1);
      s2 += __expf(lrelu(e4.z + ed4.z) - mx2); s3 += __expf(lrelu(e4.w + ed4.w) - mx3);
    }
    #pragma unroll
    for (int off = 1; off < 64; off <<= 1){
      s0 += __shfl_xor(s0, off); s1 += __shfl_xor(s1, off);
      s2 += __shfl_xor(s2, off); s3 += __shfl_xor(s3, off);
    }
    const float inv0 = 1.f / (s0 + 1e-16f), inv1 = 1.f / (s1 + 1e-16f);
    const float inv2 = 1.f / (s2 + 1e-16f), inv3 = 1.f / (s3 + 1e-16f);
    for (int base = 0; base < deg; base += 64){
      const int cnt = min(64, deg - base);
      int s_reg = 0; float a0 = 0.f, a1 = 0.f, a2 = 0.f, a3 = 0.f;
      if (lane < cnt){
        s_reg = edge_src[rs + base + lane];
        const float4 e4 = *reinterpret_cast<const float4*>(&es[s_reg * 4]);
        a0 = __expf(lrelu(e4.x + ed4.x) - mx0) * inv0;
        a1 = __expf(lrelu(e4.y + ed4.y) - mx1) * inv1;
        a2 = __expf(lrelu(e4.z + ed4.z) - mx2) * inv2;
        a3 = __expf(lrelu(e4.w + ed4.w) - mx3) * inv3;
      }
      gather(cnt, s_reg, a0, a1, a2, a3);
    }
  }

  // sum the 4 heads (lanes l, l^16, l^32 butterfly), lanes 0-15 write 8 cols each
  #pragma unroll
  for (int q = 0; q < 8; q++){
    acc[q] += __shfl_xor(acc[q], 16);
    acc[q] += __shfl_xor(acc[q], 32);
  }
  if (lane < 16){
    *reinterpret_cast<float4*>(&out[(size_t)n * 128 + lane * 8]) =
        make_float4(acc[0] * 0.25f, acc[1] * 0.25f, acc[2] * 0.25f, acc[3] * 0.25f);
    *reinterpret_cast<float4*>(&out[(size_t)n * 128 + lane * 8 + 4]) =
        make_float4(acc[4] * 0.25f, acc[5] * 0.25f, acc[6] * 0.25f, acc[7] * 0.25f);
  }
}

// =============================== driver ====================================
extern "C" void kernel_launch(void* const* d_in, const int* in_sizes, int n_in,
                              void* d_out, int out_size, void* d_ws, size_t ws_size,
                              hipStream_t stream) {
  const float* x   = (const float*)d_in[0];
  const int*   src = (const int*)  d_in[1];
  const int*   dst = (const int*)  d_in[2];
  const float* W1  = (const float*)d_in[3];
  const float* a1s = (const float*)d_in[4];
  const float* a1d = (const float*)d_in[5];
  const float* W2  = (const float*)d_in[6];
  const float* a2s = (const float*)d_in[7];
  const float* a2d = (const float*)d_in[8];
  const float* W3  = (const float*)d_in[9];
  const float* a3s = (const float*)d_in[10];
  const float* a3d = (const float*)d_in[11];

  const int N  = in_sizes[0] / 96;
  const int E  = in_sizes[1];
  const int Mp = (N + 127) & ~127;

  char* ws = (char*)d_ws;
  auto alloc = [&](size_t bytes) -> void* {
    void* p = (void*)ws;
    ws += (bytes + 255) & ~(size_t)255;
    return p;
  };
  int*      row_start = (int*)     alloc((size_t)(N + 1) * 4);
  int*      cursor    = (int*)     alloc((size_t)N * 4);
  int*      edge_src  = (int*)     alloc((size_t)E * 4);
  float*    es        = (float*)   alloc((size_t)N * 4 * 4);
  float*    ed        = (float*)   alloc((size_t)N * 4 * 4);
  void*     hbuf      =            alloc((size_t)N * 512 * 2);  // fp16 L3 / fp32 L1,2
  float*    actA      = (float*)   alloc((size_t)N * 128 * 4);
  float*    actB      = (float*)   alloc((size_t)N * 128 * 4);
  uint32_t* Apk       = (uint32_t*)alloc((size_t)Mp * 128 * 4);
  uint32_t* Wpk       = (uint32_t*)alloc((size_t)512 * 128 * 4);
  float*  hbufF = (float*)hbuf;
  __half* hbufH = (__half*)hbuf;

  // ---- CSR build ----
  zero_int_kernel<<<(N + 255) / 256, 256, 0, stream>>>(cursor, N);
  hist_kernel<<<(E + 255) / 256, 256, 0, stream>>>(dst, cursor, E);
  scan_kernel<<<1, 1024, 0, stream>>>(cursor, row_start, cursor, N);
  fill_kernel<<<(E + 255) / 256, 256, 0, stream>>>(src, dst, cursor, edge_src, E);
  sort_kernel<<<(N + 255) / 256, 256, 0, stream>>>(row_start, edge_src, N);

  const int aggGrid  = (N + 3) / 4;
  const int attnGrid = (N * 4 + 255) / 256;

  // ---- layer 1: [N,96] @ [96,128] ----
  split_pack_kernel<<<Mp, 96, 0, stream>>>(x, Apk, N, 96);
  split_pack_w_kernel<<<128, 96, 0, stream>>>(W1, Wpk, 96, 128);
  gemm_mfma_kernel<float><<<dim3(Mp / 128, 1), 256, 0, stream>>>(Apk, Wpk, hbufF, N, 96, 128);
  attn_kernel<32><<<attnGrid, 256, 0, stream>>>(hbufF, a1s, a1d, es, ed, N);
  aggregate12_kernel<<<aggGrid, 256, 0, stream>>>(row_start, edge_src, hbufF, es, ed, actA, N);

  // ---- layer 2: [N,128] @ [128,128] ----
  split_pack_kernel<<<Mp, 128, 0, stream>>>(actA, Apk, N, 128);
  split_pack_w_kernel<<<128, 128, 0, stream>>>(W2, Wpk, 128, 128);
  gemm_mfma_kernel<float><<<dim3(Mp / 128, 1), 256, 0, stream>>>(Apk, Wpk, hbufF, N, 128, 128);
  attn_kernel<32><<<attnGrid, 256, 0, stream>>>(hbufF, a2s, a2d, es, ed, N);
  aggregate12_kernel<<<aggGrid, 256, 0, stream>>>(row_start, edge_src, hbufF, es, ed, actB, N);

  // ---- layer 3: [N,128] @ [128,512] (fp16 table), head-mean ----
  split_pack_kernel<<<Mp, 128, 0, stream>>>(actB, Apk, N, 128);
  split_pack_w_kernel<<<512, 128, 0, stream>>>(W3, Wpk, 128, 512);
  gemm_mfma_kernel<__half><<<dim3(Mp / 128, 4), 256, 0, stream>>>(Apk, Wpk, hbufH, N, 128, 512);
  attn_h_kernel<<<attnGrid, 256, 0, stream>>>(hbufH, a3s, a3d, es, ed, N);
  aggregate3_kernel<<<aggGrid, 256, 0, stream>>>(row_start, edge_src, hbufH, es, ed, (float*)d_out, N);
}

// Round 5
// 642.987 us; speedup vs baseline: 1.2920x; 1.1458x over previous
//
#include <hip/hip_runtime.h>
#include <hip/hip_bf16.h>
#include <hip/hip_fp16.h>
#include <cstddef>
#include <stdint.h>
#include <math.h>

// ---------------------------------------------------------------------------
// GAT 3-layer forward on MI355X.
//   CSR build: zero -> histogram(dst) -> scan -> fill -> wave bitonic sort
//   per layer: split-bf16 (hi/lo, 3x MFMA) GEMM (dual fp16+fp32 out) ->
//              attn coefs (fp32) -> wave-per-node fused segment softmax +
//              fp16-table gather-aggregate (fp32 accum).
// ---------------------------------------------------------------------------

static __device__ __forceinline__ float lrelu(float x){ return x > 0.f ? x : 0.2f * x; }
static __device__ __forceinline__ float elu_f(float x){ return x > 0.f ? x : expm1f(x); }

typedef __bf16 bf16x8 __attribute__((ext_vector_type(8)));
typedef float  f32x4  __attribute__((ext_vector_type(4)));

// ============================ CSR build ====================================
__global__ void zero_int_kernel(int* __restrict__ p, int n){
  int i = blockIdx.x * blockDim.x + threadIdx.x;
  if (i < n) p[i] = 0;
}

__global__ void hist_kernel(const int* __restrict__ dst, int* __restrict__ deg, int E){
  int e = blockIdx.x * blockDim.x + threadIdx.x;
  if (e < E) atomicAdd(&deg[dst[e]], 1);
}

__global__ __launch_bounds__(1024) void scan_kernel(const int* __restrict__ deg,
    int* __restrict__ row_start, int* __restrict__ cursor, int N){
  __shared__ int wsum[16];
  __shared__ int s_carry;
  const int tid = threadIdx.x, lane = tid & 63, wid = tid >> 6;
  if (tid == 0) s_carry = 0;
  __syncthreads();
  for (int base = 0; base < N; base += 1024){
    int i = base + tid;
    int v = (i < N) ? deg[i] : 0;
    int incl = v;
    #pragma unroll
    for (int off = 1; off < 64; off <<= 1){
      int t = __shfl_up(incl, off);
      if (lane >= off) incl += t;
    }
    if (lane == 63) wsum[wid] = incl;
    __syncthreads();
    if (tid == 0){
      int run = 0;
      #pragma unroll
      for (int w = 0; w < 16; w++){ int t = wsum[w]; wsum[w] = run; run += t; }
    }
    __syncthreads();
    int excl = s_carry + wsum[wid] + incl - v;
    if (i < N){ row_start[i] = excl; cursor[i] = excl; }
    __syncthreads();
    if (tid == 1023) s_carry = excl + v;
    __syncthreads();
  }
  if (tid == 0) row_start[N] = s_carry;
}

__global__ void fill_kernel(const int* __restrict__ src, const int* __restrict__ dst,
    int* __restrict__ cursor, int* __restrict__ edge_src, int E){
  int e = blockIdx.x * blockDim.x + threadIdx.x;
  if (e < E){
    int p = atomicAdd(&cursor[dst[e]], 1);
    edge_src[p] = src[e];
  }
}

// deterministic order: ascending srcs. Wave bitonic for deg<=64 (the norm).
__global__ __launch_bounds__(256) void sort_kernel(
    const int* __restrict__ row_start, int* __restrict__ edge_src, int N){
  const int lane = threadIdx.x & 63;
  const int n = blockIdx.x * 4 + (threadIdx.x >> 6);
  if (n >= N) return;
  const int rs = row_start[n], deg = row_start[n + 1] - rs;
  if (deg <= 1) return;
  if (deg <= 64){
    int v = (lane < deg) ? edge_src[rs + lane] : 0x7FFFFFFF;
    #pragma unroll
    for (int k = 2; k <= 64; k <<= 1){
      #pragma unroll
      for (int j = k >> 1; j >= 1; j >>= 1){
        int partner = __shfl_xor(v, j);
        const bool up = ((lane & k) == 0);
        const bool keepmin = (((lane & j) == 0) == up);
        v = keepmin ? min(v, partner) : max(v, partner);
      }
    }
    if (lane < deg) edge_src[rs + lane] = v;
  } else if (lane == 0){
    for (int i = rs + 1; i < rs + deg; i++){
      int key = edge_src[i];
      int j = i - 1;
      while (j >= rs && edge_src[j] > key){ edge_src[j + 1] = edge_src[j]; j--; }
      edge_src[j + 1] = key;
    }
  }
}

// ====================== split-bf16 packing =================================
static __device__ __forceinline__ uint32_t pack_hi_lo(float a){
  uint32_t u  = __float_as_uint(a);
  uint32_t hb = (u + 0x7FFFu + ((u >> 16) & 1u)) & 0xFFFF0000u;  // bf16 RNE of a
  float lof   = a - __uint_as_float(hb);
  uint32_t ul = __float_as_uint(lof);
  uint32_t lb = (ul + 0x7FFFu + ((ul >> 16) & 1u)) >> 16;        // bf16 RNE of residual
  return (hb >> 16) | (lb << 16);
}

__global__ void split_pack_kernel(const float* __restrict__ A, uint32_t* __restrict__ P,
                                  int M, int K){
  const int r = blockIdx.x;
  const int c = threadIdx.x;
  float a = (r < M) ? A[(size_t)r * K + c] : 0.f;
  P[(size_t)r * K + c] = pack_hi_lo(a);
}

__global__ void split_pack_w_kernel(const float* __restrict__ W, uint32_t* __restrict__ P,
                                    int K, int N){
  const int n = blockIdx.x;
  const int k = threadIdx.x;
  P[(size_t)n * K + k] = pack_hi_lo(W[(size_t)k * N + n]);
}

// ====================== MFMA GEMM (split-bf16, 3 mfma) =====================
union PKU { uint32_t u[4]; bf16x8 v; };

static __device__ __forceinline__ void unpack_frag(const uint4 q0, const uint4 q1,
                                                   bf16x8& hi, bf16x8& lo){
  PKU H, L;
  H.u[0] = (q0.x & 0xFFFFu) | (q0.y << 16);
  H.u[1] = (q0.z & 0xFFFFu) | (q0.w << 16);
  H.u[2] = (q1.x & 0xFFFFu) | (q1.y << 16);
  H.u[3] = (q1.z & 0xFFFFu) | (q1.w << 16);
  L.u[0] = (q0.x >> 16) | (q0.y & 0xFFFF0000u);
  L.u[1] = (q0.z >> 16) | (q0.w & 0xFFFF0000u);
  L.u[2] = (q1.x >> 16) | (q1.y & 0xFFFF0000u);
  L.u[3] = (q1.z >> 16) | (q1.w & 0xFFFF0000u);
  hi = H.v; lo = L.v;
}

// C = A@W. Apk [Mp,K] packed, Wpk [Nout,K] packed. 128x128 tile, 4 waves 2x2.
// Writes fp16 table Ch always; also fp32 Cf when non-null (attn precision).
__global__ __launch_bounds__(256) void gemm_mfma_kernel(
    const uint32_t* __restrict__ Apk, const uint32_t* __restrict__ Wpk,
    __half* __restrict__ Ch, float* __restrict__ Cf, int M, int K, int Nout)
{
  __shared__ uint32_t Asl[4096];   // [128 rows][32 k] u32, XOR-swizzled
  __shared__ uint32_t Bsl[4096];
  const int tid  = threadIdx.x;
  const int lane = tid & 63;
  const int wid  = tid >> 6;
  const int wm   = (wid >> 1) * 64;
  const int wn   = (wid & 1) * 64;
  const int bm   = blockIdx.x * 128;
  const int bn   = blockIdx.y * 128;
  const int srow = tid >> 3;
  const int skof = (tid & 7) * 4;
  const int fr   = lane & 15;
  const int kg   = (lane >> 4) * 8;

  f32x4 acc[4][4] = {};

  for (int kt = 0; kt < K; kt += 32){
    uint4 av[4], bv[4];
    #pragma unroll
    for (int it = 0; it < 4; it++){
      const int r = srow + it * 32;
      av[it] = *reinterpret_cast<const uint4*>(Apk + (size_t)(bm + r) * K + kt + skof);
      bv[it] = *reinterpret_cast<const uint4*>(Wpk + (size_t)(bn + r) * K + kt + skof);
    }
    __syncthreads();
    #pragma unroll
    for (int it = 0; it < 4; it++){
      const int r  = srow + it * 32;
      const int sw = (r * 32 + skof) ^ ((r & 7) << 2);
      *reinterpret_cast<uint4*>(&Asl[sw]) = av[it];
      *reinterpret_cast<uint4*>(&Bsl[sw]) = bv[it];
    }
    __syncthreads();

    bf16x8 Ah[4], Al[4];
    #pragma unroll
    for (int mf = 0; mf < 4; mf++){
      const int r  = wm + mf * 16 + fr;
      const int b  = r * 32 + kg;
      const int sx = (r & 7) << 2;
      const uint4 q0 = *reinterpret_cast<const uint4*>(&Asl[b ^ sx]);
      const uint4 q1 = *reinterpret_cast<const uint4*>(&Asl[(b + 4) ^ sx]);
      unpack_frag(q0, q1, Ah[mf], Al[mf]);
    }
    #pragma unroll
    for (int nf = 0; nf < 4; nf++){
      const int r  = wn + nf * 16 + fr;
      const int b  = r * 32 + kg;
      const int sx = (r & 7) << 2;
      const uint4 q0 = *reinterpret_cast<const uint4*>(&Bsl[b ^ sx]);
      const uint4 q1 = *reinterpret_cast<const uint4*>(&Bsl[(b + 4) ^ sx]);
      bf16x8 Bh, Bl;
      unpack_frag(q0, q1, Bh, Bl);
      #pragma unroll
      for (int mf = 0; mf < 4; mf++){
        acc[mf][nf] = __builtin_amdgcn_mfma_f32_16x16x32_bf16(Al[mf], Bh, acc[mf][nf], 0, 0, 0);
        acc[mf][nf] = __builtin_amdgcn_mfma_f32_16x16x32_bf16(Ah[mf], Bl, acc[mf][nf], 0, 0, 0);
        acc[mf][nf] = __builtin_amdgcn_mfma_f32_16x16x32_bf16(Ah[mf], Bh, acc[mf][nf], 0, 0, 0);
      }
    }
  }

  #pragma unroll
  for (int mf = 0; mf < 4; mf++){
    #pragma unroll
    for (int nf = 0; nf < 4; nf++){
      const int col = bn + wn + nf * 16 + fr;
      #pragma unroll
      for (int j = 0; j < 4; j++){
        const int row = bm + wm + mf * 16 + (lane >> 4) * 4 + j;
        if (row < M){
          const float v = acc[mf][nf][j];
          Ch[(size_t)row * Nout + col] = __float2half(v);
          if (Cf) Cf[(size_t)row * Nout + col] = v;
        }
      }
    }
  }
}

// =========================== attention coefs ===============================
// fp32 h (layers 1/2, D=32)
__global__ __launch_bounds__(256) void attn_kernel(
    const float* __restrict__ h, const float* __restrict__ a_s, const float* __restrict__ a_d,
    float* __restrict__ es, float* __restrict__ ed, int N)
{
  int gid = blockIdx.x * blockDim.x + threadIdx.x;
  int n = gid >> 2, hh = gid & 3;
  if (n >= N) return;
  const float* hp = h + (size_t)n * 128 + hh * 32;
  const float* sp = a_s + hh * 32;
  const float* dp = a_d + hh * 32;
  float ss = 0.f, sd = 0.f;
  #pragma unroll
  for (int d = 0; d < 32; d += 4){
    float4 hv = *reinterpret_cast<const float4*>(hp + d);
    float4 sv = *reinterpret_cast<const float4*>(sp + d);
    float4 dv = *reinterpret_cast<const float4*>(dp + d);
    ss += hv.x * sv.x + hv.y * sv.y + hv.z * sv.z + hv.w * sv.w;
    sd += hv.x * dv.x + hv.y * dv.y + hv.z * dv.z + hv.w * dv.w;
  }
  es[n * 4 + hh] = ss;
  ed[n * 4 + hh] = sd;
}

// fp16 h (layer 3, D=128)
__global__ __launch_bounds__(256) void attn_h_kernel(
    const __half* __restrict__ h, const float* __restrict__ a_s, const float* __restrict__ a_d,
    float* __restrict__ es, float* __restrict__ ed, int N)
{
  int gid = blockIdx.x * blockDim.x + threadIdx.x;
  int n = gid >> 2, hh = gid & 3;
  if (n >= N) return;
  const __half2* hp = reinterpret_cast<const __half2*>(h + (size_t)n * 512 + hh * 128);
  const float* sp = a_s + hh * 128;
  const float* dp = a_d + hh * 128;
  float ss = 0.f, sd = 0.f;
  #pragma unroll 8
  for (int d2 = 0; d2 < 64; d2++){
    float2 f = __half22float2(hp[d2]);
    ss += f.x * sp[2 * d2] + f.y * sp[2 * d2 + 1];
    sd += f.x * dp[2 * d2] + f.y * dp[2 * d2 + 1];
  }
  es[n * 4 + hh] = ss;
  ed[n * 4 + hh] = sd;
}

// ==================== aggregate: layers 1/2 (fp16 table, concat+ELU) =======
// [N,128] fp16 table: 16 lanes x 8 halfs cover a row; 4 edges per iteration.
// col = (lane&15)*8 + q  ->  head = (lane&15)>>2 (all 8 cols same head).
__global__ __launch_bounds__(256) void aggregate12_kernel(
    const int* __restrict__ row_start, const int* __restrict__ edge_src,
    const __half* __restrict__ hbuf, const float* __restrict__ es, const float* __restrict__ ed,
    float* __restrict__ out, int N)
{
  const int lane = threadIdx.x & 63;
  const int n = blockIdx.x * 4 + (threadIdx.x >> 6);
  if (n >= N) return;
  const int rs  = row_start[n];
  const int deg = row_start[n + 1] - rs;
  const float4 ed4 = *reinterpret_cast<const float4*>(&ed[n * 4]);
  const int sub  = lane >> 4;        // edge subgroup 0..3
  const int cl   = lane & 15;        // col lane
  const int head = cl >> 2;
  float acc[8] = {0.f, 0.f, 0.f, 0.f, 0.f, 0.f, 0.f, 0.f};

  auto gather = [&](int cnt, int s_reg, float a0, float a1, float a2, float a3){
    for (int j = 0; j < cnt; j += 4){
      const int  el    = j + sub;
      const bool valid = el < cnt;
      const int  ei    = valid ? el : 0;
      const int  s     = __shfl(s_reg, ei);
      const float b0 = __shfl(a0, ei), b1 = __shfl(a1, ei);
      const float b2 = __shfl(a2, ei), b3 = __shfl(a3, ei);
      float al = head == 0 ? b0 : head == 1 ? b1 : head == 2 ? b2 : b3;
      if (!valid) al = 0.f;
      const uint4 raw = *reinterpret_cast<const uint4*>(hbuf + (size_t)s * 128 + cl * 8);
      const __half2* hp = reinterpret_cast<const __half2*>(&raw);
      #pragma unroll
      for (int q = 0; q < 4; q++){
        float2 f = __half22float2(hp[q]);
        acc[q * 2]     = fmaf(f.x, al, acc[q * 2]);
        acc[q * 2 + 1] = fmaf(f.y, al, acc[q * 2 + 1]);
      }
    }
  };

  if (deg <= 64){
    int   s_reg = 0;
    float e0 = -INFINITY, e1 = -INFINITY, e2 = -INFINITY, e3 = -INFINITY;
    if (lane < deg){
      s_reg = edge_src[rs + lane];
      const float4 e4 = *reinterpret_cast<const float4*>(&es[s_reg * 4]);
      e0 = lrelu(e4.x + ed4.x); e1 = lrelu(e4.y + ed4.y);
      e2 = lrelu(e4.z + ed4.z); e3 = lrelu(e4.w + ed4.w);
    }
    float mx0 = e0, mx1 = e1, mx2 = e2, mx3 = e3;
    #pragma unroll
    for (int off = 1; off < 64; off <<= 1){
      mx0 = fmaxf(mx0, __shfl_xor(mx0, off)); mx1 = fmaxf(mx1, __shfl_xor(mx1, off));
      mx2 = fmaxf(mx2, __shfl_xor(mx2, off)); mx3 = fmaxf(mx3, __shfl_xor(mx3, off));
    }
    float p0 = 0.f, p1 = 0.f, p2 = 0.f, p3 = 0.f;
    if (lane < deg){
      p0 = __expf(e0 - mx0); p1 = __expf(e1 - mx1);
      p2 = __expf(e2 - mx2); p3 = __expf(e3 - mx3);
    }
    float s0 = p0, s1 = p1, s2 = p2, s3 = p3;
    #pragma unroll
    for (int off = 1; off < 64; off <<= 1){
      s0 += __shfl_xor(s0, off); s1 += __shfl_xor(s1, off);
      s2 += __shfl_xor(s2, off); s3 += __shfl_xor(s3, off);
    }
    gather(deg, s_reg,
           p0 / (s0 + 1e-16f), p1 / (s1 + 1e-16f),
           p2 / (s2 + 1e-16f), p3 / (s3 + 1e-16f));
  } else {
    float mx0 = -INFINITY, mx1 = -INFINITY, mx2 = -INFINITY, mx3 = -INFINITY;
    for (int i = lane; i < deg; i += 64){
      int s = edge_src[rs + i];
      float4 e4 = *reinterpret_cast<const float4*>(&es[s * 4]);
      mx0 = fmaxf(mx0, lrelu(e4.x + ed4.x)); mx1 = fmaxf(mx1, lrelu(e4.y + ed4.y));
      mx2 = fmaxf(mx2, lrelu(e4.z + ed4.z)); mx3 = fmaxf(mx3, lrelu(e4.w + ed4.w));
    }
    #pragma unroll
    for (int off = 1; off < 64; off <<= 1){
      mx0 = fmaxf(mx0, __shfl_xor(mx0, off)); mx1 = fmaxf(mx1, __shfl_xor(mx1, off));
      mx2 = fmaxf(mx2, __shfl_xor(mx2, off)); mx3 = fmaxf(mx3, __shfl_xor(mx3, off));
    }
    float s0 = 0.f, s1 = 0.f, s2 = 0.f, s3 = 0.f;
    for (int i = lane; i < deg; i += 64){
      int s = edge_src[rs + i];
      float4 e4 = *reinterpret_cast<const float4*>(&es[s * 4]);
      s0 += __expf(lrelu(e4.x + ed4.x) - mx0); s1 += __expf(lrelu(e4.y + ed4.y) - mx1);
      s2 += __expf(lrelu(e4.z + ed4.z) - mx2); s3 += __expf(lrelu(e4.w + ed4.w) - mx3);
    }
    #pragma unroll
    for (int off = 1; off < 64; off <<= 1){
      s0 += __shfl_xor(s0, off); s1 += __shfl_xor(s1, off);
      s2 += __shfl_xor(s2, off); s3 += __shfl_xor(s3, off);
    }
    const float inv0 = 1.f / (s0 + 1e-16f), inv1 = 1.f / (s1 + 1e-16f);
    const float inv2 = 1.f / (s2 + 1e-16f), inv3 = 1.f / (s3 + 1e-16f);
    for (int base = 0; base < deg; base += 64){
      const int cnt = min(64, deg - base);
      int s_reg = 0; float a0 = 0.f, a1 = 0.f, a2 = 0.f, a3 = 0.f;
      if (lane < cnt){
        s_reg = edge_src[rs + base + lane];
        const float4 e4 = *reinterpret_cast<const float4*>(&es[s_reg * 4]);
        a0 = __expf(lrelu(e4.x + ed4.x) - mx0) * inv0;
        a1 = __expf(lrelu(e4.y + ed4.y) - mx1) * inv1;
        a2 = __expf(lrelu(e4.z + ed4.z) - mx2) * inv2;
        a3 = __expf(lrelu(e4.w + ed4.w) - mx3) * inv3;
      }
      gather(cnt, s_reg, a0, a1, a2, a3);
    }
  }

  // 4 copies of each col class at lanes {cl, cl+16, cl+32, cl+48}
  #pragma unroll
  for (int q = 0; q < 8; q++){
    acc[q] += __shfl_xor(acc[q], 16);
    acc[q] += __shfl_xor(acc[q], 32);
  }
  if (lane < 16){
    *reinterpret_cast<float4*>(&out[(size_t)n * 128 + lane * 8]) =
        make_float4(elu_f(acc[0]), elu_f(acc[1]), elu_f(acc[2]), elu_f(acc[3]));
    *reinterpret_cast<float4*>(&out[(size_t)n * 128 + lane * 8 + 4]) =
        make_float4(elu_f(acc[4]), elu_f(acc[5]), elu_f(acc[6]), elu_f(acc[7]));
  }
}

// ==================== aggregate: layer 3 (fp16 table, head-mean) ===========
__global__ __launch_bounds__(256) void aggregate3_kernel(
    const int* __restrict__ row_start, const int* __restrict__ edge_src,
    const __half* __restrict__ hbuf, const float* __restrict__ es, const float* __restrict__ ed,
    float* __restrict__ out, int N)
{
  const int lane = threadIdx.x & 63;
  const int n = blockIdx.x * 4 + (threadIdx.x >> 6);
  if (n >= N) return;
  const int rs  = row_start[n];
  const int deg = row_start[n + 1] - rs;
  const float4 ed4 = *reinterpret_cast<const float4*>(&ed[n * 4]);
  const int head = lane >> 4;
  float acc[8] = {0.f, 0.f, 0.f, 0.f, 0.f, 0.f, 0.f, 0.f};

  auto gather = [&](int cnt, int s_reg, float a0, float a1, float a2, float a3){
    for (int j = 0; j < cnt; j++){
      const int s = __shfl(s_reg, j);
      const float b0 = __shfl(a0, j), b1 = __shfl(a1, j);
      const float b2 = __shfl(a2, j), b3 = __shfl(a3, j);
      const float al = head == 0 ? b0 : head == 1 ? b1 : head == 2 ? b2 : b3;
      const uint4 raw = *reinterpret_cast<const uint4*>(hbuf + (size_t)s * 512 + lane * 8);
      const __half2* hp = reinterpret_cast<const __half2*>(&raw);
      #pragma unroll
      for (int q = 0; q < 4; q++){
        float2 f = __half22float2(hp[q]);
        acc[q * 2]     = fmaf(f.x, al, acc[q * 2]);
        acc[q * 2 + 1] = fmaf(f.y, al, acc[q * 2 + 1]);
      }
    }
  };

  if (deg <= 64){
    int   s_reg = 0;
    float e0 = -INFINITY, e1 = -INFINITY, e2 = -INFINITY, e3 = -INFINITY;
    if (lane < deg){
      s_reg = edge_src[rs + lane];
      const float4 e4 = *reinterpret_cast<const float4*>(&es[s_reg * 4]);
      e0 = lrelu(e4.x + ed4.x); e1 = lrelu(e4.y + ed4.y);
      e2 = lrelu(e4.z + ed4.z); e3 = lrelu(e4.w + ed4.w);
    }
    float mx0 = e0, mx1 = e1, mx2 = e2, mx3 = e3;
    #pragma unroll
    for (int off = 1; off < 64; off <<= 1){
      mx0 = fmaxf(mx0, __shfl_xor(mx0, off)); mx1 = fmaxf(mx1, __shfl_xor(mx1, off));
      mx2 = fmaxf(mx2, __shfl_xor(mx2, off)); mx3 = fmaxf(mx3, __shfl_xor(mx3, off));
    }
    float p0 = 0.f, p1 = 0.f, p2 = 0.f, p3 = 0.f;
    if (lane < deg){
      p0 = __expf(e0 - mx0); p1 = __expf(e1 - mx1);
      p2 = __expf(e2 - mx2); p3 = __expf(e3 - mx3);
    }
    float s0 = p0, s1 = p1, s2 = p2, s3 = p3;
    #pragma unroll
    for (int off = 1; off < 64; off <<= 1){
      s0 += __shfl_xor(s0, off); s1 += __shfl_xor(s1, off);
      s2 += __shfl_xor(s2, off); s3 += __shfl_xor(s3, off);
    }
    gather(deg, s_reg,
           p0 / (s0 + 1e-16f), p1 / (s1 + 1e-16f),
           p2 / (s2 + 1e-16f), p3 / (s3 + 1e-16f));
  } else {
    float mx0 = -INFINITY, mx1 = -INFINITY, mx2 = -INFINITY, mx3 = -INFINITY;
    for (int i = lane; i < deg; i += 64){
      int s = edge_src[rs + i];
      float4 e4 = *reinterpret_cast<const float4*>(&es[s * 4]);
      mx0 = fmaxf(mx0, lrelu(e4.x + ed4.x)); mx1 = fmaxf(mx1, lrelu(e4.y + ed4.y));
      mx2 = fmaxf(mx2, lrelu(e4.z + ed4.z)); mx3 = fmaxf(mx3, lrelu(e4.w + ed4.w));
    }
    #pragma unroll
    for (int off = 1; off < 64; off <<= 1){
      mx0 = fmaxf(mx0, __shfl_xor(mx0, off)); mx1 = fmaxf(mx1, __shfl_xor(mx1, off));
      mx2 = fmaxf(mx2, __shfl_xor(mx2, off)); mx3 = fmaxf(mx3, __shfl_xor(mx3, off));
    }
    float s0 = 0.f, s1 = 0.f, s2 = 0.f, s3 = 0.f;
    for (int i = lane; i < deg; i += 64){
      int s = edge_src[rs + i];
      float4 e4 = *reinterpret_cast<const float4*>(&es[s * 4]);
      s0 += __expf(lrelu(e4.x + ed4.x) - mx0); s1 += __expf(lrelu(e4.y + ed4.y) - mx1);
      s2 += __expf(lrelu(e4.z + ed4.z) - mx2); s3 += __expf(lrelu(e4.w + ed4.w) - mx3);
    }
    #pragma unroll
    for (int off = 1; off < 64; off <<= 1){
      s0 += __shfl_xor(s0, off); s1 += __shfl_xor(s1, off);
      s2 += __shfl_xor(s2, off); s3 += __shfl_xor(s3, off);
    }
    const float inv0 = 1.f / (s0 + 1e-16f), inv1 = 1.f / (s1 + 1e-16f);
    const float inv2 = 1.f / (s2 + 1e-16f), inv3 = 1.f / (s3 + 1e-16f);
    for (int base = 0; base < deg; base += 64){
      const int cnt = min(64, deg - base);
      int s_reg = 0; float a0 = 0.f, a1 = 0.f, a2 = 0.f, a3 = 0.f;
      if (lane < cnt){
        s_reg = edge_src[rs + base + lane];
        const float4 e4 = *reinterpret_cast<const float4*>(&es[s_reg * 4]);
        a0 = __expf(lrelu(e4.x + ed4.x) - mx0) * inv0;
        a1 = __expf(lrelu(e4.y + ed4.y) - mx1) * inv1;
        a2 = __expf(lrelu(e4.z + ed4.z) - mx2) * inv2;
        a3 = __expf(lrelu(e4.w + ed4.w) - mx3) * inv3;
      }
      gather(cnt, s_reg, a0, a1, a2, a3);
    }
  }

  #pragma unroll
  for (int q = 0; q < 8; q++){
    acc[q] += __shfl_xor(acc[q], 16);
    acc[q] += __shfl_xor(acc[q], 32);
  }
  if (lane < 16){
    *reinterpret_cast<float4*>(&out[(size_t)n * 128 + lane * 8]) =
        make_float4(acc[0] * 0.25f, acc[1] * 0.25f, acc[2] * 0.25f, acc[3] * 0.25f);
    *reinterpret_cast<float4*>(&out[(size_t)n * 128 + lane * 8 + 4]) =
        make_float4(acc[4] * 0.25f, acc[5] * 0.25f, acc[6] * 0.25f, acc[7] * 0.25f);
  }
}

// =============================== driver ====================================
extern "C" void kernel_launch(void* const* d_in, const int* in_sizes, int n_in,
                              void* d_out, int out_size, void* d_ws, size_t ws_size,
                              hipStream_t stream) {
  const float* x   = (const float*)d_in[0];
  const int*   src = (const int*)  d_in[1];
  const int*   dst = (const int*)  d_in[2];
  const float* W1  = (const float*)d_in[3];
  const float* a1s = (const float*)d_in[4];
  const float* a1d = (const float*)d_in[5];
  const float* W2  = (const float*)d_in[6];
  const float* a2s = (const float*)d_in[7];
  const float* a2d = (const float*)d_in[8];
  const float* W3  = (const float*)d_in[9];
  const float* a3s = (const float*)d_in[10];
  const float* a3d = (const float*)d_in[11];

  const int N  = in_sizes[0] / 96;
  const int E  = in_sizes[1];
  const int Mp = (N + 127) & ~127;

  char* ws = (char*)d_ws;
  auto alloc = [&](size_t bytes) -> void* {
    void* p = (void*)ws;
    ws += (bytes + 255) & ~(size_t)255;
    return p;
  };
  int*      row_start = (int*)     alloc((size_t)(N + 1) * 4);
  int*      cursor    = (int*)     alloc((size_t)N * 4);
  int*      edge_src  = (int*)     alloc((size_t)E * 4);
  float*    es        = (float*)   alloc((size_t)N * 4 * 4);
  float*    ed        = (float*)   alloc((size_t)N * 4 * 4);
  __half*   hbufH     = (__half*)  alloc((size_t)N * 512 * 2);  // fp16 gather table
  float*    h32       = (float*)   alloc((size_t)N * 128 * 4);  // fp32 h for attn L1/2
  float*    actA      = (float*)   alloc((size_t)N * 128 * 4);
  float*    actB      = (float*)   alloc((size_t)N * 128 * 4);
  uint32_t* Apk       = (uint32_t*)alloc((size_t)Mp * 128 * 4);
  uint32_t* Wpk       = (uint32_t*)alloc((size_t)512 * 128 * 4);

  // ---- CSR build ----
  zero_int_kernel<<<(N + 255) / 256, 256, 0, stream>>>(cursor, N);
  hist_kernel<<<(E + 255) / 256, 256, 0, stream>>>(dst, cursor, E);
  scan_kernel<<<1, 1024, 0, stream>>>(cursor, row_start, cursor, N);
  fill_kernel<<<(E + 255) / 256, 256, 0, stream>>>(src, dst, cursor, edge_src, E);
  sort_kernel<<<(N + 3) / 4, 256, 0, stream>>>(row_start, edge_src, N);

  const int aggGrid  = (N + 3) / 4;
  const int attnGrid = (N * 4 + 255) / 256;

  // ---- layer 1: [N,96] @ [96,128] ----
  split_pack_kernel<<<Mp, 96, 0, stream>>>(x, Apk, N, 96);
  split_pack_w_kernel<<<128, 96, 0, stream>>>(W1, Wpk, 96, 128);
  gemm_mfma_kernel<<<dim3(Mp / 128, 1), 256, 0, stream>>>(Apk, Wpk, hbufH, h32, N, 96, 128);
  attn_kernel<<<attnGrid, 256, 0, stream>>>(h32, a1s, a1d, es, ed, N);
  aggregate12_kernel<<<aggGrid, 256, 0, stream>>>(row_start, edge_src, hbufH, es, ed, actA, N);

  // ---- layer 2: [N,128] @ [128,128] ----
  split_pack_kernel<<<Mp, 128, 0, stream>>>(actA, Apk, N, 128);
  split_pack_w_kernel<<<128, 128, 0, stream>>>(W2, Wpk, 128, 128);
  gemm_mfma_kernel<<<dim3(Mp / 128, 1), 256, 0, stream>>>(Apk, Wpk, hbufH, h32, N, 128, 128);
  attn_kernel<<<attnGrid, 256, 0, stream>>>(h32, a2s, a2d, es, ed, N);
  aggregate12_kernel<<<aggGrid, 256, 0, stream>>>(row_start, edge_src, hbufH, es, ed, actB, N);

  // ---- layer 3: [N,128] @ [128,512] (fp16 table), head-mean ----
  split_pack_kernel<<<Mp, 128, 0, stream>>>(actB, Apk, N, 128);
  split_pack_w_kernel<<<512, 128, 0, stream>>>(W3, Wpk, 128, 512);
  gemm_mfma_kernel<<<dim3(Mp / 128, 4), 256, 0, stream>>>(Apk, Wpk, hbufH, (float*)nullptr, N, 128, 512);
  attn_h_kernel<<<attnGrid, 256, 0, stream>>>(hbufH, a3s, a3d, es, ed, N);
  aggregate3_kernel<<<aggGrid, 256, 0, stream>>>(row_start, edge_src, hbufH, es, ed, (float*)d_out, N);
}

// Round 6
// 615.651 us; speedup vs baseline: 1.3494x; 1.0444x over previous
//
#include <hip/hip_runtime.h>
#include <hip/hip_bf16.h>
#include <hip/hip_fp16.h>
#include <cstddef>
#include <stdint.h>
#include <math.h>

// ---------------------------------------------------------------------------
// GAT 3-layer forward on MI355X.
//   CSR: zero -> hist -> 3-kernel parallel scan -> fill -> wave bitonic sort
//   L1/L2: split-bf16 MFMA GEMM (fp16 table out) -> folded attn coefs from
//          layer INPUT -> fused softmax + fp16 gather (fp32/fp16 dual out)
//   L3 (algebraic swap): folded attn from actB -> gather actB-fp16 into
//          z[N,4,128] emitted as packed split-bf16 -> one GEMM z@W3r -> d_out
// ---------------------------------------------------------------------------

static __device__ __forceinline__ float lrelu(float x){ return x > 0.f ? x : 0.2f * x; }
static __device__ __forceinline__ float elu_f(float x){ return x > 0.f ? x : expm1f(x); }

typedef __bf16 bf16x8 __attribute__((ext_vector_type(8)));
typedef float  f32x4  __attribute__((ext_vector_type(4)));

// ============================ CSR build ====================================
__global__ void zero_int_kernel(int* __restrict__ p, int n){
  int i = blockIdx.x * blockDim.x + threadIdx.x;
  if (i < n) p[i] = 0;
}

__global__ void hist_kernel(const int* __restrict__ dst, int* __restrict__ deg, int E){
  int e = blockIdx.x * blockDim.x + threadIdx.x;
  if (e < E) atomicAdd(&deg[dst[e]], 1);
}

// parallel scan: per-block scan -> block-sum scan -> add offsets
__global__ __launch_bounds__(1024) void scan1_kernel(const int* __restrict__ deg,
    int* __restrict__ partial, int* __restrict__ blocksum, int N){
  __shared__ int wsum[16];
  const int tid = threadIdx.x, lane = tid & 63, wid = tid >> 6;
  const int i = blockIdx.x * 1024 + tid;
  int v = (i < N) ? deg[i] : 0;
  int incl = v;
  #pragma unroll
  for (int off = 1; off < 64; off <<= 1){
    int t = __shfl_up(incl, off);
    if (lane >= off) incl += t;
  }
  if (lane == 63) wsum[wid] = incl;
  __syncthreads();
  if (tid == 0){
    int run = 0;
    #pragma unroll
    for (int w = 0; w < 16; w++){ int t = wsum[w]; wsum[w] = run; run += t; }
    blocksum[blockIdx.x] = run;
  }
  __syncthreads();
  if (i < N) partial[i] = wsum[wid] + incl - v;
}

__global__ void scan2_kernel(int* __restrict__ blocksum, int nb){
  const int lane = threadIdx.x;
  int v = (lane < nb) ? blocksum[lane] : 0;
  int incl = v;
  #pragma unroll
  for (int off = 1; off < 64; off <<= 1){
    int t = __shfl_up(incl, off);
    if (lane >= off) incl += t;
  }
  if (lane < nb) blocksum[lane] = incl - v;
}

__global__ void scan3_kernel(const int* __restrict__ partial, const int* __restrict__ blocksum,
    int* __restrict__ row_start, int* __restrict__ cursor, int N, int E){
  const int i = blockIdx.x * blockDim.x + threadIdx.x;
  if (i < N){
    const int r = partial[i] + blocksum[i >> 10];
    row_start[i] = r;
    cursor[i] = r;
  }
  if (i == 0) row_start[N] = E;
}

__global__ void fill_kernel(const int* __restrict__ src, const int* __restrict__ dst,
    int* __restrict__ cursor, int* __restrict__ edge_src, int E){
  int e = blockIdx.x * blockDim.x + threadIdx.x;
  if (e < E){
    int p = atomicAdd(&cursor[dst[e]], 1);
    edge_src[p] = src[e];
  }
}

// deterministic order: ascending srcs. Wave bitonic for deg<=64 (the norm).
__global__ __launch_bounds__(256) void sort_kernel(
    const int* __restrict__ row_start, int* __restrict__ edge_src, int N){
  const int lane = threadIdx.x & 63;
  const int n = blockIdx.x * 4 + (threadIdx.x >> 6);
  if (n >= N) return;
  const int rs = row_start[n], deg = row_start[n + 1] - rs;
  if (deg <= 1) return;
  if (deg <= 64){
    int v = (lane < deg) ? edge_src[rs + lane] : 0x7FFFFFFF;
    #pragma unroll
    for (int k = 2; k <= 64; k <<= 1){
      #pragma unroll
      for (int j = k >> 1; j >= 1; j >>= 1){
        int partner = __shfl_xor(v, j);
        const bool up = ((lane & k) == 0);
        const bool keepmin = (((lane & j) == 0) == up);
        v = keepmin ? min(v, partner) : max(v, partner);
      }
    }
    if (lane < deg) edge_src[rs + lane] = v;
  } else if (lane == 0){
    for (int i = rs + 1; i < rs + deg; i++){
      int key = edge_src[i];
      int j = i - 1;
      while (j >= rs && edge_src[j] > key){ edge_src[j + 1] = edge_src[j]; j--; }
      edge_src[j + 1] = key;
    }
  }
}

// ====================== split-bf16 packing =================================
static __device__ __forceinline__ uint32_t pack_hi_lo(float a){
  uint32_t u  = __float_as_uint(a);
  uint32_t hb = (u + 0x7FFFu + ((u >> 16) & 1u)) & 0xFFFF0000u;  // bf16 RNE of a
  float lof   = a - __uint_as_float(hb);
  uint32_t ul = __float_as_uint(lof);
  uint32_t lb = (ul + 0x7FFFu + ((ul >> 16) & 1u)) >> 16;        // bf16 RNE of residual
  return (hb >> 16) | (lb << 16);
}

__global__ void split_pack_kernel(const float* __restrict__ A, uint32_t* __restrict__ P,
                                  int M, int K){
  const int r = blockIdx.x;
  const int c = threadIdx.x;
  float a = (r < M) ? A[(size_t)r * K + c] : 0.f;
  P[(size_t)r * K + c] = pack_hi_lo(a);
}

__global__ void split_pack_w_kernel(const float* __restrict__ W, uint32_t* __restrict__ P,
                                    int K, int N){
  const int n = blockIdx.x;
  const int k = threadIdx.x;
  P[(size_t)n * K + k] = pack_hi_lo(W[(size_t)k * N + n]);
}

// W3 reordered+transposed for the post-aggregation GEMM, 0.25 head-mean folded:
// Wpk[nout, h*128+k] = pack(0.25 * W3[k, h*128+nout]). grid 128, block 512.
__global__ void pack_w3r_kernel(const float* __restrict__ W3, uint32_t* __restrict__ P){
  const int nout = blockIdx.x;
  const int kk   = threadIdx.x;
  const int h = kk >> 7, k = kk & 127;
  P[(size_t)nout * 512 + kk] = pack_hi_lo(W3[(size_t)k * 512 + h * 128 + nout] * 0.25f);
}

// fold attention vectors into layer-input space: wes[h,k] = sum_d W[k,h*D+d]*a_s[h,d]
__global__ void fold_kernel(const float* __restrict__ W, const float* __restrict__ as_,
                            const float* __restrict__ ad_, float* __restrict__ wes,
                            float* __restrict__ wed, int K, int D){
  int gid = blockIdx.x * blockDim.x + threadIdx.x;
  if (gid >= 4 * K) return;
  int h = gid / K, k = gid - h * K;
  const float* wr = W + (size_t)k * (4 * D) + h * D;
  const float* sa = as_ + h * D;
  const float* da = ad_ + h * D;
  float ss = 0.f, sd = 0.f;
  for (int d = 0; d < D; d++){ float w = wr[d]; ss += w * sa[d]; sd += w * da[d]; }
  wes[h * K + k] = ss;
  wed[h * K + k] = sd;
}

// ====================== MFMA GEMM (split-bf16, 3 mfma) =====================
union PKU { uint32_t u[4]; bf16x8 v; };

static __device__ __forceinline__ void unpack_frag(const uint4 q0, const uint4 q1,
                                                   bf16x8& hi, bf16x8& lo){
  PKU H, L;
  H.u[0] = (q0.x & 0xFFFFu) | (q0.y << 16);
  H.u[1] = (q0.z & 0xFFFFu) | (q0.w << 16);
  H.u[2] = (q1.x & 0xFFFFu) | (q1.y << 16);
  H.u[3] = (q1.z & 0xFFFFu) | (q1.w << 16);
  L.u[0] = (q0.x >> 16) | (q0.y & 0xFFFF0000u);
  L.u[1] = (q0.z >> 16) | (q0.w & 0xFFFF0000u);
  L.u[2] = (q1.x >> 16) | (q1.y & 0xFFFF0000u);
  L.u[3] = (q1.z >> 16) | (q1.w & 0xFFFF0000u);
  hi = H.v; lo = L.v;
}

// C = A@W. Apk [Mp,K] packed, Wpk [Nout,K] packed. 128x128 tile, 4 waves 2x2.
// Ch (fp16) and Cf (fp32) are each optional.
__global__ __launch_bounds__(256) void gemm_mfma_kernel(
    const uint32_t* __restrict__ Apk, const uint32_t* __restrict__ Wpk,
    __half* __restrict__ Ch, float* __restrict__ Cf, int M, int K, int Nout)
{
  __shared__ uint32_t Asl[4096];   // [128 rows][32 k] u32, XOR-swizzled
  __shared__ uint32_t Bsl[4096];
  const int tid  = threadIdx.x;
  const int lane = tid & 63;
  const int wid  = tid >> 6;
  const int wm   = (wid >> 1) * 64;
  const int wn   = (wid & 1) * 64;
  const int bm   = blockIdx.x * 128;
  const int bn   = blockIdx.y * 128;
  const int srow = tid >> 3;
  const int skof = (tid & 7) * 4;
  const int fr   = lane & 15;
  const int kg   = (lane >> 4) * 8;

  f32x4 acc[4][4] = {};

  for (int kt = 0; kt < K; kt += 32){
    uint4 av[4], bv[4];
    #pragma unroll
    for (int it = 0; it < 4; it++){
      const int r = srow + it * 32;
      av[it] = *reinterpret_cast<const uint4*>(Apk + (size_t)(bm + r) * K + kt + skof);
      bv[it] = *reinterpret_cast<const uint4*>(Wpk + (size_t)(bn + r) * K + kt + skof);
    }
    __syncthreads();
    #pragma unroll
    for (int it = 0; it < 4; it++){
      const int r  = srow + it * 32;
      const int sw = (r * 32 + skof) ^ ((r & 7) << 2);
      *reinterpret_cast<uint4*>(&Asl[sw]) = av[it];
      *reinterpret_cast<uint4*>(&Bsl[sw]) = bv[it];
    }
    __syncthreads();

    bf16x8 Ah[4], Al[4];
    #pragma unroll
    for (int mf = 0; mf < 4; mf++){
      const int r  = wm + mf * 16 + fr;
      const int b  = r * 32 + kg;
      const int sx = (r & 7) << 2;
      const uint4 q0 = *reinterpret_cast<const uint4*>(&Asl[b ^ sx]);
      const uint4 q1 = *reinterpret_cast<const uint4*>(&Asl[(b + 4) ^ sx]);
      unpack_frag(q0, q1, Ah[mf], Al[mf]);
    }
    #pragma unroll
    for (int nf = 0; nf < 4; nf++){
      const int r  = wn + nf * 16 + fr;
      const int b  = r * 32 + kg;
      const int sx = (r & 7) << 2;
      const uint4 q0 = *reinterpret_cast<const uint4*>(&Bsl[b ^ sx]);
      const uint4 q1 = *reinterpret_cast<const uint4*>(&Bsl[(b + 4) ^ sx]);
      bf16x8 Bh, Bl;
      unpack_frag(q0, q1, Bh, Bl);
      #pragma unroll
      for (int mf = 0; mf < 4; mf++){
        acc[mf][nf] = __builtin_amdgcn_mfma_f32_16x16x32_bf16(Al[mf], Bh, acc[mf][nf], 0, 0, 0);
        acc[mf][nf] = __builtin_amdgcn_mfma_f32_16x16x32_bf16(Ah[mf], Bl, acc[mf][nf], 0, 0, 0);
        acc[mf][nf] = __builtin_amdgcn_mfma_f32_16x16x32_bf16(Ah[mf], Bh, acc[mf][nf], 0, 0, 0);
      }
    }
  }

  #pragma unroll
  for (int mf = 0; mf < 4; mf++){
    #pragma unroll
    for (int nf = 0; nf < 4; nf++){
      const int col = bn + wn + nf * 16 + fr;
      #pragma unroll
      for (int j = 0; j < 4; j++){
        const int row = bm + wm + mf * 16 + (lane >> 4) * 4 + j;
        if (row < M){
          const float v = acc[mf][nf][j];
          if (Ch) Ch[(size_t)row * Nout + col] = __float2half(v);
          if (Cf) Cf[(size_t)row * Nout + col] = v;
        }
      }
    }
  }
}

// ================= attention coefs from folded weights =====================
// es[n,h] = dot(in[n,:K], wes[h,:K]) — in is the LAYER INPUT (fp32).
template<int K>
__global__ __launch_bounds__(256) void attn_fold_kernel(
    const float* __restrict__ in, const float* __restrict__ wes, const float* __restrict__ wed,
    float* __restrict__ es, float* __restrict__ ed, int N)
{
  int gid = blockIdx.x * blockDim.x + threadIdx.x;
  int n = gid >> 2, h = gid & 3;
  if (n >= N) return;
  const float* ip = in + (size_t)n * K;
  const float* sp = wes + h * K;
  const float* dp = wed + h * K;
  float ss = 0.f, sd = 0.f;
  #pragma unroll
  for (int d = 0; d < K; d += 4){
    float4 hv = *reinterpret_cast<const float4*>(ip + d);
    float4 sv = *reinterpret_cast<const float4*>(sp + d);
    float4 dv = *reinterpret_cast<const float4*>(dp + d);
    ss += hv.x * sv.x + hv.y * sv.y + hv.z * sv.z + hv.w * sv.w;
    sd += hv.x * dv.x + hv.y * dv.y + hv.z * dv.z + hv.w * dv.w;
  }
  es[n * 4 + h] = ss;
  ed[n * 4 + h] = sd;
}

// ============ shared per-node softmax (deg<=64 fast path) ==================
// Returns this lane's edge src (s_reg) and its 4 normalized alphas.
// For deg>64 falls back inside the aggregate kernels (generic chunked path).

// ==================== aggregate: layers 1/2 (fp16 table, concat+ELU) =======
__global__ __launch_bounds__(256) void aggregate12_kernel(
    const int* __restrict__ row_start, const int* __restrict__ edge_src,
    const __half* __restrict__ hbuf, const float* __restrict__ es, const float* __restrict__ ed,
    float* __restrict__ out, __half* __restrict__ out16, int N)
{
  const int lane = threadIdx.x & 63;
  const int n = blockIdx.x * 4 + (threadIdx.x >> 6);
  if (n >= N) return;
  const int rs  = row_start[n];
  const int deg = row_start[n + 1] - rs;
  const float4 ed4 = *reinterpret_cast<const float4*>(&ed[n * 4]);
  const int sub  = lane >> 4;
  const int cl   = lane & 15;
  const int head = cl >> 2;
  float acc[8] = {0.f, 0.f, 0.f, 0.f, 0.f, 0.f, 0.f, 0.f};

  auto gather = [&](int cnt, int s_reg, float a0, float a1, float a2, float a3){
    for (int j = 0; j < cnt; j += 4){
      const int  el    = j + sub;
      const bool valid = el < cnt;
      const int  ei    = valid ? el : 0;
      const int  s     = __shfl(s_reg, ei);
      const float b0 = __shfl(a0, ei), b1 = __shfl(a1, ei);
      const float b2 = __shfl(a2, ei), b3 = __shfl(a3, ei);
      float al = head == 0 ? b0 : head == 1 ? b1 : head == 2 ? b2 : b3;
      if (!valid) al = 0.f;
      const uint4 raw = *reinterpret_cast<const uint4*>(hbuf + (size_t)s * 128 + cl * 8);
      const __half2* hp = reinterpret_cast<const __half2*>(&raw);
      #pragma unroll
      for (int q = 0; q < 4; q++){
        float2 f = __half22float2(hp[q]);
        acc[q * 2]     = fmaf(f.x, al, acc[q * 2]);
        acc[q * 2 + 1] = fmaf(f.y, al, acc[q * 2 + 1]);
      }
    }
  };

  if (deg <= 64){
    int   s_reg = 0;
    float e0 = -INFINITY, e1 = -INFINITY, e2 = -INFINITY, e3 = -INFINITY;
    if (lane < deg){
      s_reg = edge_src[rs + lane];
      const float4 e4 = *reinterpret_cast<const float4*>(&es[s_reg * 4]);
      e0 = lrelu(e4.x + ed4.x); e1 = lrelu(e4.y + ed4.y);
      e2 = lrelu(e4.z + ed4.z); e3 = lrelu(e4.w + ed4.w);
    }
    float mx0 = e0, mx1 = e1, mx2 = e2, mx3 = e3;
    #pragma unroll
    for (int off = 1; off < 64; off <<= 1){
      mx0 = fmaxf(mx0, __shfl_xor(mx0, off)); mx1 = fmaxf(mx1, __shfl_xor(mx1, off));
      mx2 = fmaxf(mx2, __shfl_xor(mx2, off)); mx3 = fmaxf(mx3, __shfl_xor(mx3, off));
    }
    float p0 = 0.f, p1 = 0.f, p2 = 0.f, p3 = 0.f;
    if (lane < deg){
      p0 = __expf(e0 - mx0); p1 = __expf(e1 - mx1);
      p2 = __expf(e2 - mx2); p3 = __expf(e3 - mx3);
    }
    float s0 = p0, s1 = p1, s2 = p2, s3 = p3;
    #pragma unroll
    for (int off = 1; off < 64; off <<= 1){
      s0 += __shfl_xor(s0, off); s1 += __shfl_xor(s1, off);
      s2 += __shfl_xor(s2, off); s3 += __shfl_xor(s3, off);
    }
    gather(deg, s_reg,
           p0 / (s0 + 1e-16f), p1 / (s1 + 1e-16f),
           p2 / (s2 + 1e-16f), p3 / (s3 + 1e-16f));
  } else {
    float mx0 = -INFINITY, mx1 = -INFINITY, mx2 = -INFINITY, mx3 = -INFINITY;
    for (int i = lane; i < deg; i += 64){
      int s = edge_src[rs + i];
      float4 e4 = *reinterpret_cast<const float4*>(&es[s * 4]);
      mx0 = fmaxf(mx0, lrelu(e4.x + ed4.x)); mx1 = fmaxf(mx1, lrelu(e4.y + ed4.y));
      mx2 = fmaxf(mx2, lrelu(e4.z + ed4.z)); mx3 = fmaxf(mx3, lrelu(e4.w + ed4.w));
    }
    #pragma unroll
    for (int off = 1; off < 64; off <<= 1){
      mx0 = fmaxf(mx0, __shfl_xor(mx0, off)); mx1 = fmaxf(mx1, __shfl_xor(mx1, off));
      mx2 = fmaxf(mx2, __shfl_xor(mx2, off)); mx3 = fmaxf(mx3, __shfl_xor(mx3, off));
    }
    float s0 = 0.f, s1 = 0.f, s2 = 0.f, s3 = 0.f;
    for (int i = lane; i < deg; i += 64){
      int s = edge_src[rs + i];
      float4 e4 = *reinterpret_cast<const float4*>(&es[s * 4]);
      s0 += __expf(lrelu(e4.x + ed4.x) - mx0); s1 += __expf(lrelu(e4.y + ed4.y) - mx1);
      s2 += __expf(lrelu(e4.z + ed4.z) - mx2); s3 += __expf(lrelu(e4.w + ed4.w) - mx3);
    }
    #pragma unroll
    for (int off = 1; off < 64; off <<= 1){
      s0 += __shfl_xor(s0, off); s1 += __shfl_xor(s1, off);
      s2 += __shfl_xor(s2, off); s3 += __shfl_xor(s3, off);
    }
    const float inv0 = 1.f / (s0 + 1e-16f), inv1 = 1.f / (s1 + 1e-16f);
    const float inv2 = 1.f / (s2 + 1e-16f), inv3 = 1.f / (s3 + 1e-16f);
    for (int base = 0; base < deg; base += 64){
      const int cnt = min(64, deg - base);
      int s_reg = 0; float a0 = 0.f, a1 = 0.f, a2 = 0.f, a3 = 0.f;
      if (lane < cnt){
        s_reg = edge_src[rs + base + lane];
        const float4 e4 = *reinterpret_cast<const float4*>(&es[s_reg * 4]);
        a0 = __expf(lrelu(e4.x + ed4.x) - mx0) * inv0;
        a1 = __expf(lrelu(e4.y + ed4.y) - mx1) * inv1;
        a2 = __expf(lrelu(e4.z + ed4.z) - mx2) * inv2;
        a3 = __expf(lrelu(e4.w + ed4.w) - mx3) * inv3;
      }
      gather(cnt, s_reg, a0, a1, a2, a3);
    }
  }

  #pragma unroll
  for (int q = 0; q < 8; q++){
    acc[q] += __shfl_xor(acc[q], 16);
    acc[q] += __shfl_xor(acc[q], 32);
  }
  if (lane < 16){
    const float o[8] = {elu_f(acc[0]), elu_f(acc[1]), elu_f(acc[2]), elu_f(acc[3]),
                        elu_f(acc[4]), elu_f(acc[5]), elu_f(acc[6]), elu_f(acc[7])};
    *reinterpret_cast<float4*>(&out[(size_t)n * 128 + lane * 8]) =
        make_float4(o[0], o[1], o[2], o[3]);
    *reinterpret_cast<float4*>(&out[(size_t)n * 128 + lane * 8 + 4]) =
        make_float4(o[4], o[5], o[6], o[7]);
    if (out16){
      union { __half2 h2[4]; uint4 u; } pk;
      pk.h2[0] = __floats2half2_rn(o[0], o[1]);
      pk.h2[1] = __floats2half2_rn(o[2], o[3]);
      pk.h2[2] = __floats2half2_rn(o[4], o[5]);
      pk.h2[3] = __floats2half2_rn(o[6], o[7]);
      *reinterpret_cast<uint4*>(&out16[(size_t)n * 128 + lane * 8]) = pk.u;
    }
  }
}

// ======= aggregate layer 3: gather actB16 -> z[N,4,128] packed split-bf16 ==
__global__ __launch_bounds__(256) void aggregate3_pack_kernel(
    const int* __restrict__ row_start, const int* __restrict__ edge_src,
    const __half* __restrict__ tbl, const float* __restrict__ es, const float* __restrict__ ed,
    uint32_t* __restrict__ Zpk, int N)
{
  const int lane = threadIdx.x & 63;
  const int n = blockIdx.x * 4 + (threadIdx.x >> 6);
  if (n >= N) return;
  const int rs  = row_start[n];
  const int deg = row_start[n + 1] - rs;
  const float4 ed4 = *reinterpret_cast<const float4*>(&ed[n * 4]);
  const int sub = lane >> 4;
  const int cl  = lane & 15;
  float acc[4][8] = {};

  auto gather = [&](int cnt, int s_reg, float a0, float a1, float a2, float a3){
    for (int j = 0; j < cnt; j += 4){
      const int  el    = j + sub;
      const bool valid = el < cnt;
      const int  ei    = valid ? el : 0;
      const int  s     = __shfl(s_reg, ei);
      float al[4];
      al[0] = __shfl(a0, ei); al[1] = __shfl(a1, ei);
      al[2] = __shfl(a2, ei); al[3] = __shfl(a3, ei);
      if (!valid){ al[0] = al[1] = al[2] = al[3] = 0.f; }
      const uint4 raw = *reinterpret_cast<const uint4*>(tbl + (size_t)s * 128 + cl * 8);
      const __half2* hp = reinterpret_cast<const __half2*>(&raw);
      float f[8];
      #pragma unroll
      for (int q = 0; q < 4; q++){
        float2 t = __half22float2(hp[q]);
        f[q * 2] = t.x; f[q * 2 + 1] = t.y;
      }
      #pragma unroll
      for (int h = 0; h < 4; h++)
        #pragma unroll
        for (int q = 0; q < 8; q++)
          acc[h][q] = fmaf(f[q], al[h], acc[h][q]);
    }
  };

  if (deg <= 64){
    int   s_reg = 0;
    float e0 = -INFINITY, e1 = -INFINITY, e2 = -INFINITY, e3 = -INFINITY;
    if (lane < deg){
      s_reg = edge_src[rs + lane];
      const float4 e4 = *reinterpret_cast<const float4*>(&es[s_reg * 4]);
      e0 = lrelu(e4.x + ed4.x); e1 = lrelu(e4.y + ed4.y);
      e2 = lrelu(e4.z + ed4.z); e3 = lrelu(e4.w + ed4.w);
    }
    float mx0 = e0, mx1 = e1, mx2 = e2, mx3 = e3;
    #pragma unroll
    for (int off = 1; off < 64; off <<= 1){
      mx0 = fmaxf(mx0, __shfl_xor(mx0, off)); mx1 = fmaxf(mx1, __shfl_xor(mx1, off));
      mx2 = fmaxf(mx2, __shfl_xor(mx2, off)); mx3 = fmaxf(mx3, __shfl_xor(mx3, off));
    }
    float p0 = 0.f, p1 = 0.f, p2 = 0.f, p3 = 0.f;
    if (lane < deg){
      p0 = __expf(e0 - mx0); p1 = __expf(e1 - mx1);
      p2 = __expf(e2 - mx2); p3 = __expf(e3 - mx3);
    }
    float s0 = p0, s1 = p1, s2 = p2, s3 = p3;
    #pragma unroll
    for (int off = 1; off < 64; off <<= 1){
      s0 += __shfl_xor(s0, off); s1 += __shfl_xor(s1, off);
      s2 += __shfl_xor(s2, off); s3 += __shfl_xor(s3, off);
    }
    gather(deg, s_reg,
           p0 / (s0 + 1e-16f), p1 / (s1 + 1e-16f),
           p2 / (s2 + 1e-16f), p3 / (s3 + 1e-16f));
  } else {
    float mx0 = -INFINITY, mx1 = -INFINITY, mx2 = -INFINITY, mx3 = -INFINITY;
    for (int i = lane; i < deg; i += 64){
      int s = edge_src[rs + i];
      float4 e4 = *reinterpret_cast<const float4*>(&es[s * 4]);
      mx0 = fmaxf(mx0, lrelu(e4.x + ed4.x)); mx1 = fmaxf(mx1, lrelu(e4.y + ed4.y));
      mx2 = fmaxf(mx2, lrelu(e4.z + ed4.z)); mx3 = fmaxf(mx3, lrelu(e4.w + ed4.w));
    }
    #pragma unroll
    for (int off = 1; off < 64; off <<= 1){
      mx0 = fmaxf(mx0, __shfl_xor(mx0, off)); mx1 = fmaxf(mx1, __shfl_xor(mx1, off));
      mx2 = fmaxf(mx2, __shfl_xor(mx2, off)); mx3 = fmaxf(mx3, __shfl_xor(mx3, off));
    }
    float s0 = 0.f, s1 = 0.f, s2 = 0.f, s3 = 0.f;
    for (int i = lane; i < deg; i += 64){
      int s = edge_src[rs + i];
      float4 e4 = *reinterpret_cast<const float4*>(&es[s * 4]);
      s0 += __expf(lrelu(e4.x + ed4.x) - mx0); s1 += __expf(lrelu(e4.y + ed4.y) - mx1);
      s2 += __expf(lrelu(e4.z + ed4.z) - mx2); s3 += __expf(lrelu(e4.w + ed4.w) - mx3);
    }
    #pragma unroll
    for (int off = 1; off < 64; off <<= 1){
      s0 += __shfl_xor(s0, off); s1 += __shfl_xor(s1, off);
      s2 += __shfl_xor(s2, off); s3 += __shfl_xor(s3, off);
    }
    const float inv0 = 1.f / (s0 + 1e-16f), inv1 = 1.f / (s1 + 1e-16f);
    const float inv2 = 1.f / (s2 + 1e-16f), inv3 = 1.f / (s3 + 1e-16f);
    for (int base = 0; base < deg; base += 64){
      const int cnt = min(64, deg - base);
      int s_reg = 0; float a0 = 0.f, a1 = 0.f, a2 = 0.f, a3 = 0.f;
      if (lane < cnt){
        s_reg = edge_src[rs + base + lane];
        const float4 e4 = *reinterpret_cast<const float4*>(&es[s_reg * 4]);
        a0 = __expf(lrelu(e4.x + ed4.x) - mx0) * inv0;
        a1 = __expf(lrelu(e4.y + ed4.y) - mx1) * inv1;
        a2 = __expf(lrelu(e4.z + ed4.z) - mx2) * inv2;
        a3 = __expf(lrelu(e4.w + ed4.w) - mx3) * inv3;
      }
      gather(cnt, s_reg, a0, a1, a2, a3);
    }
  }

  #pragma unroll
  for (int h = 0; h < 4; h++)
    #pragma unroll
    for (int q = 0; q < 8; q++){
      acc[h][q] += __shfl_xor(acc[h][q], 16);
      acc[h][q] += __shfl_xor(acc[h][q], 32);
    }
  if (lane < 16){
    #pragma unroll
    for (int h = 0; h < 4; h++){
      uint4 u0, u1;
      u0.x = pack_hi_lo(acc[h][0]); u0.y = pack_hi_lo(acc[h][1]);
      u0.z = pack_hi_lo(acc[h][2]); u0.w = pack_hi_lo(acc[h][3]);
      u1.x = pack_hi_lo(acc[h][4]); u1.y = pack_hi_lo(acc[h][5]);
      u1.z = pack_hi_lo(acc[h][6]); u1.w = pack_hi_lo(acc[h][7]);
      uint32_t* zp = Zpk + (size_t)n * 512 + h * 128 + cl * 8;
      *reinterpret_cast<uint4*>(zp)     = u0;
      *reinterpret_cast<uint4*>(zp + 4) = u1;
    }
  }
}

// =============================== driver ====================================
extern "C" void kernel_launch(void* const* d_in, const int* in_sizes, int n_in,
                              void* d_out, int out_size, void* d_ws, size_t ws_size,
                              hipStream_t stream) {
  const float* x   = (const float*)d_in[0];
  const int*   src = (const int*)  d_in[1];
  const int*   dst = (const int*)  d_in[2];
  const float* W1  = (const float*)d_in[3];
  const float* a1s = (const float*)d_in[4];
  const float* a1d = (const float*)d_in[5];
  const float* W2  = (const float*)d_in[6];
  const float* a2s = (const float*)d_in[7];
  const float* a2d = (const float*)d_in[8];
  const float* W3  = (const float*)d_in[9];
  const float* a3s = (const float*)d_in[10];
  const float* a3d = (const float*)d_in[11];

  const int N  = in_sizes[0] / 96;
  const int E  = in_sizes[1];
  const int Mp = (N + 127) & ~127;
  const int nb = (N + 1023) / 1024;

  char* ws = (char*)d_ws;
  auto alloc = [&](size_t bytes) -> void* {
    void* p = (void*)ws;
    ws += (bytes + 255) & ~(size_t)255;
    return p;
  };
  int*      row_start = (int*)     alloc((size_t)(N + 1) * 4);
  int*      cursor    = (int*)     alloc((size_t)N * 4);
  int*      blocksum  = (int*)     alloc((size_t)1024 * 4);
  int*      edge_src  = (int*)     alloc((size_t)E * 4);
  float*    es        = (float*)   alloc((size_t)N * 4 * 4);
  float*    ed        = (float*)   alloc((size_t)N * 4 * 4);
  float*    wes       = (float*)   alloc((size_t)4 * 128 * 4);
  float*    wed       = (float*)   alloc((size_t)4 * 128 * 4);
  __half*   hbufH     = (__half*)  alloc((size_t)N * 128 * 2);   // L1/L2 gather table
  float*    actA      = (float*)   alloc((size_t)N * 128 * 4);
  float*    actB      = (float*)   alloc((size_t)N * 128 * 4);
  __half*   actB16    = (__half*)  alloc((size_t)N * 128 * 2);   // L3 gather table
  uint32_t* Apk       = (uint32_t*)alloc((size_t)Mp * 512 * 4);  // packed A / z
  uint32_t* Wpk       = (uint32_t*)alloc((size_t)128 * 512 * 4);

  // ---- CSR build ----
  zero_int_kernel<<<(N + 255) / 256, 256, 0, stream>>>(cursor, N);
  hist_kernel<<<(E + 255) / 256, 256, 0, stream>>>(dst, cursor, E);
  scan1_kernel<<<nb, 1024, 0, stream>>>(cursor, row_start, blocksum, N);
  scan2_kernel<<<1, 64, 0, stream>>>(blocksum, nb);
  scan3_kernel<<<(N + 255) / 256, 256, 0, stream>>>(row_start, blocksum, row_start, cursor, N, E);
  fill_kernel<<<(E + 255) / 256, 256, 0, stream>>>(src, dst, cursor, edge_src, E);
  sort_kernel<<<(N + 3) / 4, 256, 0, stream>>>(row_start, edge_src, N);

  const int aggGrid  = (N + 3) / 4;
  const int attnGrid = (N * 4 + 255) / 256;

  // ---- layer 1: [N,96] @ [96,128] ----
  fold_kernel<<<2, 256, 0, stream>>>(W1, a1s, a1d, wes, wed, 96, 32);
  split_pack_kernel<<<Mp, 96, 0, stream>>>(x, Apk, N, 96);
  split_pack_w_kernel<<<128, 96, 0, stream>>>(W1, Wpk, 96, 128);
  gemm_mfma_kernel<<<dim3(Mp / 128, 1), 256, 0, stream>>>(Apk, Wpk, hbufH, (float*)nullptr, N, 96, 128);
  attn_fold_kernel<96><<<attnGrid, 256, 0, stream>>>(x, wes, wed, es, ed, N);
  aggregate12_kernel<<<aggGrid, 256, 0, stream>>>(row_start, edge_src, hbufH, es, ed, actA, (__half*)nullptr, N);

  // ---- layer 2: [N,128] @ [128,128] ----
  fold_kernel<<<2, 256, 0, stream>>>(W2, a2s, a2d, wes, wed, 128, 32);
  split_pack_kernel<<<Mp, 128, 0, stream>>>(actA, Apk, N, 128);
  split_pack_w_kernel<<<128, 128, 0, stream>>>(W2, Wpk, 128, 128);
  gemm_mfma_kernel<<<dim3(Mp / 128, 1), 256, 0, stream>>>(Apk, Wpk, hbufH, (float*)nullptr, N, 128, 128);
  attn_fold_kernel<128><<<attnGrid, 256, 0, stream>>>(actA, wes, wed, es, ed, N);
  aggregate12_kernel<<<aggGrid, 256, 0, stream>>>(row_start, edge_src, hbufH, es, ed, actB, actB16, N);

  // ---- layer 3 (aggregate-then-transform): ----
  fold_kernel<<<2, 256, 0, stream>>>(W3, a3s, a3d, wes, wed, 128, 128);
  attn_fold_kernel<128><<<attnGrid, 256, 0, stream>>>(actB, wes, wed, es, ed, N);
  aggregate3_pack_kernel<<<aggGrid, 256, 0, stream>>>(row_start, edge_src, actB16, es, ed, Apk, N);
  pack_w3r_kernel<<<128, 512, 0, stream>>>(W3, Wpk);
  gemm_mfma_kernel<<<dim3(Mp / 128, 1), 256, 0, stream>>>(Apk, Wpk, (__half*)nullptr, (float*)d_out, N, 512, 128);
}

// Round 7
// 523.808 us; speedup vs baseline: 1.5859x; 1.1753x over previous
//
#include <hip/hip_runtime.h>
#include <hip/hip_bf16.h>
#include <hip/hip_fp16.h>
#include <cstddef>
#include <stdint.h>
#include <math.h>

// ---------------------------------------------------------------------------
// GAT 3-layer forward on MI355X.
//   CSR: zero -> hist -> 3-kernel parallel scan -> fill -> wave bitonic sort
//   L1/L2: split-bf16 MFMA GEMM (fp16 table out) -> folded attn coefs from
//          layer INPUT -> fused softmax + fp16 gather (fp32/fp16 dual out)
//   L3 (algebraic swap): folded attn from actB -> gather actB-fp16 into
//          z[N,4,128] fp16 -> one fp16-MFMA GEMM z@W3r -> d_out
// ---------------------------------------------------------------------------

static __device__ __forceinline__ float lrelu(float x){ return x > 0.f ? x : 0.2f * x; }
static __device__ __forceinline__ float elu_f(float x){ return x > 0.f ? x : expm1f(x); }

typedef __bf16    bf16x8 __attribute__((ext_vector_type(8)));
typedef _Float16  f16x8  __attribute__((ext_vector_type(8)));
typedef float     f32x4  __attribute__((ext_vector_type(4)));

// ============================ CSR build ====================================
__global__ void zero_int_kernel(int* __restrict__ p, int n){
  int i = blockIdx.x * blockDim.x + threadIdx.x;
  if (i < n) p[i] = 0;
}

__global__ void hist_kernel(const int* __restrict__ dst, int* __restrict__ deg, int E){
  int e = blockIdx.x * blockDim.x + threadIdx.x;
  if (e < E) atomicAdd(&deg[dst[e]], 1);
}

// parallel scan: per-block scan -> block-sum scan -> add offsets
__global__ __launch_bounds__(1024) void scan1_kernel(const int* __restrict__ deg,
    int* __restrict__ partial, int* __restrict__ blocksum, int N){
  __shared__ int wsum[16];
  const int tid = threadIdx.x, lane = tid & 63, wid = tid >> 6;
  const int i = blockIdx.x * 1024 + tid;
  int v = (i < N) ? deg[i] : 0;
  int incl = v;
  #pragma unroll
  for (int off = 1; off < 64; off <<= 1){
    int t = __shfl_up(incl, off);
    if (lane >= off) incl += t;
  }
  if (lane == 63) wsum[wid] = incl;
  __syncthreads();
  if (tid == 0){
    int run = 0;
    #pragma unroll
    for (int w = 0; w < 16; w++){ int t = wsum[w]; wsum[w] = run; run += t; }
    blocksum[blockIdx.x] = run;
  }
  __syncthreads();
  if (i < N) partial[i] = wsum[wid] + incl - v;
}

__global__ void scan2_kernel(int* __restrict__ blocksum, int nb){
  const int lane = threadIdx.x;
  int v = (lane < nb) ? blocksum[lane] : 0;
  int incl = v;
  #pragma unroll
  for (int off = 1; off < 64; off <<= 1){
    int t = __shfl_up(incl, off);
    if (lane >= off) incl += t;
  }
  if (lane < nb) blocksum[lane] = incl - v;
}

__global__ void scan3_kernel(const int* __restrict__ partial, const int* __restrict__ blocksum,
    int* __restrict__ row_start, int* __restrict__ cursor, int N, int E){
  const int i = blockIdx.x * blockDim.x + threadIdx.x;
  if (i < N){
    const int r = partial[i] + blocksum[i >> 10];
    row_start[i] = r;
    cursor[i] = r;
  }
  if (i == 0) row_start[N] = E;
}

__global__ void fill_kernel(const int* __restrict__ src, const int* __restrict__ dst,
    int* __restrict__ cursor, int* __restrict__ edge_src, int E){
  int e = blockIdx.x * blockDim.x + threadIdx.x;
  if (e < E){
    int p = atomicAdd(&cursor[dst[e]], 1);
    edge_src[p] = src[e];
  }
}

// deterministic order: ascending srcs. Wave bitonic for deg<=64 (the norm).
__global__ __launch_bounds__(256) void sort_kernel(
    const int* __restrict__ row_start, int* __restrict__ edge_src, int N){
  const int lane = threadIdx.x & 63;
  const int n = blockIdx.x * 4 + (threadIdx.x >> 6);
  if (n >= N) return;
  const int rs = row_start[n], deg = row_start[n + 1] - rs;
  if (deg <= 1) return;
  if (deg <= 64){
    int v = (lane < deg) ? edge_src[rs + lane] : 0x7FFFFFFF;
    #pragma unroll
    for (int k = 2; k <= 64; k <<= 1){
      #pragma unroll
      for (int j = k >> 1; j >= 1; j >>= 1){
        int partner = __shfl_xor(v, j);
        const bool up = ((lane & k) == 0);
        const bool keepmin = (((lane & j) == 0) == up);
        v = keepmin ? min(v, partner) : max(v, partner);
      }
    }
    if (lane < deg) edge_src[rs + lane] = v;
  } else if (lane == 0){
    for (int i = rs + 1; i < rs + deg; i++){
      int key = edge_src[i];
      int j = i - 1;
      while (j >= rs && edge_src[j] > key){ edge_src[j + 1] = edge_src[j]; j--; }
      edge_src[j + 1] = key;
    }
  }
}

// ====================== split-bf16 packing =================================
static __device__ __forceinline__ uint32_t pack_hi_lo(float a){
  uint32_t u  = __float_as_uint(a);
  uint32_t hb = (u + 0x7FFFu + ((u >> 16) & 1u)) & 0xFFFF0000u;  // bf16 RNE of a
  float lof   = a - __uint_as_float(hb);
  uint32_t ul = __float_as_uint(lof);
  uint32_t lb = (ul + 0x7FFFu + ((ul >> 16) & 1u)) >> 16;        // bf16 RNE of residual
  return (hb >> 16) | (lb << 16);
}

__global__ void split_pack_kernel(const float* __restrict__ A, uint32_t* __restrict__ P,
                                  int M, int K){
  const int r = blockIdx.x;
  const int c = threadIdx.x;
  float a = (r < M) ? A[(size_t)r * K + c] : 0.f;
  P[(size_t)r * K + c] = pack_hi_lo(a);
}

__global__ void split_pack_w_kernel(const float* __restrict__ W, uint32_t* __restrict__ P,
                                    int K, int N){
  const int n = blockIdx.x;
  const int k = threadIdx.x;
  P[(size_t)n * K + k] = pack_hi_lo(W[(size_t)k * N + n]);
}

// W3 reordered+transposed fp16, 0.25 head-mean folded:
// W3h[nout, h*128+k] = fp16(0.25 * W3[k, h*128+nout]). grid 128, block 512.
__global__ void pack_w3r_h_kernel(const float* __restrict__ W3, __half* __restrict__ P){
  const int nout = blockIdx.x;
  const int kk   = threadIdx.x;
  const int h = kk >> 7, k = kk & 127;
  P[(size_t)nout * 512 + kk] = __float2half(0.25f * W3[(size_t)k * 512 + h * 128 + nout]);
}

// fold attention vectors into layer-input space: wes[h,k] = sum_d W[k,h*D+d]*a_s[h,d]
__global__ void fold_kernel(const float* __restrict__ W, const float* __restrict__ as_,
                            const float* __restrict__ ad_, float* __restrict__ wes,
                            float* __restrict__ wed, int K, int D){
  int gid = blockIdx.x * blockDim.x + threadIdx.x;
  if (gid >= 4 * K) return;
  int h = gid / K, k = gid - h * K;
  const float* wr = W + (size_t)k * (4 * D) + h * D;
  const float* sa = as_ + h * D;
  const float* da = ad_ + h * D;
  float ss = 0.f, sd = 0.f;
  for (int d = 0; d < D; d++){ float w = wr[d]; ss += w * sa[d]; sd += w * da[d]; }
  wes[h * K + k] = ss;
  wed[h * K + k] = sd;
}

// ====================== MFMA GEMM (split-bf16, 3 mfma) =====================
union PKU { uint32_t u[4]; bf16x8 v; };

static __device__ __forceinline__ void unpack_frag(const uint4 q0, const uint4 q1,
                                                   bf16x8& hi, bf16x8& lo){
  PKU H, L;
  H.u[0] = (q0.x & 0xFFFFu) | (q0.y << 16);
  H.u[1] = (q0.z & 0xFFFFu) | (q0.w << 16);
  H.u[2] = (q1.x & 0xFFFFu) | (q1.y << 16);
  H.u[3] = (q1.z & 0xFFFFu) | (q1.w << 16);
  L.u[0] = (q0.x >> 16) | (q0.y & 0xFFFF0000u);
  L.u[1] = (q0.z >> 16) | (q0.w & 0xFFFF0000u);
  L.u[2] = (q1.x >> 16) | (q1.y & 0xFFFF0000u);
  L.u[3] = (q1.z >> 16) | (q1.w & 0xFFFF0000u);
  hi = H.v; lo = L.v;
}

// C = A@W (L1/L2). Apk [Mp,K] packed, Wpk [Nout,K] packed. 128x128 tile.
__global__ __launch_bounds__(256) void gemm_mfma_kernel(
    const uint32_t* __restrict__ Apk, const uint32_t* __restrict__ Wpk,
    __half* __restrict__ Ch, float* __restrict__ Cf, int M, int K, int Nout)
{
  __shared__ uint32_t Asl[4096];   // [128 rows][32 k] u32, XOR-swizzled
  __shared__ uint32_t Bsl[4096];
  const int tid  = threadIdx.x;
  const int lane = tid & 63;
  const int wid  = tid >> 6;
  const int wm   = (wid >> 1) * 64;
  const int wn   = (wid & 1) * 64;
  const int bm   = blockIdx.x * 128;
  const int bn   = blockIdx.y * 128;
  const int srow = tid >> 3;
  const int skof = (tid & 7) * 4;
  const int fr   = lane & 15;
  const int kg   = (lane >> 4) * 8;

  f32x4 acc[4][4] = {};

  for (int kt = 0; kt < K; kt += 32){
    uint4 av[4], bv[4];
    #pragma unroll
    for (int it = 0; it < 4; it++){
      const int r = srow + it * 32;
      av[it] = *reinterpret_cast<const uint4*>(Apk + (size_t)(bm + r) * K + kt + skof);
      bv[it] = *reinterpret_cast<const uint4*>(Wpk + (size_t)(bn + r) * K + kt + skof);
    }
    __syncthreads();
    #pragma unroll
    for (int it = 0; it < 4; it++){
      const int r  = srow + it * 32;
      const int sw = (r * 32 + skof) ^ ((r & 7) << 2);
      *reinterpret_cast<uint4*>(&Asl[sw]) = av[it];
      *reinterpret_cast<uint4*>(&Bsl[sw]) = bv[it];
    }
    __syncthreads();

    bf16x8 Ah[4], Al[4];
    #pragma unroll
    for (int mf = 0; mf < 4; mf++){
      const int r  = wm + mf * 16 + fr;
      const int b  = r * 32 + kg;
      const int sx = (r & 7) << 2;
      const uint4 q0 = *reinterpret_cast<const uint4*>(&Asl[b ^ sx]);
      const uint4 q1 = *reinterpret_cast<const uint4*>(&Asl[(b + 4) ^ sx]);
      unpack_frag(q0, q1, Ah[mf], Al[mf]);
    }
    #pragma unroll
    for (int nf = 0; nf < 4; nf++){
      const int r  = wn + nf * 16 + fr;
      const int b  = r * 32 + kg;
      const int sx = (r & 7) << 2;
      const uint4 q0 = *reinterpret_cast<const uint4*>(&Bsl[b ^ sx]);
      const uint4 q1 = *reinterpret_cast<const uint4*>(&Bsl[(b + 4) ^ sx]);
      bf16x8 Bh, Bl;
      unpack_frag(q0, q1, Bh, Bl);
      #pragma unroll
      for (int mf = 0; mf < 4; mf++){
        acc[mf][nf] = __builtin_amdgcn_mfma_f32_16x16x32_bf16(Al[mf], Bh, acc[mf][nf], 0, 0, 0);
        acc[mf][nf] = __builtin_amdgcn_mfma_f32_16x16x32_bf16(Ah[mf], Bl, acc[mf][nf], 0, 0, 0);
        acc[mf][nf] = __builtin_amdgcn_mfma_f32_16x16x32_bf16(Ah[mf], Bh, acc[mf][nf], 0, 0, 0);
      }
    }
  }

  #pragma unroll
  for (int mf = 0; mf < 4; mf++){
    #pragma unroll
    for (int nf = 0; nf < 4; nf++){
      const int col = bn + wn + nf * 16 + fr;
      #pragma unroll
      for (int j = 0; j < 4; j++){
        const int row = bm + wm + mf * 16 + (lane >> 4) * 4 + j;
        if (row < M){
          const float v = acc[mf][nf][j];
          if (Ch) Ch[(size_t)row * Nout + col] = __float2half(v);
          if (Cf) Cf[(size_t)row * Nout + col] = v;
        }
      }
    }
  }
}

// ============== fp16-MFMA GEMM for the final z@W3r (K=512) ================
// C[M,128] = Zh[Mp,512] @ W3h[128,512]^T. BM=64, BN=128 (whole Nout), 4 waves,
// wave = 32x64, frags 2x4 of 16x16x32. LDS rows padded: stride 40 halfs.
__global__ __launch_bounds__(256) void gemm_f16_kernel(
    const __half* __restrict__ Zh, const __half* __restrict__ W3h,
    float* __restrict__ C, int M)
{
  constexpr int LDA = 40;            // halfs per LDS row (32 + 8 pad)
  __shared__ __half As[64 * LDA];
  __shared__ __half Bs[128 * LDA];
  const int tid  = threadIdx.x;
  const int lane = tid & 63;
  const int wid  = tid >> 6;
  const int wm   = (wid >> 1) * 32;
  const int wn   = (wid & 1) * 64;
  const int bm   = blockIdx.x * 64;
  const int fr   = lane & 15;
  const int kg   = (lane >> 4) * 8;
  const int arow = tid >> 2;         // 0..63
  const int akc  = (tid & 3) * 8;    // half-offset within 32-half k-tile

  f32x4 acc[2][4] = {};

  for (int kt = 0; kt < 512; kt += 32){
    const uint4 a  = *reinterpret_cast<const uint4*>(Zh  + (size_t)(bm + arow) * 512 + kt + akc);
    const uint4 b0 = *reinterpret_cast<const uint4*>(W3h + (size_t)arow        * 512 + kt + akc);
    const uint4 b1 = *reinterpret_cast<const uint4*>(W3h + (size_t)(arow + 64) * 512 + kt + akc);
    __syncthreads();
    *reinterpret_cast<uint4*>(&As[arow * LDA + akc])        = a;
    *reinterpret_cast<uint4*>(&Bs[arow * LDA + akc])        = b0;
    *reinterpret_cast<uint4*>(&Bs[(arow + 64) * LDA + akc]) = b1;
    __syncthreads();

    f16x8 af[2], bf[4];
    #pragma unroll
    for (int mf = 0; mf < 2; mf++)
      af[mf] = *reinterpret_cast<const f16x8*>(&As[(wm + mf * 16 + fr) * LDA + kg]);
    #pragma unroll
    for (int nf = 0; nf < 4; nf++)
      bf[nf] = *reinterpret_cast<const f16x8*>(&Bs[(wn + nf * 16 + fr) * LDA + kg]);
    #pragma unroll
    for (int mf = 0; mf < 2; mf++)
      #pragma unroll
      for (int nf = 0; nf < 4; nf++)
        acc[mf][nf] = __builtin_amdgcn_mfma_f32_16x16x32_f16(af[mf], bf[nf], acc[mf][nf], 0, 0, 0);
  }

  #pragma unroll
  for (int mf = 0; mf < 2; mf++){
    #pragma unroll
    for (int nf = 0; nf < 4; nf++){
      const int col = wn + nf * 16 + fr;
      #pragma unroll
      for (int j = 0; j < 4; j++){
        const int row = bm + wm + mf * 16 + (lane >> 4) * 4 + j;
        if (row < M) C[(size_t)row * 128 + col] = acc[mf][nf][j];
      }
    }
  }
}

// ================= attention coefs from folded weights =====================
template<int K>
__global__ __launch_bounds__(256) void attn_fold_kernel(
    const float* __restrict__ in, const float* __restrict__ wes, const float* __restrict__ wed,
    float* __restrict__ es, float* __restrict__ ed, int N)
{
  int gid = blockIdx.x * blockDim.x + threadIdx.x;
  int n = gid >> 2, h = gid & 3;
  if (n >= N) return;
  const float* ip = in + (size_t)n * K;
  const float* sp = wes + h * K;
  const float* dp = wed + h * K;
  float ss = 0.f, sd = 0.f;
  #pragma unroll
  for (int d = 0; d < K; d += 4){
    float4 hv = *reinterpret_cast<const float4*>(ip + d);
    float4 sv = *reinterpret_cast<const float4*>(sp + d);
    float4 dv = *reinterpret_cast<const float4*>(dp + d);
    ss += hv.x * sv.x + hv.y * sv.y + hv.z * sv.z + hv.w * sv.w;
    sd += hv.x * dv.x + hv.y * dv.y + hv.z * dv.z + hv.w * dv.w;
  }
  es[n * 4 + h] = ss;
  ed[n * 4 + h] = sd;
}

// ==================== aggregate: layers 1/2 (fp16 table, concat+ELU) =======
__global__ __launch_bounds__(256) void aggregate12_kernel(
    const int* __restrict__ row_start, const int* __restrict__ edge_src,
    const __half* __restrict__ hbuf, const float* __restrict__ es, const float* __restrict__ ed,
    float* __restrict__ out, __half* __restrict__ out16, int N)
{
  const int lane = threadIdx.x & 63;
  const int n = blockIdx.x * 4 + (threadIdx.x >> 6);
  if (n >= N) return;
  const int rs  = row_start[n];
  const int deg = row_start[n + 1] - rs;
  const float4 ed4 = *reinterpret_cast<const float4*>(&ed[n * 4]);
  const int sub  = lane >> 4;
  const int cl   = lane & 15;
  const int head = cl >> 2;
  float acc[8] = {0.f, 0.f, 0.f, 0.f, 0.f, 0.f, 0.f, 0.f};

  auto gather = [&](int cnt, int s_reg, float a0, float a1, float a2, float a3){
    for (int j = 0; j < cnt; j += 4){
      const int  el    = j + sub;
      const bool valid = el < cnt;
      const int  ei    = valid ? el : 0;
      const int  s     = __shfl(s_reg, ei);
      const float b0 = __shfl(a0, ei), b1 = __shfl(a1, ei);
      const float b2 = __shfl(a2, ei), b3 = __shfl(a3, ei);
      float al = head == 0 ? b0 : head == 1 ? b1 : head == 2 ? b2 : b3;
      if (!valid) al = 0.f;
      const uint4 raw = *reinterpret_cast<const uint4*>(hbuf + (size_t)s * 128 + cl * 8);
      const __half2* hp = reinterpret_cast<const __half2*>(&raw);
      #pragma unroll
      for (int q = 0; q < 4; q++){
        float2 f = __half22float2(hp[q]);
        acc[q * 2]     = fmaf(f.x, al, acc[q * 2]);
        acc[q * 2 + 1] = fmaf(f.y, al, acc[q * 2 + 1]);
      }
    }
  };

  if (deg <= 64){
    int   s_reg = 0;
    float e0 = -INFINITY, e1 = -INFINITY, e2 = -INFINITY, e3 = -INFINITY;
    if (lane < deg){
      s_reg = edge_src[rs + lane];
      const float4 e4 = *reinterpret_cast<const float4*>(&es[s_reg * 4]);
      e0 = lrelu(e4.x + ed4.x); e1 = lrelu(e4.y + ed4.y);
      e2 = lrelu(e4.z + ed4.z); e3 = lrelu(e4.w + ed4.w);
    }
    float mx0 = e0, mx1 = e1, mx2 = e2, mx3 = e3;
    #pragma unroll
    for (int off = 1; off < 64; off <<= 1){
      mx0 = fmaxf(mx0, __shfl_xor(mx0, off)); mx1 = fmaxf(mx1, __shfl_xor(mx1, off));
      mx2 = fmaxf(mx2, __shfl_xor(mx2, off)); mx3 = fmaxf(mx3, __shfl_xor(mx3, off));
    }
    float p0 = 0.f, p1 = 0.f, p2 = 0.f, p3 = 0.f;
    if (lane < deg){
      p0 = __expf(e0 - mx0); p1 = __expf(e1 - mx1);
      p2 = __expf(e2 - mx2); p3 = __expf(e3 - mx3);
    }
    float s0 = p0, s1 = p1, s2 = p2, s3 = p3;
    #pragma unroll
    for (int off = 1; off < 64; off <<= 1){
      s0 += __shfl_xor(s0, off); s1 += __shfl_xor(s1, off);
      s2 += __shfl_xor(s2, off); s3 += __shfl_xor(s3, off);
    }
    gather(deg, s_reg,
           p0 / (s0 + 1e-16f), p1 / (s1 + 1e-16f),
           p2 / (s2 + 1e-16f), p3 / (s3 + 1e-16f));
  } else {
    float mx0 = -INFINITY, mx1 = -INFINITY, mx2 = -INFINITY, mx3 = -INFINITY;
    for (int i = lane; i < deg; i += 64){
      int s = edge_src[rs + i];
      float4 e4 = *reinterpret_cast<const float4*>(&es[s * 4]);
      mx0 = fmaxf(mx0, lrelu(e4.x + ed4.x)); mx1 = fmaxf(mx1, lrelu(e4.y + ed4.y));
      mx2 = fmaxf(mx2, lrelu(e4.z + ed4.z)); mx3 = fmaxf(mx3, lrelu(e4.w + ed4.w));
    }
    #pragma unroll
    for (int off = 1; off < 64; off <<= 1){
      mx0 = fmaxf(mx0, __shfl_xor(mx0, off)); mx1 = fmaxf(mx1, __shfl_xor(mx1, off));
      mx2 = fmaxf(mx2, __shfl_xor(mx2, off)); mx3 = fmaxf(mx3, __shfl_xor(mx3, off));
    }
    float s0 = 0.f, s1 = 0.f, s2 = 0.f, s3 = 0.f;
    for (int i = lane; i < deg; i += 64){
      int s = edge_src[rs + i];
      float4 e4 = *reinterpret_cast<const float4*>(&es[s * 4]);
      s0 += __expf(lrelu(e4.x + ed4.x) - mx0); s1 += __expf(lrelu(e4.y + ed4.y) - mx1);
      s2 += __expf(lrelu(e4.z + ed4.z) - mx2); s3 += __expf(lrelu(e4.w + ed4.w) - mx3);
    }
    #pragma unroll
    for (int off = 1; off < 64; off <<= 1){
      s0 += __shfl_xor(s0, off); s1 += __shfl_xor(s1, off);
      s2 += __shfl_xor(s2, off); s3 += __shfl_xor(s3, off);
    }
    const float inv0 = 1.f / (s0 + 1e-16f), inv1 = 1.f / (s1 + 1e-16f);
    const float inv2 = 1.f / (s2 + 1e-16f), inv3 = 1.f / (s3 + 1e-16f);
    for (int base = 0; base < deg; base += 64){
      const int cnt = min(64, deg - base);
      int s_reg = 0; float a0 = 0.f, a1 = 0.f, a2 = 0.f, a3 = 0.f;
      if (lane < cnt){
        s_reg = edge_src[rs + base + lane];
        const float4 e4 = *reinterpret_cast<const float4*>(&es[s_reg * 4]);
        a0 = __expf(lrelu(e4.x + ed4.x) - mx0) * inv0;
        a1 = __expf(lrelu(e4.y + ed4.y) - mx1) * inv1;
        a2 = __expf(lrelu(e4.z + ed4.z) - mx2) * inv2;
        a3 = __expf(lrelu(e4.w + ed4.w) - mx3) * inv3;
      }
      gather(cnt, s_reg, a0, a1, a2, a3);
    }
  }

  #pragma unroll
  for (int q = 0; q < 8; q++){
    acc[q] += __shfl_xor(acc[q], 16);
    acc[q] += __shfl_xor(acc[q], 32);
  }
  if (lane < 16){
    const float o[8] = {elu_f(acc[0]), elu_f(acc[1]), elu_f(acc[2]), elu_f(acc[3]),
                        elu_f(acc[4]), elu_f(acc[5]), elu_f(acc[6]), elu_f(acc[7])};
    *reinterpret_cast<float4*>(&out[(size_t)n * 128 + lane * 8]) =
        make_float4(o[0], o[1], o[2], o[3]);
    *reinterpret_cast<float4*>(&out[(size_t)n * 128 + lane * 8 + 4]) =
        make_float4(o[4], o[5], o[6], o[7]);
    if (out16){
      union { __half2 h2[4]; uint4 u; } pk;
      pk.h2[0] = __floats2half2_rn(o[0], o[1]);
      pk.h2[1] = __floats2half2_rn(o[2], o[3]);
      pk.h2[2] = __floats2half2_rn(o[4], o[5]);
      pk.h2[3] = __floats2half2_rn(o[6], o[7]);
      *reinterpret_cast<uint4*>(&out16[(size_t)n * 128 + lane * 8]) = pk.u;
    }
  }
}

// ========= aggregate layer 3: gather actB16 -> z[N,4,128] fp16 =============
__global__ __launch_bounds__(256) void aggregate3_pack_kernel(
    const int* __restrict__ row_start, const int* __restrict__ edge_src,
    const __half* __restrict__ tbl, const float* __restrict__ es, const float* __restrict__ ed,
    __half* __restrict__ Zh, int N)
{
  const int lane = threadIdx.x & 63;
  const int n = blockIdx.x * 4 + (threadIdx.x >> 6);
  if (n >= N) return;
  const int rs  = row_start[n];
  const int deg = row_start[n + 1] - rs;
  const float4 ed4 = *reinterpret_cast<const float4*>(&ed[n * 4]);
  const int sub = lane >> 4;
  const int cl  = lane & 15;
  float acc[4][8] = {};

  auto gather = [&](int cnt, int s_reg, float a0, float a1, float a2, float a3){
    for (int j = 0; j < cnt; j += 4){
      const int  el    = j + sub;
      const bool valid = el < cnt;
      const int  ei    = valid ? el : 0;
      const int  s     = __shfl(s_reg, ei);
      float al[4];
      al[0] = __shfl(a0, ei); al[1] = __shfl(a1, ei);
      al[2] = __shfl(a2, ei); al[3] = __shfl(a3, ei);
      if (!valid){ al[0] = al[1] = al[2] = al[3] = 0.f; }
      const uint4 raw = *reinterpret_cast<const uint4*>(tbl + (size_t)s * 128 + cl * 8);
      const __half2* hp = reinterpret_cast<const __half2*>(&raw);
      float f[8];
      #pragma unroll
      for (int q = 0; q < 4; q++){
        float2 t = __half22float2(hp[q]);
        f[q * 2] = t.x; f[q * 2 + 1] = t.y;
      }
      #pragma unroll
      for (int h = 0; h < 4; h++)
        #pragma unroll
        for (int q = 0; q < 8; q++)
          acc[h][q] = fmaf(f[q], al[h], acc[h][q]);
    }
  };

  if (deg <= 64){
    int   s_reg = 0;
    float e0 = -INFINITY, e1 = -INFINITY, e2 = -INFINITY, e3 = -INFINITY;
    if (lane < deg){
      s_reg = edge_src[rs + lane];
      const float4 e4 = *reinterpret_cast<const float4*>(&es[s_reg * 4]);
      e0 = lrelu(e4.x + ed4.x); e1 = lrelu(e4.y + ed4.y);
      e2 = lrelu(e4.z + ed4.z); e3 = lrelu(e4.w + ed4.w);
    }
    float mx0 = e0, mx1 = e1, mx2 = e2, mx3 = e3;
    #pragma unroll
    for (int off = 1; off < 64; off <<= 1){
      mx0 = fmaxf(mx0, __shfl_xor(mx0, off)); mx1 = fmaxf(mx1, __shfl_xor(mx1, off));
      mx2 = fmaxf(mx2, __shfl_xor(mx2, off)); mx3 = fmaxf(mx3, __shfl_xor(mx3, off));
    }
    float p0 = 0.f, p1 = 0.f, p2 = 0.f, p3 = 0.f;
    if (lane < deg){
      p0 = __expf(e0 - mx0); p1 = __expf(e1 - mx1);
      p2 = __expf(e2 - mx2); p3 = __expf(e3 - mx3);
    }
    float s0 = p0, s1 = p1, s2 = p2, s3 = p3;
    #pragma unroll
    for (int off = 1; off < 64; off <<= 1){
      s0 += __shfl_xor(s0, off); s1 += __shfl_xor(s1, off);
      s2 += __shfl_xor(s2, off); s3 += __shfl_xor(s3, off);
    }
    gather(deg, s_reg,
           p0 / (s0 + 1e-16f), p1 / (s1 + 1e-16f),
           p2 / (s2 + 1e-16f), p3 / (s3 + 1e-16f));
  } else {
    float mx0 = -INFINITY, mx1 = -INFINITY, mx2 = -INFINITY, mx3 = -INFINITY;
    for (int i = lane; i < deg; i += 64){
      int s = edge_src[rs + i];
      float4 e4 = *reinterpret_cast<const float4*>(&es[s * 4]);
      mx0 = fmaxf(mx0, lrelu(e4.x + ed4.x)); mx1 = fmaxf(mx1, lrelu(e4.y + ed4.y));
      mx2 = fmaxf(mx2, lrelu(e4.z + ed4.z)); mx3 = fmaxf(mx3, lrelu(e4.w + ed4.w));
    }
    #pragma unroll
    for (int off = 1; off < 64; off <<= 1){
      mx0 = fmaxf(mx0, __shfl_xor(mx0, off)); mx1 = fmaxf(mx1, __shfl_xor(mx1, off));
      mx2 = fmaxf(mx2, __shfl_xor(mx2, off)); mx3 = fmaxf(mx3, __shfl_xor(mx3, off));
    }
    float s0 = 0.f, s1 = 0.f, s2 = 0.f, s3 = 0.f;
    for (int i = lane; i < deg; i += 64){
      int s = edge_src[rs + i];
      float4 e4 = *reinterpret_cast<const float4*>(&es[s * 4]);
      s0 += __expf(lrelu(e4.x + ed4.x) - mx0); s1 += __expf(lrelu(e4.y + ed4.y) - mx1);
      s2 += __expf(lrelu(e4.z + ed4.z) - mx2); s3 += __expf(lrelu(e4.w + ed4.w) - mx3);
    }
    #pragma unroll
    for (int off = 1; off < 64; off <<= 1){
      s0 += __shfl_xor(s0, off); s1 += __shfl_xor(s1, off);
      s2 += __shfl_xor(s2, off); s3 += __shfl_xor(s3, off);
    }
    const float inv0 = 1.f / (s0 + 1e-16f), inv1 = 1.f / (s1 + 1e-16f);
    const float inv2 = 1.f / (s2 + 1e-16f), inv3 = 1.f / (s3 + 1e-16f);
    for (int base = 0; base < deg; base += 64){
      const int cnt = min(64, deg - base);
      int s_reg = 0; float a0 = 0.f, a1 = 0.f, a2 = 0.f, a3 = 0.f;
      if (lane < cnt){
        s_reg = edge_src[rs + base + lane];
        const float4 e4 = *reinterpret_cast<const float4*>(&es[s_reg * 4]);
        a0 = __expf(lrelu(e4.x + ed4.x) - mx0) * inv0;
        a1 = __expf(lrelu(e4.y + ed4.y) - mx1) * inv1;
        a2 = __expf(lrelu(e4.z + ed4.z) - mx2) * inv2;
        a3 = __expf(lrelu(e4.w + ed4.w) - mx3) * inv3;
      }
      gather(cnt, s_reg, a0, a1, a2, a3);
    }
  }

  #pragma unroll
  for (int h = 0; h < 4; h++)
    #pragma unroll
    for (int q = 0; q < 8; q++){
      acc[h][q] += __shfl_xor(acc[h][q], 16);
      acc[h][q] += __shfl_xor(acc[h][q], 32);
    }
  if (lane < 16){
    #pragma unroll
    for (int h = 0; h < 4; h++){
      union { __half2 h2[4]; uint4 u; } pk;
      pk.h2[0] = __floats2half2_rn(acc[h][0], acc[h][1]);
      pk.h2[1] = __floats2half2_rn(acc[h][2], acc[h][3]);
      pk.h2[2] = __floats2half2_rn(acc[h][4], acc[h][5]);
      pk.h2[3] = __floats2half2_rn(acc[h][6], acc[h][7]);
      *reinterpret_cast<uint4*>(Zh + (size_t)n * 512 + h * 128 + cl * 8) = pk.u;
    }
  }
}

// =============================== driver ====================================
extern "C" void kernel_launch(void* const* d_in, const int* in_sizes, int n_in,
                              void* d_out, int out_size, void* d_ws, size_t ws_size,
                              hipStream_t stream) {
  const float* x   = (const float*)d_in[0];
  const int*   src = (const int*)  d_in[1];
  const int*   dst = (const int*)  d_in[2];
  const float* W1  = (const float*)d_in[3];
  const float* a1s = (const float*)d_in[4];
  const float* a1d = (const float*)d_in[5];
  const float* W2  = (const float*)d_in[6];
  const float* a2s = (const float*)d_in[7];
  const float* a2d = (const float*)d_in[8];
  const float* W3  = (const float*)d_in[9];
  const float* a3s = (const float*)d_in[10];
  const float* a3d = (const float*)d_in[11];

  const int N  = in_sizes[0] / 96;
  const int E  = in_sizes[1];
  const int Mp = (N + 127) & ~127;
  const int nb = (N + 1023) / 1024;

  char* ws = (char*)d_ws;
  auto alloc = [&](size_t bytes) -> void* {
    void* p = (void*)ws;
    ws += (bytes + 255) & ~(size_t)255;
    return p;
  };
  int*      row_start = (int*)     alloc((size_t)(N + 1) * 4);
  int*      cursor    = (int*)     alloc((size_t)N * 4);
  int*      blocksum  = (int*)     alloc((size_t)1024 * 4);
  int*      edge_src  = (int*)     alloc((size_t)E * 4);
  float*    es        = (float*)   alloc((size_t)N * 4 * 4);
  float*    ed        = (float*)   alloc((size_t)N * 4 * 4);
  float*    wes       = (float*)   alloc((size_t)4 * 128 * 4);
  float*    wed       = (float*)   alloc((size_t)4 * 128 * 4);
  __half*   hbufH     = (__half*)  alloc((size_t)N * 128 * 2);   // L1/L2 gather table
  float*    actA      = (float*)   alloc((size_t)N * 128 * 4);
  float*    actB      = (float*)   alloc((size_t)N * 128 * 4);
  __half*   actB16    = (__half*)  alloc((size_t)N * 128 * 2);   // L3 gather table
  __half*   Zh        = (__half*)  alloc((size_t)Mp * 512 * 2);  // fp16 z
  __half*   W3h       = (__half*)  alloc((size_t)128 * 512 * 2); // fp16 W3r
  uint32_t* Apk       = (uint32_t*)alloc((size_t)Mp * 128 * 4);  // packed A (L1/L2)
  uint32_t* Wpk       = (uint32_t*)alloc((size_t)128 * 128 * 4);

  // ---- CSR build ----
  zero_int_kernel<<<(N + 255) / 256, 256, 0, stream>>>(cursor, N);
  hist_kernel<<<(E + 255) / 256, 256, 0, stream>>>(dst, cursor, E);
  scan1_kernel<<<nb, 1024, 0, stream>>>(cursor, row_start, blocksum, N);
  scan2_kernel<<<1, 64, 0, stream>>>(blocksum, nb);
  scan3_kernel<<<(N + 255) / 256, 256, 0, stream>>>(row_start, blocksum, row_start, cursor, N, E);
  fill_kernel<<<(E + 255) / 256, 256, 0, stream>>>(src, dst, cursor, edge_src, E);
  sort_kernel<<<(N + 3) / 4, 256, 0, stream>>>(row_start, edge_src, N);

  const int aggGrid  = (N + 3) / 4;
  const int attnGrid = (N * 4 + 255) / 256;

  // ---- layer 1: [N,96] @ [96,128] ----
  fold_kernel<<<2, 256, 0, stream>>>(W1, a1s, a1d, wes, wed, 96, 32);
  split_pack_kernel<<<Mp, 96, 0, stream>>>(x, Apk, N, 96);
  split_pack_w_kernel<<<128, 96, 0, stream>>>(W1, Wpk, 96, 128);
  gemm_mfma_kernel<<<dim3(Mp / 128, 1), 256, 0, stream>>>(Apk, Wpk, hbufH, (float*)nullptr, N, 96, 128);
  attn_fold_kernel<96><<<attnGrid, 256, 0, stream>>>(x, wes, wed, es, ed, N);
  aggregate12_kernel<<<aggGrid, 256, 0, stream>>>(row_start, edge_src, hbufH, es, ed, actA, (__half*)nullptr, N);

  // ---- layer 2: [N,128] @ [128,128] ----
  fold_kernel<<<2, 256, 0, stream>>>(W2, a2s, a2d, wes, wed, 128, 32);
  split_pack_kernel<<<Mp, 128, 0, stream>>>(actA, Apk, N, 128);
  split_pack_w_kernel<<<128, 128, 0, stream>>>(W2, Wpk, 128, 128);
  gemm_mfma_kernel<<<dim3(Mp / 128, 1), 256, 0, stream>>>(Apk, Wpk, hbufH, (float*)nullptr, N, 128, 128);
  attn_fold_kernel<128><<<attnGrid, 256, 0, stream>>>(actA, wes, wed, es, ed, N);
  aggregate12_kernel<<<aggGrid, 256, 0, stream>>>(row_start, edge_src, hbufH, es, ed, actB, actB16, N);

  // ---- layer 3 (aggregate-then-transform, all fp16) ----
  fold_kernel<<<2, 256, 0, stream>>>(W3, a3s, a3d, wes, wed, 128, 128);
  attn_fold_kernel<128><<<attnGrid, 256, 0, stream>>>(actB, wes, wed, es, ed, N);
  aggregate3_pack_kernel<<<aggGrid, 256, 0, stream>>>(row_start, edge_src, actB16, es, ed, Zh, N);
  pack_w3r_h_kernel<<<128, 512, 0, stream>>>(W3, W3h);
  gemm_f16_kernel<<<Mp / 64, 256, 0, stream>>>(Zh, W3h, (float*)d_out, N);
}

// Round 8
// 494.576 us; speedup vs baseline: 1.6797x; 1.0591x over previous
//
#include <hip/hip_runtime.h>
#include <hip/hip_bf16.h>
#include <hip/hip_fp16.h>
#include <cstddef>
#include <stdint.h>
#include <math.h>

// ---------------------------------------------------------------------------
// GAT 3-layer forward on MI355X.
//   CSR: zero -> hist -> 3-kernel parallel scan -> fill -> wave bitonic sort
//   L1/L2: split-bf16 MFMA GEMM (fp32 A packed in-register, fp16 table out)
//          -> folded attn coefs -> fused softmax + 4-deep batched fp16 gather
//   L3 (algebraic swap): folded attn -> gather actB16 -> z[N,4,128] fp16
//          -> one fp16-MFMA GEMM z@W3r -> d_out
// ---------------------------------------------------------------------------

static __device__ __forceinline__ float lrelu(float x){ return x > 0.f ? x : 0.2f * x; }
static __device__ __forceinline__ float elu_f(float x){ return x > 0.f ? x : expm1f(x); }

typedef __bf16    bf16x8 __attribute__((ext_vector_type(8)));
typedef _Float16  f16x8  __attribute__((ext_vector_type(8)));
typedef float     f32x4  __attribute__((ext_vector_type(4)));

// ============================ CSR build ====================================
__global__ void zero_int_kernel(int* __restrict__ p, int n){
  int i = blockIdx.x * blockDim.x + threadIdx.x;
  if (i < n) p[i] = 0;
}

__global__ void hist_kernel(const int* __restrict__ dst, int* __restrict__ deg, int E){
  int e = blockIdx.x * blockDim.x + threadIdx.x;
  if (e < E) atomicAdd(&deg[dst[e]], 1);
}

__global__ __launch_bounds__(1024) void scan1_kernel(const int* __restrict__ deg,
    int* __restrict__ partial, int* __restrict__ blocksum, int N){
  __shared__ int wsum[16];
  const int tid = threadIdx.x, lane = tid & 63, wid = tid >> 6;
  const int i = blockIdx.x * 1024 + tid;
  int v = (i < N) ? deg[i] : 0;
  int incl = v;
  #pragma unroll
  for (int off = 1; off < 64; off <<= 1){
    int t = __shfl_up(incl, off);
    if (lane >= off) incl += t;
  }
  if (lane == 63) wsum[wid] = incl;
  __syncthreads();
  if (tid == 0){
    int run = 0;
    #pragma unroll
    for (int w = 0; w < 16; w++){ int t = wsum[w]; wsum[w] = run; run += t; }
    blocksum[blockIdx.x] = run;
  }
  __syncthreads();
  if (i < N) partial[i] = wsum[wid] + incl - v;
}

__global__ void scan2_kernel(int* __restrict__ blocksum, int nb){
  const int lane = threadIdx.x;
  int v = (lane < nb) ? blocksum[lane] : 0;
  int incl = v;
  #pragma unroll
  for (int off = 1; off < 64; off <<= 1){
    int t = __shfl_up(incl, off);
    if (lane >= off) incl += t;
  }
  if (lane < nb) blocksum[lane] = incl - v;
}

__global__ void scan3_kernel(const int* __restrict__ partial, const int* __restrict__ blocksum,
    int* __restrict__ row_start, int* __restrict__ cursor, int N, int E){
  const int i = blockIdx.x * blockDim.x + threadIdx.x;
  if (i < N){
    const int r = partial[i] + blocksum[i >> 10];
    row_start[i] = r;
    cursor[i] = r;
  }
  if (i == 0) row_start[N] = E;
}

__global__ void fill_kernel(const int* __restrict__ src, const int* __restrict__ dst,
    int* __restrict__ cursor, int* __restrict__ edge_src, int E){
  int e = blockIdx.x * blockDim.x + threadIdx.x;
  if (e < E){
    int p = atomicAdd(&cursor[dst[e]], 1);
    edge_src[p] = src[e];
  }
}

// deterministic order: ascending srcs. Wave bitonic for deg<=64 (the norm).
__global__ __launch_bounds__(256) void sort_kernel(
    const int* __restrict__ row_start, int* __restrict__ edge_src, int N){
  const int lane = threadIdx.x & 63;
  const int n = blockIdx.x * 4 + (threadIdx.x >> 6);
  if (n >= N) return;
  const int rs = row_start[n], deg = row_start[n + 1] - rs;
  if (deg <= 1) return;
  if (deg <= 64){
    int v = (lane < deg) ? edge_src[rs + lane] : 0x7FFFFFFF;
    #pragma unroll
    for (int k = 2; k <= 64; k <<= 1){
      #pragma unroll
      for (int j = k >> 1; j >= 1; j >>= 1){
        int partner = __shfl_xor(v, j);
        const bool up = ((lane & k) == 0);
        const bool keepmin = (((lane & j) == 0) == up);
        v = keepmin ? min(v, partner) : max(v, partner);
      }
    }
    if (lane < deg) edge_src[rs + lane] = v;
  } else if (lane == 0){
    for (int i = rs + 1; i < rs + deg; i++){
      int key = edge_src[i];
      int j = i - 1;
      while (j >= rs && edge_src[j] > key){ edge_src[j + 1] = edge_src[j]; j--; }
      edge_src[j + 1] = key;
    }
  }
}

// ====================== split-bf16 packing =================================
static __device__ __forceinline__ uint32_t pack_hi_lo(float a){
  uint32_t u  = __float_as_uint(a);
  uint32_t hb = (u + 0x7FFFu + ((u >> 16) & 1u)) & 0xFFFF0000u;  // bf16 RNE of a
  float lof   = a - __uint_as_float(hb);
  uint32_t ul = __float_as_uint(lof);
  uint32_t lb = (ul + 0x7FFFu + ((ul >> 16) & 1u)) >> 16;        // bf16 RNE of residual
  return (hb >> 16) | (lb << 16);
}

__global__ void split_pack_w_kernel(const float* __restrict__ W, uint32_t* __restrict__ P,
                                    int K, int N){
  const int n = blockIdx.x;
  const int k = threadIdx.x;
  P[(size_t)n * K + k] = pack_hi_lo(W[(size_t)k * N + n]);
}

// W3 reordered+transposed fp16, 0.25 head-mean folded.
__global__ void pack_w3r_h_kernel(const float* __restrict__ W3, __half* __restrict__ P){
  const int nout = blockIdx.x;
  const int kk   = threadIdx.x;
  const int h = kk >> 7, k = kk & 127;
  P[(size_t)nout * 512 + kk] = __float2half(0.25f * W3[(size_t)k * 512 + h * 128 + nout]);
}

// fold attention vectors into layer-input space: wes[h,k] = sum_d W[k,h*D+d]*a_s[h,d]
__global__ void fold_kernel(const float* __restrict__ W, const float* __restrict__ as_,
                            const float* __restrict__ ad_, float* __restrict__ wes,
                            float* __restrict__ wed, int K, int D){
  int gid = blockIdx.x * blockDim.x + threadIdx.x;
  if (gid >= 4 * K) return;
  int h = gid / K, k = gid - h * K;
  const float* wr = W + (size_t)k * (4 * D) + h * D;
  const float* sa = as_ + h * D;
  const float* da = ad_ + h * D;
  float ss = 0.f, sd = 0.f;
  for (int d = 0; d < D; d++){ float w = wr[d]; ss += w * sa[d]; sd += w * da[d]; }
  wes[h * K + k] = ss;
  wed[h * K + k] = sd;
}

// ====================== MFMA GEMM (split-bf16, 3 mfma) =====================
union PKU { uint32_t u[4]; bf16x8 v; };

static __device__ __forceinline__ void unpack_frag(const uint4 q0, const uint4 q1,
                                                   bf16x8& hi, bf16x8& lo){
  PKU H, L;
  H.u[0] = (q0.x & 0xFFFFu) | (q0.y << 16);
  H.u[1] = (q0.z & 0xFFFFu) | (q0.w << 16);
  H.u[2] = (q1.x & 0xFFFFu) | (q1.y << 16);
  H.u[3] = (q1.z & 0xFFFFu) | (q1.w << 16);
  L.u[0] = (q0.x >> 16) | (q0.y & 0xFFFF0000u);
  L.u[1] = (q0.z >> 16) | (q0.w & 0xFFFF0000u);
  L.u[2] = (q1.x >> 16) | (q1.y & 0xFFFF0000u);
  L.u[3] = (q1.z >> 16) | (q1.w & 0xFFFF0000u);
  hi = H.v; lo = L.v;
}

// C = A@W (L1/L2). A fp32 [M,K] (packed in-register), Wpk [Nout,K] packed.
// 128x128 tile, 4 waves 2x2, each wave 64x64 via 4x4 frags of 16x16x32.
__global__ __launch_bounds__(256) void gemm_mfma_kernel(
    const float* __restrict__ A, const uint32_t* __restrict__ Wpk,
    __half* __restrict__ Ch, float* __restrict__ Cf, int M, int K, int Nout)
{
  __shared__ uint32_t Asl[4096];   // [128 rows][32 k] u32, XOR-swizzled
  __shared__ uint32_t Bsl[4096];
  const int tid  = threadIdx.x;
  const int lane = tid & 63;
  const int wid  = tid >> 6;
  const int wm   = (wid >> 1) * 64;
  const int wn   = (wid & 1) * 64;
  const int bm   = blockIdx.x * 128;
  const int bn   = blockIdx.y * 128;
  const int srow = tid >> 3;
  const int skof = (tid & 7) * 4;
  const int fr   = lane & 15;
  const int kg   = (lane >> 4) * 8;

  f32x4 acc[4][4] = {};

  for (int kt = 0; kt < K; kt += 32){
    float4 av[4]; uint4 bv[4];
    #pragma unroll
    for (int it = 0; it < 4; it++){
      const int r = srow + it * 32;
      av[it] = (bm + r < M)
          ? *reinterpret_cast<const float4*>(A + (size_t)(bm + r) * K + kt + skof)
          : make_float4(0.f, 0.f, 0.f, 0.f);
      bv[it] = *reinterpret_cast<const uint4*>(Wpk + (size_t)(bn + r) * K + kt + skof);
    }
    __syncthreads();
    #pragma unroll
    for (int it = 0; it < 4; it++){
      const int r  = srow + it * 32;
      const int sw = (r * 32 + skof) ^ ((r & 7) << 2);
      uint4 pv;
      pv.x = pack_hi_lo(av[it].x); pv.y = pack_hi_lo(av[it].y);
      pv.z = pack_hi_lo(av[it].z); pv.w = pack_hi_lo(av[it].w);
      *reinterpret_cast<uint4*>(&Asl[sw]) = pv;
      *reinterpret_cast<uint4*>(&Bsl[sw]) = bv[it];
    }
    __syncthreads();

    bf16x8 Ah[4], Al[4];
    #pragma unroll
    for (int mf = 0; mf < 4; mf++){
      const int r  = wm + mf * 16 + fr;
      const int b  = r * 32 + kg;
      const int sx = (r & 7) << 2;
      const uint4 q0 = *reinterpret_cast<const uint4*>(&Asl[b ^ sx]);
      const uint4 q1 = *reinterpret_cast<const uint4*>(&Asl[(b + 4) ^ sx]);
      unpack_frag(q0, q1, Ah[mf], Al[mf]);
    }
    #pragma unroll
    for (int nf = 0; nf < 4; nf++){
      const int r  = wn + nf * 16 + fr;
      const int b  = r * 32 + kg;
      const int sx = (r & 7) << 2;
      const uint4 q0 = *reinterpret_cast<const uint4*>(&Bsl[b ^ sx]);
      const uint4 q1 = *reinterpret_cast<const uint4*>(&Bsl[(b + 4) ^ sx]);
      bf16x8 Bh, Bl;
      unpack_frag(q0, q1, Bh, Bl);
      #pragma unroll
      for (int mf = 0; mf < 4; mf++){
        acc[mf][nf] = __builtin_amdgcn_mfma_f32_16x16x32_bf16(Al[mf], Bh, acc[mf][nf], 0, 0, 0);
        acc[mf][nf] = __builtin_amdgcn_mfma_f32_16x16x32_bf16(Ah[mf], Bl, acc[mf][nf], 0, 0, 0);
        acc[mf][nf] = __builtin_amdgcn_mfma_f32_16x16x32_bf16(Ah[mf], Bh, acc[mf][nf], 0, 0, 0);
      }
    }
  }

  #pragma unroll
  for (int mf = 0; mf < 4; mf++){
    #pragma unroll
    for (int nf = 0; nf < 4; nf++){
      const int col = bn + wn + nf * 16 + fr;
      #pragma unroll
      for (int j = 0; j < 4; j++){
        const int row = bm + wm + mf * 16 + (lane >> 4) * 4 + j;
        if (row < M){
          const float v = acc[mf][nf][j];
          if (Ch) Ch[(size_t)row * Nout + col] = __float2half(v);
          if (Cf) Cf[(size_t)row * Nout + col] = v;
        }
      }
    }
  }
}

// ============== fp16-MFMA GEMM for the final z@W3r (K=512) ================
__global__ __launch_bounds__(256) void gemm_f16_kernel(
    const __half* __restrict__ Zh, const __half* __restrict__ W3h,
    float* __restrict__ C, int M)
{
  constexpr int LDA = 40;
  __shared__ __half As[64 * LDA];
  __shared__ __half Bs[128 * LDA];
  const int tid  = threadIdx.x;
  const int lane = tid & 63;
  const int wid  = tid >> 6;
  const int wm   = (wid >> 1) * 32;
  const int wn   = (wid & 1) * 64;
  const int bm   = blockIdx.x * 64;
  const int fr   = lane & 15;
  const int kg   = (lane >> 4) * 8;
  const int arow = tid >> 2;
  const int akc  = (tid & 3) * 8;

  f32x4 acc[2][4] = {};

  for (int kt = 0; kt < 512; kt += 32){
    const uint4 a  = *reinterpret_cast<const uint4*>(Zh  + (size_t)(bm + arow) * 512 + kt + akc);
    const uint4 b0 = *reinterpret_cast<const uint4*>(W3h + (size_t)arow        * 512 + kt + akc);
    const uint4 b1 = *reinterpret_cast<const uint4*>(W3h + (size_t)(arow + 64) * 512 + kt + akc);
    __syncthreads();
    *reinterpret_cast<uint4*>(&As[arow * LDA + akc])        = a;
    *reinterpret_cast<uint4*>(&Bs[arow * LDA + akc])        = b0;
    *reinterpret_cast<uint4*>(&Bs[(arow + 64) * LDA + akc]) = b1;
    __syncthreads();

    f16x8 af[2], bf[4];
    #pragma unroll
    for (int mf = 0; mf < 2; mf++)
      af[mf] = *reinterpret_cast<const f16x8*>(&As[(wm + mf * 16 + fr) * LDA + kg]);
    #pragma unroll
    for (int nf = 0; nf < 4; nf++)
      bf[nf] = *reinterpret_cast<const f16x8*>(&Bs[(wn + nf * 16 + fr) * LDA + kg]);
    #pragma unroll
    for (int mf = 0; mf < 2; mf++)
      #pragma unroll
      for (int nf = 0; nf < 4; nf++)
        acc[mf][nf] = __builtin_amdgcn_mfma_f32_16x16x32_f16(af[mf], bf[nf], acc[mf][nf], 0, 0, 0);
  }

  #pragma unroll
  for (int mf = 0; mf < 2; mf++){
    #pragma unroll
    for (int nf = 0; nf < 4; nf++){
      const int col = wn + nf * 16 + fr;
      #pragma unroll
      for (int j = 0; j < 4; j++){
        const int row = bm + wm + mf * 16 + (lane >> 4) * 4 + j;
        if (row < M) C[(size_t)row * 128 + col] = acc[mf][nf][j];
      }
    }
  }
}

// ================= attention coefs from folded weights =====================
template<int K>
__global__ __launch_bounds__(256) void attn_fold_kernel(
    const float* __restrict__ in, const float* __restrict__ wes, const float* __restrict__ wed,
    float* __restrict__ es, float* __restrict__ ed, int N)
{
  int gid = blockIdx.x * blockDim.x + threadIdx.x;
  int n = gid >> 2, h = gid & 3;
  if (n >= N) return;
  const float* ip = in + (size_t)n * K;
  const float* sp = wes + h * K;
  const float* dp = wed + h * K;
  float ss = 0.f, sd = 0.f;
  #pragma unroll
  for (int d = 0; d < K; d += 4){
    float4 hv = *reinterpret_cast<const float4*>(ip + d);
    float4 sv = *reinterpret_cast<const float4*>(sp + d);
    float4 dv = *reinterpret_cast<const float4*>(dp + d);
    ss += hv.x * sv.x + hv.y * sv.y + hv.z * sv.z + hv.w * sv.w;
    sd += hv.x * dv.x + hv.y * dv.y + hv.z * dv.z + hv.w * dv.w;
  }
  es[n * 4 + h] = ss;
  ed[n * 4 + h] = sd;
}

// ==================== aggregate: layers 1/2 (fp16 table, concat+ELU) =======
// 4-deep batched gather: 16 edges per outer iter, 4 uint4 loads in flight.
__global__ __launch_bounds__(256) void aggregate12_kernel(
    const int* __restrict__ row_start, const int* __restrict__ edge_src,
    const __half* __restrict__ hbuf, const float* __restrict__ es, const float* __restrict__ ed,
    float* __restrict__ out, __half* __restrict__ out16, int N)
{
  const int lane = threadIdx.x & 63;
  const int n = blockIdx.x * 4 + (threadIdx.x >> 6);
  if (n >= N) return;
  const int rs  = row_start[n];
  const int deg = row_start[n + 1] - rs;
  const float4 ed4 = *reinterpret_cast<const float4*>(&ed[n * 4]);
  const int sub  = lane >> 4;
  const int cl   = lane & 15;
  const int head = cl >> 2;
  float acc[8] = {0.f, 0.f, 0.f, 0.f, 0.f, 0.f, 0.f, 0.f};

  auto gather = [&](int cnt, int s_reg, float a0, float a1, float a2, float a3){
    for (int j = 0; j < cnt; j += 16){
      uint4 raw[4]; float alv[4];
      #pragma unroll
      for (int t = 0; t < 4; t++){
        const int  el    = j + t * 4 + sub;
        const bool valid = el < cnt;
        const int  ei    = valid ? el : 0;
        const int  s     = __shfl(s_reg, ei);
        const float b0 = __shfl(a0, ei), b1 = __shfl(a1, ei);
        const float b2 = __shfl(a2, ei), b3 = __shfl(a3, ei);
        float al = head == 0 ? b0 : head == 1 ? b1 : head == 2 ? b2 : b3;
        alv[t] = valid ? al : 0.f;
        raw[t] = *reinterpret_cast<const uint4*>(hbuf + (size_t)s * 128 + cl * 8);
      }
      #pragma unroll
      for (int t = 0; t < 4; t++){
        const __half2* hp = reinterpret_cast<const __half2*>(&raw[t]);
        #pragma unroll
        for (int q = 0; q < 4; q++){
          float2 f = __half22float2(hp[q]);
          acc[q * 2]     = fmaf(f.x, alv[t], acc[q * 2]);
          acc[q * 2 + 1] = fmaf(f.y, alv[t], acc[q * 2 + 1]);
        }
      }
    }
  };

  if (deg <= 64){
    int   s_reg = 0;
    float e0 = -INFINITY, e1 = -INFINITY, e2 = -INFINITY, e3 = -INFINITY;
    if (lane < deg){
      s_reg = edge_src[rs + lane];
      const float4 e4 = *reinterpret_cast<const float4*>(&es[s_reg * 4]);
      e0 = lrelu(e4.x + ed4.x); e1 = lrelu(e4.y + ed4.y);
      e2 = lrelu(e4.z + ed4.z); e3 = lrelu(e4.w + ed4.w);
    }
    float mx0 = e0, mx1 = e1, mx2 = e2, mx3 = e3;
    #pragma unroll
    for (int off = 1; off < 64; off <<= 1){
      mx0 = fmaxf(mx0, __shfl_xor(mx0, off)); mx1 = fmaxf(mx1, __shfl_xor(mx1, off));
      mx2 = fmaxf(mx2, __shfl_xor(mx2, off)); mx3 = fmaxf(mx3, __shfl_xor(mx3, off));
    }
    float p0 = 0.f, p1 = 0.f, p2 = 0.f, p3 = 0.f;
    if (lane < deg){
      p0 = __expf(e0 - mx0); p1 = __expf(e1 - mx1);
      p2 = __expf(e2 - mx2); p3 = __expf(e3 - mx3);
    }
    float s0 = p0, s1 = p1, s2 = p2, s3 = p3;
    #pragma unroll
    for (int off = 1; off < 64; off <<= 1){
      s0 += __shfl_xor(s0, off); s1 += __shfl_xor(s1, off);
      s2 += __shfl_xor(s2, off); s3 += __shfl_xor(s3, off);
    }
    gather(deg, s_reg,
           p0 / (s0 + 1e-16f), p1 / (s1 + 1e-16f),
           p2 / (s2 + 1e-16f), p3 / (s3 + 1e-16f));
  } else {
    float mx0 = -INFINITY, mx1 = -INFINITY, mx2 = -INFINITY, mx3 = -INFINITY;
    for (int i = lane; i < deg; i += 64){
      int s = edge_src[rs + i];
      float4 e4 = *reinterpret_cast<const float4*>(&es[s * 4]);
      mx0 = fmaxf(mx0, lrelu(e4.x + ed4.x)); mx1 = fmaxf(mx1, lrelu(e4.y + ed4.y));
      mx2 = fmaxf(mx2, lrelu(e4.z + ed4.z)); mx3 = fmaxf(mx3, lrelu(e4.w + ed4.w));
    }
    #pragma unroll
    for (int off = 1; off < 64; off <<= 1){
      mx0 = fmaxf(mx0, __shfl_xor(mx0, off)); mx1 = fmaxf(mx1, __shfl_xor(mx1, off));
      mx2 = fmaxf(mx2, __shfl_xor(mx2, off)); mx3 = fmaxf(mx3, __shfl_xor(mx3, off));
    }
    float s0 = 0.f, s1 = 0.f, s2 = 0.f, s3 = 0.f;
    for (int i = lane; i < deg; i += 64){
      int s = edge_src[rs + i];
      float4 e4 = *reinterpret_cast<const float4*>(&es[s * 4]);
      s0 += __expf(lrelu(e4.x + ed4.x) - mx0); s1 += __expf(lrelu(e4.y + ed4.y) - mx1);
      s2 += __expf(lrelu(e4.z + ed4.z) - mx2); s3 += __expf(lrelu(e4.w + ed4.w) - mx3);
    }
    #pragma unroll
    for (int off = 1; off < 64; off <<= 1){
      s0 += __shfl_xor(s0, off); s1 += __shfl_xor(s1, off);
      s2 += __shfl_xor(s2, off); s3 += __shfl_xor(s3, off);
    }
    const float inv0 = 1.f / (s0 + 1e-16f), inv1 = 1.f / (s1 + 1e-16f);
    const float inv2 = 1.f / (s2 + 1e-16f), inv3 = 1.f / (s3 + 1e-16f);
    for (int base = 0; base < deg; base += 64){
      const int cnt = min(64, deg - base);
      int s_reg = 0; float a0 = 0.f, a1 = 0.f, a2 = 0.f, a3 = 0.f;
      if (lane < cnt){
        s_reg = edge_src[rs + base + lane];
        const float4 e4 = *reinterpret_cast<const float4*>(&es[s_reg * 4]);
        a0 = __expf(lrelu(e4.x + ed4.x) - mx0) * inv0;
        a1 = __expf(lrelu(e4.y + ed4.y) - mx1) * inv1;
        a2 = __expf(lrelu(e4.z + ed4.z) - mx2) * inv2;
        a3 = __expf(lrelu(e4.w + ed4.w) - mx3) * inv3;
      }
      gather(cnt, s_reg, a0, a1, a2, a3);
    }
  }

  #pragma unroll
  for (int q = 0; q < 8; q++){
    acc[q] += __shfl_xor(acc[q], 16);
    acc[q] += __shfl_xor(acc[q], 32);
  }
  if (lane < 16){
    const float o[8] = {elu_f(acc[0]), elu_f(acc[1]), elu_f(acc[2]), elu_f(acc[3]),
                        elu_f(acc[4]), elu_f(acc[5]), elu_f(acc[6]), elu_f(acc[7])};
    *reinterpret_cast<float4*>(&out[(size_t)n * 128 + lane * 8]) =
        make_float4(o[0], o[1], o[2], o[3]);
    *reinterpret_cast<float4*>(&out[(size_t)n * 128 + lane * 8 + 4]) =
        make_float4(o[4], o[5], o[6], o[7]);
    if (out16){
      union { __half2 h2[4]; uint4 u; } pk;
      pk.h2[0] = __floats2half2_rn(o[0], o[1]);
      pk.h2[1] = __floats2half2_rn(o[2], o[3]);
      pk.h2[2] = __floats2half2_rn(o[4], o[5]);
      pk.h2[3] = __floats2half2_rn(o[6], o[7]);
      *reinterpret_cast<uint4*>(&out16[(size_t)n * 128 + lane * 8]) = pk.u;
    }
  }
}

// ========= aggregate layer 3: gather actB16 -> z[N,4,128] fp16 =============
__global__ __launch_bounds__(256) void aggregate3_pack_kernel(
    const int* __restrict__ row_start, const int* __restrict__ edge_src,
    const __half* __restrict__ tbl, const float* __restrict__ es, const float* __restrict__ ed,
    __half* __restrict__ Zh, int N)
{
  const int lane = threadIdx.x & 63;
  const int n = blockIdx.x * 4 + (threadIdx.x >> 6);
  if (n >= N) return;
  const int rs  = row_start[n];
  const int deg = row_start[n + 1] - rs;
  const float4 ed4 = *reinterpret_cast<const float4*>(&ed[n * 4]);
  const int sub = lane >> 4;
  const int cl  = lane & 15;
  float acc[4][8] = {};

  auto gather = [&](int cnt, int s_reg, float a0, float a1, float a2, float a3){
    for (int j = 0; j < cnt; j += 16){
      uint4 raw[4]; float alv[4][4];
      #pragma unroll
      for (int t = 0; t < 4; t++){
        const int  el    = j + t * 4 + sub;
        const bool valid = el < cnt;
        const int  ei    = valid ? el : 0;
        const int  s     = __shfl(s_reg, ei);
        const float b0 = __shfl(a0, ei), b1 = __shfl(a1, ei);
        const float b2 = __shfl(a2, ei), b3 = __shfl(a3, ei);
        alv[t][0] = valid ? b0 : 0.f; alv[t][1] = valid ? b1 : 0.f;
        alv[t][2] = valid ? b2 : 0.f; alv[t][3] = valid ? b3 : 0.f;
        raw[t] = *reinterpret_cast<const uint4*>(tbl + (size_t)s * 128 + cl * 8);
      }
      #pragma unroll
      for (int t = 0; t < 4; t++){
        const __half2* hp = reinterpret_cast<const __half2*>(&raw[t]);
        float f[8];
        #pragma unroll
        for (int q = 0; q < 4; q++){
          float2 v = __half22float2(hp[q]);
          f[q * 2] = v.x; f[q * 2 + 1] = v.y;
        }
        #pragma unroll
        for (int h = 0; h < 4; h++)
          #pragma unroll
          for (int q = 0; q < 8; q++)
            acc[h][q] = fmaf(f[q], alv[t][h], acc[h][q]);
      }
    }
  };

  if (deg <= 64){
    int   s_reg = 0;
    float e0 = -INFINITY, e1 = -INFINITY, e2 = -INFINITY, e3 = -INFINITY;
    if (lane < deg){
      s_reg = edge_src[rs + lane];
      const float4 e4 = *reinterpret_cast<const float4*>(&es[s_reg * 4]);
      e0 = lrelu(e4.x + ed4.x); e1 = lrelu(e4.y + ed4.y);
      e2 = lrelu(e4.z + ed4.z); e3 = lrelu(e4.w + ed4.w);
    }
    float mx0 = e0, mx1 = e1, mx2 = e2, mx3 = e3;
    #pragma unroll
    for (int off = 1; off < 64; off <<= 1){
      mx0 = fmaxf(mx0, __shfl_xor(mx0, off)); mx1 = fmaxf(mx1, __shfl_xor(mx1, off));
      mx2 = fmaxf(mx2, __shfl_xor(mx2, off)); mx3 = fmaxf(mx3, __shfl_xor(mx3, off));
    }
    float p0 = 0.f, p1 = 0.f, p2 = 0.f, p3 = 0.f;
    if (lane < deg){
      p0 = __expf(e0 - mx0); p1 = __expf(e1 - mx1);
      p2 = __expf(e2 - mx2); p3 = __expf(e3 - mx3);
    }
    float s0 = p0, s1 = p1, s2 = p2, s3 = p3;
    #pragma unroll
    for (int off = 1; off < 64; off <<= 1){
      s0 += __shfl_xor(s0, off); s1 += __shfl_xor(s1, off);
      s2 += __shfl_xor(s2, off); s3 += __shfl_xor(s3, off);
    }
    gather(deg, s_reg,
           p0 / (s0 + 1e-16f), p1 / (s1 + 1e-16f),
           p2 / (s2 + 1e-16f), p3 / (s3 + 1e-16f));
  } else {
    float mx0 = -INFINITY, mx1 = -INFINITY, mx2 = -INFINITY, mx3 = -INFINITY;
    for (int i = lane; i < deg; i += 64){
      int s = edge_src[rs + i];
      float4 e4 = *reinterpret_cast<const float4*>(&es[s * 4]);
      mx0 = fmaxf(mx0, lrelu(e4.x + ed4.x)); mx1 = fmaxf(mx1, lrelu(e4.y + ed4.y));
      mx2 = fmaxf(mx2, lrelu(e4.z + ed4.z)); mx3 = fmaxf(mx3, lrelu(e4.w + ed4.w));
    }
    #pragma unroll
    for (int off = 1; off < 64; off <<= 1){
      mx0 = fmaxf(mx0, __shfl_xor(mx0, off)); mx1 = fmaxf(mx1, __shfl_xor(mx1, off));
      mx2 = fmaxf(mx2, __shfl_xor(mx2, off)); mx3 = fmaxf(mx3, __shfl_xor(mx3, off));
    }
    float s0 = 0.f, s1 = 0.f, s2 = 0.f, s3 = 0.f;
    for (int i = lane; i < deg; i += 64){
      int s = edge_src[rs + i];
      float4 e4 = *reinterpret_cast<const float4*>(&es[s * 4]);
      s0 += __expf(lrelu(e4.x + ed4.x) - mx0); s1 += __expf(lrelu(e4.y + ed4.y) - mx1);
      s2 += __expf(lrelu(e4.z + ed4.z) - mx2); s3 += __expf(lrelu(e4.w + ed4.w) - mx3);
    }
    #pragma unroll
    for (int off = 1; off < 64; off <<= 1){
      s0 += __shfl_xor(s0, off); s1 += __shfl_xor(s1, off);
      s2 += __shfl_xor(s2, off); s3 += __shfl_xor(s3, off);
    }
    const float inv0 = 1.f / (s0 + 1e-16f), inv1 = 1.f / (s1 + 1e-16f);
    const float inv2 = 1.f / (s2 + 1e-16f), inv3 = 1.f / (s3 + 1e-16f);
    for (int base = 0; base < deg; base += 64){
      const int cnt = min(64, deg - base);
      int s_reg = 0; float a0 = 0.f, a1 = 0.f, a2 = 0.f, a3 = 0.f;
      if (lane < cnt){
        s_reg = edge_src[rs + base + lane];
        const float4 e4 = *reinterpret_cast<const float4*>(&es[s_reg * 4]);
        a0 = __expf(lrelu(e4.x + ed4.x) - mx0) * inv0;
        a1 = __expf(lrelu(e4.y + ed4.y) - mx1) * inv1;
        a2 = __expf(lrelu(e4.z + ed4.z) - mx2) * inv2;
        a3 = __expf(lrelu(e4.w + ed4.w) - mx3) * inv3;
      }
      gather(cnt, s_reg, a0, a1, a2, a3);
    }
  }

  #pragma unroll
  for (int h = 0; h < 4; h++)
    #pragma unroll
    for (int q = 0; q < 8; q++){
      acc[h][q] += __shfl_xor(acc[h][q], 16);
      acc[h][q] += __shfl_xor(acc[h][q], 32);
    }
  if (lane < 16){
    #pragma unroll
    for (int h = 0; h < 4; h++){
      union { __half2 h2[4]; uint4 u; } pk;
      pk.h2[0] = __floats2half2_rn(acc[h][0], acc[h][1]);
      pk.h2[1] = __floats2half2_rn(acc[h][2], acc[h][3]);
      pk.h2[2] = __floats2half2_rn(acc[h][4], acc[h][5]);
      pk.h2[3] = __floats2half2_rn(acc[h][6], acc[h][7]);
      *reinterpret_cast<uint4*>(Zh + (size_t)n * 512 + h * 128 + cl * 8) = pk.u;
    }
  }
}

// =============================== driver ====================================
extern "C" void kernel_launch(void* const* d_in, const int* in_sizes, int n_in,
                              void* d_out, int out_size, void* d_ws, size_t ws_size,
                              hipStream_t stream) {
  const float* x   = (const float*)d_in[0];
  const int*   src = (const int*)  d_in[1];
  const int*   dst = (const int*)  d_in[2];
  const float* W1  = (const float*)d_in[3];
  const float* a1s = (const float*)d_in[4];
  const float* a1d = (const float*)d_in[5];
  const float* W2  = (const float*)d_in[6];
  const float* a2s = (const float*)d_in[7];
  const float* a2d = (const float*)d_in[8];
  const float* W3  = (const float*)d_in[9];
  const float* a3s = (const float*)d_in[10];
  const float* a3d = (const float*)d_in[11];

  const int N  = in_sizes[0] / 96;
  const int E  = in_sizes[1];
  const int Mp = (N + 127) & ~127;
  const int nb = (N + 1023) / 1024;

  char* ws = (char*)d_ws;
  auto alloc = [&](size_t bytes) -> void* {
    void* p = (void*)ws;
    ws += (bytes + 255) & ~(size_t)255;
    return p;
  };
  int*      row_start = (int*)     alloc((size_t)(N + 1) * 4);
  int*      cursor    = (int*)     alloc((size_t)N * 4);
  int*      blocksum  = (int*)     alloc((size_t)1024 * 4);
  int*      edge_src  = (int*)     alloc((size_t)E * 4);
  float*    es        = (float*)   alloc((size_t)N * 4 * 4);
  float*    ed        = (float*)   alloc((size_t)N * 4 * 4);
  float*    wes       = (float*)   alloc((size_t)4 * 128 * 4);
  float*    wed       = (float*)   alloc((size_t)4 * 128 * 4);
  __half*   hbufH     = (__half*)  alloc((size_t)N * 128 * 2);   // L1/L2 gather table
  float*    actA      = (float*)   alloc((size_t)N * 128 * 4);
  float*    actB      = (float*)   alloc((size_t)N * 128 * 4);
  __half*   actB16    = (__half*)  alloc((size_t)N * 128 * 2);   // L3 gather table
  __half*   Zh        = (__half*)  alloc((size_t)Mp * 512 * 2);  // fp16 z
  __half*   W3h       = (__half*)  alloc((size_t)128 * 512 * 2); // fp16 W3r
  uint32_t* Wpk       = (uint32_t*)alloc((size_t)128 * 128 * 4);

  // ---- CSR build ----
  zero_int_kernel<<<(N + 255) / 256, 256, 0, stream>>>(cursor, N);
  hist_kernel<<<(E + 255) / 256, 256, 0, stream>>>(dst, cursor, E);
  scan1_kernel<<<nb, 1024, 0, stream>>>(cursor, row_start, blocksum, N);
  scan2_kernel<<<1, 64, 0, stream>>>(blocksum, nb);
  scan3_kernel<<<(N + 255) / 256, 256, 0, stream>>>(row_start, blocksum, row_start, cursor, N, E);
  fill_kernel<<<(E + 255) / 256, 256, 0, stream>>>(src, dst, cursor, edge_src, E);
  sort_kernel<<<(N + 3) / 4, 256, 0, stream>>>(row_start, edge_src, N);

  const int aggGrid  = (N + 3) / 4;
  const int attnGrid = (N * 4 + 255) / 256;

  // ---- layer 1: [N,96] @ [96,128] ----
  fold_kernel<<<2, 256, 0, stream>>>(W1, a1s, a1d, wes, wed, 96, 32);
  split_pack_w_kernel<<<128, 96, 0, stream>>>(W1, Wpk, 96, 128);
  gemm_mfma_kernel<<<dim3(Mp / 128, 1), 256, 0, stream>>>(x, Wpk, hbufH, (float*)nullptr, N, 96, 128);
  attn_fold_kernel<96><<<attnGrid, 256, 0, stream>>>(x, wes, wed, es, ed, N);
  aggregate12_kernel<<<aggGrid, 256, 0, stream>>>(row_start, edge_src, hbufH, es, ed, actA, (__half*)nullptr, N);

  // ---- layer 2: [N,128] @ [128,128] ----
  fold_kernel<<<2, 256, 0, stream>>>(W2, a2s, a2d, wes, wed, 128, 32);
  split_pack_w_kernel<<<128, 128, 0, stream>>>(W2, Wpk, 128, 128);
  gemm_mfma_kernel<<<dim3(Mp / 128, 1), 256, 0, stream>>>(actA, Wpk, hbufH, (float*)nullptr, N, 128, 128);
  attn_fold_kernel<128><<<attnGrid, 256, 0, stream>>>(actA, wes, wed, es, ed, N);
  aggregate12_kernel<<<aggGrid, 256, 0, stream>>>(row_start, edge_src, hbufH, es, ed, actB, actB16, N);

  // ---- layer 3 (aggregate-then-transform, all fp16) ----
  fold_kernel<<<2, 256, 0, stream>>>(W3, a3s, a3d, wes, wed, 128, 128);
  attn_fold_kernel<128><<<attnGrid, 256, 0, stream>>>(actB, wes, wed, es, ed, N);
  aggregate3_pack_kernel<<<aggGrid, 256, 0, stream>>>(row_start, edge_src, actB16, es, ed, Zh, N);
  pack_w3r_h_kernel<<<128, 512, 0, stream>>>(W3, W3h);
  gemm_f16_kernel<<<Mp / 64, 256, 0, stream>>>(Zh, W3h, (float*)d_out, N);
}

// Round 9
// 427.388 us; speedup vs baseline: 1.9437x; 1.1572x over previous
//
#include <hip/hip_runtime.h>
#include <hip/hip_bf16.h>
#include <hip/hip_fp16.h>
#include <cstddef>
#include <stdint.h>
#include <math.h>

// ---------------------------------------------------------------------------
// GAT 3-layer forward on MI355X.
//   CSR: zero -> hist -> 3-kernel parallel scan -> fill -> wave bitonic sort
//   L1: split-bf16 MFMA GEMM (fp16 table) -> attn_fold(x) -> agg12
//       (softmax+gather, emits actA fp32 + NEXT-layer es/ed fused)
//   L2: GEMM(actA) -> agg12 (emits actB16 fp16 + layer-3 es/ed fused)
//   L3: gather actB16 -> z fp16 -> one fp16-MFMA GEMM z@W3r -> d_out
// ---------------------------------------------------------------------------

static __device__ __forceinline__ float lrelu(float x){ return x > 0.f ? x : 0.2f * x; }
static __device__ __forceinline__ float elu_f(float x){ return x > 0.f ? x : expm1f(x); }

typedef __bf16    bf16x8 __attribute__((ext_vector_type(8)));
typedef _Float16  f16x8  __attribute__((ext_vector_type(8)));
typedef float     f32x4  __attribute__((ext_vector_type(4)));

// ============================ CSR build ====================================
__global__ void zero_int_kernel(int* __restrict__ p, int n){
  int i = blockIdx.x * blockDim.x + threadIdx.x;
  if (i < n) p[i] = 0;
}

__global__ void hist_kernel(const int* __restrict__ dst, int* __restrict__ deg, int E){
  int e = blockIdx.x * blockDim.x + threadIdx.x;
  if (e < E) atomicAdd(&deg[dst[e]], 1);
}

__global__ __launch_bounds__(1024) void scan1_kernel(const int* __restrict__ deg,
    int* __restrict__ partial, int* __restrict__ blocksum, int N){
  __shared__ int wsum[16];
  const int tid = threadIdx.x, lane = tid & 63, wid = tid >> 6;
  const int i = blockIdx.x * 1024 + tid;
  int v = (i < N) ? deg[i] : 0;
  int incl = v;
  #pragma unroll
  for (int off = 1; off < 64; off <<= 1){
    int t = __shfl_up(incl, off);
    if (lane >= off) incl += t;
  }
  if (lane == 63) wsum[wid] = incl;
  __syncthreads();
  if (tid == 0){
    int run = 0;
    #pragma unroll
    for (int w = 0; w < 16; w++){ int t = wsum[w]; wsum[w] = run; run += t; }
    blocksum[blockIdx.x] = run;
  }
  __syncthreads();
  if (i < N) partial[i] = wsum[wid] + incl - v;
}

__global__ void scan2_kernel(int* __restrict__ blocksum, int nb){
  const int lane = threadIdx.x;
  int v = (lane < nb) ? blocksum[lane] : 0;
  int incl = v;
  #pragma unroll
  for (int off = 1; off < 64; off <<= 1){
    int t = __shfl_up(incl, off);
    if (lane >= off) incl += t;
  }
  if (lane < nb) blocksum[lane] = incl - v;
}

__global__ void scan3_kernel(const int* __restrict__ partial, const int* __restrict__ blocksum,
    int* __restrict__ row_start, int* __restrict__ cursor, int N, int E){
  const int i = blockIdx.x * blockDim.x + threadIdx.x;
  if (i < N){
    const int r = partial[i] + blocksum[i >> 10];
    row_start[i] = r;
    cursor[i] = r;
  }
  if (i == 0) row_start[N] = E;
}

__global__ void fill_kernel(const int* __restrict__ src, const int* __restrict__ dst,
    int* __restrict__ cursor, int* __restrict__ edge_src, int E){
  int e = blockIdx.x * blockDim.x + threadIdx.x;
  if (e < E){
    int p = atomicAdd(&cursor[dst[e]], 1);
    edge_src[p] = src[e];
  }
}

// deterministic order: ascending srcs. Wave bitonic for deg<=64 (the norm).
__global__ __launch_bounds__(256) void sort_kernel(
    const int* __restrict__ row_start, int* __restrict__ edge_src, int N){
  const int lane = threadIdx.x & 63;
  const int n = blockIdx.x * 4 + (threadIdx.x >> 6);
  if (n >= N) return;
  const int rs = row_start[n], deg = row_start[n + 1] - rs;
  if (deg <= 1) return;
  if (deg <= 64){
    int v = (lane < deg) ? edge_src[rs + lane] : 0x7FFFFFFF;
    #pragma unroll
    for (int k = 2; k <= 64; k <<= 1){
      #pragma unroll
      for (int j = k >> 1; j >= 1; j >>= 1){
        int partner = __shfl_xor(v, j);
        const bool up = ((lane & k) == 0);
        const bool keepmin = (((lane & j) == 0) == up);
        v = keepmin ? min(v, partner) : max(v, partner);
      }
    }
    if (lane < deg) edge_src[rs + lane] = v;
  } else if (lane == 0){
    for (int i = rs + 1; i < rs + deg; i++){
      int key = edge_src[i];
      int j = i - 1;
      while (j >= rs && edge_src[j] > key){ edge_src[j + 1] = edge_src[j]; j--; }
      edge_src[j + 1] = key;
    }
  }
}

// ====================== split-bf16 packing =================================
static __device__ __forceinline__ uint32_t pack_hi_lo(float a){
  uint32_t u  = __float_as_uint(a);
  uint32_t hb = (u + 0x7FFFu + ((u >> 16) & 1u)) & 0xFFFF0000u;  // bf16 RNE of a
  float lof   = a - __uint_as_float(hb);
  uint32_t ul = __float_as_uint(lof);
  uint32_t lb = (ul + 0x7FFFu + ((ul >> 16) & 1u)) >> 16;        // bf16 RNE of residual
  return (hb >> 16) | (lb << 16);
}

__global__ void split_pack_w_kernel(const float* __restrict__ W, uint32_t* __restrict__ P,
                                    int K, int N){
  const int n = blockIdx.x;
  const int k = threadIdx.x;
  P[(size_t)n * K + k] = pack_hi_lo(W[(size_t)k * N + n]);
}

// W3 reordered+transposed fp16, 0.25 head-mean folded.
__global__ void pack_w3r_h_kernel(const float* __restrict__ W3, __half* __restrict__ P){
  const int nout = blockIdx.x;
  const int kk   = threadIdx.x;
  const int h = kk >> 7, k = kk & 127;
  P[(size_t)nout * 512 + kk] = __float2half(0.25f * W3[(size_t)k * 512 + h * 128 + nout]);
}

// fold attention vectors into layer-input space: wes[h,k] = sum_d W[k,h*D+d]*a_s[h,d]
__global__ void fold_kernel(const float* __restrict__ W, const float* __restrict__ as_,
                            const float* __restrict__ ad_, float* __restrict__ wes,
                            float* __restrict__ wed, int K, int D){
  int gid = blockIdx.x * blockDim.x + threadIdx.x;
  if (gid >= 4 * K) return;
  int h = gid / K, k = gid - h * K;
  const float* wr = W + (size_t)k * (4 * D) + h * D;
  const float* sa = as_ + h * D;
  const float* da = ad_ + h * D;
  float ss = 0.f, sd = 0.f;
  for (int d = 0; d < D; d++){ float w = wr[d]; ss += w * sa[d]; sd += w * da[d]; }
  wes[h * K + k] = ss;
  wed[h * K + k] = sd;
}

// ====================== MFMA GEMM (split-bf16, 3 mfma) =====================
union PKU { uint32_t u[4]; bf16x8 v; };

static __device__ __forceinline__ void unpack_frag(const uint4 q0, const uint4 q1,
                                                   bf16x8& hi, bf16x8& lo){
  PKU H, L;
  H.u[0] = (q0.x & 0xFFFFu) | (q0.y << 16);
  H.u[1] = (q0.z & 0xFFFFu) | (q0.w << 16);
  H.u[2] = (q1.x & 0xFFFFu) | (q1.y << 16);
  H.u[3] = (q1.z & 0xFFFFu) | (q1.w << 16);
  L.u[0] = (q0.x >> 16) | (q0.y & 0xFFFF0000u);
  L.u[1] = (q0.z >> 16) | (q0.w & 0xFFFF0000u);
  L.u[2] = (q1.x >> 16) | (q1.y & 0xFFFF0000u);
  L.u[3] = (q1.z >> 16) | (q1.w & 0xFFFF0000u);
  hi = H.v; lo = L.v;
}

// C = A@W (L1/L2). A fp32 [M,K] (packed in-register), Wpk [Nout,K] packed.
__global__ __launch_bounds__(256) void gemm_mfma_kernel(
    const float* __restrict__ A, const uint32_t* __restrict__ Wpk,
    __half* __restrict__ Ch, float* __restrict__ Cf, int M, int K, int Nout)
{
  __shared__ uint32_t Asl[4096];   // [128 rows][32 k] u32, XOR-swizzled
  __shared__ uint32_t Bsl[4096];
  const int tid  = threadIdx.x;
  const int lane = tid & 63;
  const int wid  = tid >> 6;
  const int wm   = (wid >> 1) * 64;
  const int wn   = (wid & 1) * 64;
  const int bm   = blockIdx.x * 128;
  const int bn   = blockIdx.y * 128;
  const int srow = tid >> 3;
  const int skof = (tid & 7) * 4;
  const int fr   = lane & 15;
  const int kg   = (lane >> 4) * 8;

  f32x4 acc[4][4] = {};

  for (int kt = 0; kt < K; kt += 32){
    float4 av[4]; uint4 bv[4];
    #pragma unroll
    for (int it = 0; it < 4; it++){
      const int r = srow + it * 32;
      av[it] = (bm + r < M)
          ? *reinterpret_cast<const float4*>(A + (size_t)(bm + r) * K + kt + skof)
          : make_float4(0.f, 0.f, 0.f, 0.f);
      bv[it] = *reinterpret_cast<const uint4*>(Wpk + (size_t)(bn + r) * K + kt + skof);
    }
    __syncthreads();
    #pragma unroll
    for (int it = 0; it < 4; it++){
      const int r  = srow + it * 32;
      const int sw = (r * 32 + skof) ^ ((r & 7) << 2);
      uint4 pv;
      pv.x = pack_hi_lo(av[it].x); pv.y = pack_hi_lo(av[it].y);
      pv.z = pack_hi_lo(av[it].z); pv.w = pack_hi_lo(av[it].w);
      *reinterpret_cast<uint4*>(&Asl[sw]) = pv;
      *reinterpret_cast<uint4*>(&Bsl[sw]) = bv[it];
    }
    __syncthreads();

    bf16x8 Ah[4], Al[4];
    #pragma unroll
    for (int mf = 0; mf < 4; mf++){
      const int r  = wm + mf * 16 + fr;
      const int b  = r * 32 + kg;
      const int sx = (r & 7) << 2;
      const uint4 q0 = *reinterpret_cast<const uint4*>(&Asl[b ^ sx]);
      const uint4 q1 = *reinterpret_cast<const uint4*>(&Asl[(b + 4) ^ sx]);
      unpack_frag(q0, q1, Ah[mf], Al[mf]);
    }
    #pragma unroll
    for (int nf = 0; nf < 4; nf++){
      const int r  = wn + nf * 16 + fr;
      const int b  = r * 32 + kg;
      const int sx = (r & 7) << 2;
      const uint4 q0 = *reinterpret_cast<const uint4*>(&Bsl[b ^ sx]);
      const uint4 q1 = *reinterpret_cast<const uint4*>(&Bsl[(b + 4) ^ sx]);
      bf16x8 Bh, Bl;
      unpack_frag(q0, q1, Bh, Bl);
      #pragma unroll
      for (int mf = 0; mf < 4; mf++){
        acc[mf][nf] = __builtin_amdgcn_mfma_f32_16x16x32_bf16(Al[mf], Bh, acc[mf][nf], 0, 0, 0);
        acc[mf][nf] = __builtin_amdgcn_mfma_f32_16x16x32_bf16(Ah[mf], Bl, acc[mf][nf], 0, 0, 0);
        acc[mf][nf] = __builtin_amdgcn_mfma_f32_16x16x32_bf16(Ah[mf], Bh, acc[mf][nf], 0, 0, 0);
      }
    }
  }

  #pragma unroll
  for (int mf = 0; mf < 4; mf++){
    #pragma unroll
    for (int nf = 0; nf < 4; nf++){
      const int col = bn + wn + nf * 16 + fr;
      #pragma unroll
      for (int j = 0; j < 4; j++){
        const int row = bm + wm + mf * 16 + (lane >> 4) * 4 + j;
        if (row < M){
          const float v = acc[mf][nf][j];
          if (Ch) Ch[(size_t)row * Nout + col] = __float2half(v);
          if (Cf) Cf[(size_t)row * Nout + col] = v;
        }
      }
    }
  }
}

// ============== fp16-MFMA GEMM for the final z@W3r (K=512) ================
__global__ __launch_bounds__(256) void gemm_f16_kernel(
    const __half* __restrict__ Zh, const __half* __restrict__ W3h,
    float* __restrict__ C, int M)
{
  constexpr int LDA = 40;
  __shared__ __half As[64 * LDA];
  __shared__ __half Bs[128 * LDA];
  const int tid  = threadIdx.x;
  const int lane = tid & 63;
  const int wid  = tid >> 6;
  const int wm   = (wid >> 1) * 32;
  const int wn   = (wid & 1) * 64;
  const int bm   = blockIdx.x * 64;
  const int fr   = lane & 15;
  const int kg   = (lane >> 4) * 8;
  const int arow = tid >> 2;
  const int akc  = (tid & 3) * 8;

  f32x4 acc[2][4] = {};

  for (int kt = 0; kt < 512; kt += 32){
    const uint4 a  = *reinterpret_cast<const uint4*>(Zh  + (size_t)(bm + arow) * 512 + kt + akc);
    const uint4 b0 = *reinterpret_cast<const uint4*>(W3h + (size_t)arow        * 512 + kt + akc);
    const uint4 b1 = *reinterpret_cast<const uint4*>(W3h + (size_t)(arow + 64) * 512 + kt + akc);
    __syncthreads();
    *reinterpret_cast<uint4*>(&As[arow * LDA + akc])        = a;
    *reinterpret_cast<uint4*>(&Bs[arow * LDA + akc])        = b0;
    *reinterpret_cast<uint4*>(&Bs[(arow + 64) * LDA + akc]) = b1;
    __syncthreads();

    f16x8 af[2], bf[4];
    #pragma unroll
    for (int mf = 0; mf < 2; mf++)
      af[mf] = *reinterpret_cast<const f16x8*>(&As[(wm + mf * 16 + fr) * LDA + kg]);
    #pragma unroll
    for (int nf = 0; nf < 4; nf++)
      bf[nf] = *reinterpret_cast<const f16x8*>(&Bs[(wn + nf * 16 + fr) * LDA + kg]);
    #pragma unroll
    for (int mf = 0; mf < 2; mf++)
      #pragma unroll
      for (int nf = 0; nf < 4; nf++)
        acc[mf][nf] = __builtin_amdgcn_mfma_f32_16x16x32_f16(af[mf], bf[nf], acc[mf][nf], 0, 0, 0);
  }

  #pragma unroll
  for (int mf = 0; mf < 2; mf++){
    #pragma unroll
    for (int nf = 0; nf < 4; nf++){
      const int col = wn + nf * 16 + fr;
      #pragma unroll
      for (int j = 0; j < 4; j++){
        const int row = bm + wm + mf * 16 + (lane >> 4) * 4 + j;
        if (row < M) C[(size_t)row * 128 + col] = acc[mf][nf][j];
      }
    }
  }
}

// ================= attention coefs from folded weights (layer 1) ===========
template<int K>
__global__ __launch_bounds__(256) void attn_fold_kernel(
    const float* __restrict__ in, const float* __restrict__ wes, const float* __restrict__ wed,
    float* __restrict__ es, float* __restrict__ ed, int N)
{
  int gid = blockIdx.x * blockDim.x + threadIdx.x;
  int n = gid >> 2, h = gid & 3;
  if (n >= N) return;
  const float* ip = in + (size_t)n * K;
  const float* sp = wes + h * K;
  const float* dp = wed + h * K;
  float ss = 0.f, sd = 0.f;
  #pragma unroll
  for (int d = 0; d < K; d += 4){
    float4 hv = *reinterpret_cast<const float4*>(ip + d);
    float4 sv = *reinterpret_cast<const float4*>(sp + d);
    float4 dv = *reinterpret_cast<const float4*>(dp + d);
    ss += hv.x * sv.x + hv.y * sv.y + hv.z * sv.z + hv.w * sv.w;
    sd += hv.x * dv.x + hv.y * dv.y + hv.z * dv.z + hv.w * dv.w;
  }
  es[n * 4 + h] = ss;
  ed[n * 4 + h] = sd;
}

// ==================== aggregate: layers 1/2 (fp16 table, concat+ELU) =======
// Emits optional fp32 out + optional fp16 out16, and FUSED next-layer es/ed
// (wesN/wedN are the next layer's folded attention vectors, K=128).
__global__ __launch_bounds__(256) void aggregate12_kernel(
    const int* __restrict__ row_start, const int* __restrict__ edge_src,
    const __half* __restrict__ hbuf, const float* __restrict__ es, const float* __restrict__ ed,
    float* __restrict__ out, __half* __restrict__ out16,
    const float* __restrict__ wesN, const float* __restrict__ wedN,
    float* __restrict__ esOut, float* __restrict__ edOut, int N)
{
  const int lane = threadIdx.x & 63;
  const int n = blockIdx.x * 4 + (threadIdx.x >> 6);
  if (n >= N) return;
  const int rs  = row_start[n];
  const int deg = row_start[n + 1] - rs;
  const float4 ed4 = *reinterpret_cast<const float4*>(&ed[n * 4]);
  const int sub  = lane >> 4;
  const int cl   = lane & 15;
  const int head = cl >> 2;
  float acc[8] = {0.f, 0.f, 0.f, 0.f, 0.f, 0.f, 0.f, 0.f};

  auto gather = [&](int cnt, int s_reg, float a0, float a1, float a2, float a3){
    for (int j = 0; j < cnt; j += 4){
      const int  el    = j + sub;
      const bool valid = el < cnt;
      const int  ei    = valid ? el : 0;
      const int  s     = __shfl(s_reg, ei);
      const float b0 = __shfl(a0, ei), b1 = __shfl(a1, ei);
      const float b2 = __shfl(a2, ei), b3 = __shfl(a3, ei);
      float al = head == 0 ? b0 : head == 1 ? b1 : head == 2 ? b2 : b3;
      if (!valid) al = 0.f;
      const uint4 raw = *reinterpret_cast<const uint4*>(hbuf + (size_t)s * 128 + cl * 8);
      const __half2* hp = reinterpret_cast<const __half2*>(&raw);
      #pragma unroll
      for (int q = 0; q < 4; q++){
        float2 f = __half22float2(hp[q]);
        acc[q * 2]     = fmaf(f.x, al, acc[q * 2]);
        acc[q * 2 + 1] = fmaf(f.y, al, acc[q * 2 + 1]);
      }
    }
  };

  if (deg <= 64){
    int   s_reg = 0;
    float e0 = -INFINITY, e1 = -INFINITY, e2 = -INFINITY, e3 = -INFINITY;
    if (lane < deg){
      s_reg = edge_src[rs + lane];
      const float4 e4 = *reinterpret_cast<const float4*>(&es[s_reg * 4]);
      e0 = lrelu(e4.x + ed4.x); e1 = lrelu(e4.y + ed4.y);
      e2 = lrelu(e4.z + ed4.z); e3 = lrelu(e4.w + ed4.w);
    }
    float mx0 = e0, mx1 = e1, mx2 = e2, mx3 = e3;
    #pragma unroll
    for (int off = 1; off < 64; off <<= 1){
      mx0 = fmaxf(mx0, __shfl_xor(mx0, off)); mx1 = fmaxf(mx1, __shfl_xor(mx1, off));
      mx2 = fmaxf(mx2, __shfl_xor(mx2, off)); mx3 = fmaxf(mx3, __shfl_xor(mx3, off));
    }
    float p0 = 0.f, p1 = 0.f, p2 = 0.f, p3 = 0.f;
    if (lane < deg){
      p0 = __expf(e0 - mx0); p1 = __expf(e1 - mx1);
      p2 = __expf(e2 - mx2); p3 = __expf(e3 - mx3);
    }
    float s0 = p0, s1 = p1, s2 = p2, s3 = p3;
    #pragma unroll
    for (int off = 1; off < 64; off <<= 1){
      s0 += __shfl_xor(s0, off); s1 += __shfl_xor(s1, off);
      s2 += __shfl_xor(s2, off); s3 += __shfl_xor(s3, off);
    }
    gather(deg, s_reg,
           p0 / (s0 + 1e-16f), p1 / (s1 + 1e-16f),
           p2 / (s2 + 1e-16f), p3 / (s3 + 1e-16f));
  } else {
    float mx0 = -INFINITY, mx1 = -INFINITY, mx2 = -INFINITY, mx3 = -INFINITY;
    for (int i = lane; i < deg; i += 64){
      int s = edge_src[rs + i];
      float4 e4 = *reinterpret_cast<const float4*>(&es[s * 4]);
      mx0 = fmaxf(mx0, lrelu(e4.x + ed4.x)); mx1 = fmaxf(mx1, lrelu(e4.y + ed4.y));
      mx2 = fmaxf(mx2, lrelu(e4.z + ed4.z)); mx3 = fmaxf(mx3, lrelu(e4.w + ed4.w));
    }
    #pragma unroll
    for (int off = 1; off < 64; off <<= 1){
      mx0 = fmaxf(mx0, __shfl_xor(mx0, off)); mx1 = fmaxf(mx1, __shfl_xor(mx1, off));
      mx2 = fmaxf(mx2, __shfl_xor(mx2, off)); mx3 = fmaxf(mx3, __shfl_xor(mx3, off));
    }
    float s0 = 0.f, s1 = 0.f, s2 = 0.f, s3 = 0.f;
    for (int i = lane; i < deg; i += 64){
      int s = edge_src[rs + i];
      float4 e4 = *reinterpret_cast<const float4*>(&es[s * 4]);
      s0 += __expf(lrelu(e4.x + ed4.x) - mx0); s1 += __expf(lrelu(e4.y + ed4.y) - mx1);
      s2 += __expf(lrelu(e4.z + ed4.z) - mx2); s3 += __expf(lrelu(e4.w + ed4.w) - mx3);
    }
    #pragma unroll
    for (int off = 1; off < 64; off <<= 1){
      s0 += __shfl_xor(s0, off); s1 += __shfl_xor(s1, off);
      s2 += __shfl_xor(s2, off); s3 += __shfl_xor(s3, off);
    }
    const float inv0 = 1.f / (s0 + 1e-16f), inv1 = 1.f / (s1 + 1e-16f);
    const float inv2 = 1.f / (s2 + 1e-16f), inv3 = 1.f / (s3 + 1e-16f);
    for (int base = 0; base < deg; base += 64){
      const int cnt = min(64, deg - base);
      int s_reg = 0; float a0 = 0.f, a1 = 0.f, a2 = 0.f, a3 = 0.f;
      if (lane < cnt){
        s_reg = edge_src[rs + base + lane];
        const float4 e4 = *reinterpret_cast<const float4*>(&es[s_reg * 4]);
        a0 = __expf(lrelu(e4.x + ed4.x) - mx0) * inv0;
        a1 = __expf(lrelu(e4.y + ed4.y) - mx1) * inv1;
        a2 = __expf(lrelu(e4.z + ed4.z) - mx2) * inv2;
        a3 = __expf(lrelu(e4.w + ed4.w) - mx3) * inv3;
      }
      gather(cnt, s_reg, a0, a1, a2, a3);
    }
  }

  #pragma unroll
  for (int q = 0; q < 8; q++){
    acc[q] += __shfl_xor(acc[q], 16);
    acc[q] += __shfl_xor(acc[q], 32);
  }
  // all lanes now hold the final row values for their cl; apply ELU
  float o[8];
  #pragma unroll
  for (int q = 0; q < 8; q++) o[q] = elu_f(acc[q]);

  // fused next-layer attention coefs: subgroup h computes es/ed[n,h]
  {
    const int h = sub;
    float ssum = 0.f, dsum = 0.f;
    #pragma unroll
    for (int q = 0; q < 8; q++){
      ssum = fmaf(o[q], wesN[h * 128 + cl * 8 + q], ssum);
      dsum = fmaf(o[q], wedN[h * 128 + cl * 8 + q], dsum);
    }
    #pragma unroll
    for (int off = 1; off < 16; off <<= 1){
      ssum += __shfl_xor(ssum, off);
      dsum += __shfl_xor(dsum, off);
    }
    if (cl == 0){
      esOut[n * 4 + h] = ssum;
      edOut[n * 4 + h] = dsum;
    }
  }

  if (lane < 16){
    if (out){
      *reinterpret_cast<float4*>(&out[(size_t)n * 128 + lane * 8]) =
          make_float4(o[0], o[1], o[2], o[3]);
      *reinterpret_cast<float4*>(&out[(size_t)n * 128 + lane * 8 + 4]) =
          make_float4(o[4], o[5], o[6], o[7]);
    }
    if (out16){
      union { __half2 h2[4]; uint4 u; } pk;
      pk.h2[0] = __floats2half2_rn(o[0], o[1]);
      pk.h2[1] = __floats2half2_rn(o[2], o[3]);
      pk.h2[2] = __floats2half2_rn(o[4], o[5]);
      pk.h2[3] = __floats2half2_rn(o[6], o[7]);
      *reinterpret_cast<uint4*>(&out16[(size_t)n * 128 + lane * 8]) = pk.u;
    }
  }
}

// ========= aggregate layer 3: gather actB16 -> z[N,4,128] fp16 =============
__global__ __launch_bounds__(256) void aggregate3_pack_kernel(
    const int* __restrict__ row_start, const int* __restrict__ edge_src,
    const __half* __restrict__ tbl, const float* __restrict__ es, const float* __restrict__ ed,
    __half* __restrict__ Zh, int N)
{
  const int lane = threadIdx.x & 63;
  const int n = blockIdx.x * 4 + (threadIdx.x >> 6);
  if (n >= N) return;
  const int rs  = row_start[n];
  const int deg = row_start[n + 1] - rs;
  const float4 ed4 = *reinterpret_cast<const float4*>(&ed[n * 4]);
  const int sub = lane >> 4;
  const int cl  = lane & 15;
  float acc[4][8] = {};

  auto gather = [&](int cnt, int s_reg, float a0, float a1, float a2, float a3){
    for (int j = 0; j < cnt; j += 4){
      const int  el    = j + sub;
      const bool valid = el < cnt;
      const int  ei    = valid ? el : 0;
      const int  s     = __shfl(s_reg, ei);
      float al[4];
      al[0] = __shfl(a0, ei); al[1] = __shfl(a1, ei);
      al[2] = __shfl(a2, ei); al[3] = __shfl(a3, ei);
      if (!valid){ al[0] = al[1] = al[2] = al[3] = 0.f; }
      const uint4 raw = *reinterpret_cast<const uint4*>(tbl + (size_t)s * 128 + cl * 8);
      const __half2* hp = reinterpret_cast<const __half2*>(&raw);
      float f[8];
      #pragma unroll
      for (int q = 0; q < 4; q++){
        float2 t = __half22float2(hp[q]);
        f[q * 2] = t.x; f[q * 2 + 1] = t.y;
      }
      #pragma unroll
      for (int h = 0; h < 4; h++)
        #pragma unroll
        for (int q = 0; q < 8; q++)
          acc[h][q] = fmaf(f[q], al[h], acc[h][q]);
    }
  };

  if (deg <= 64){
    int   s_reg = 0;
    float e0 = -INFINITY, e1 = -INFINITY, e2 = -INFINITY, e3 = -INFINITY;
    if (lane < deg){
      s_reg = edge_src[rs + lane];
      const float4 e4 = *reinterpret_cast<const float4*>(&es[s_reg * 4]);
      e0 = lrelu(e4.x + ed4.x); e1 = lrelu(e4.y + ed4.y);
      e2 = lrelu(e4.z + ed4.z); e3 = lrelu(e4.w + ed4.w);
    }
    float mx0 = e0, mx1 = e1, mx2 = e2, mx3 = e3;
    #pragma unroll
    for (int off = 1; off < 64; off <<= 1){
      mx0 = fmaxf(mx0, __shfl_xor(mx0, off)); mx1 = fmaxf(mx1, __shfl_xor(mx1, off));
      mx2 = fmaxf(mx2, __shfl_xor(mx2, off)); mx3 = fmaxf(mx3, __shfl_xor(mx3, off));
    }
    float p0 = 0.f, p1 = 0.f, p2 = 0.f, p3 = 0.f;
    if (lane < deg){
      p0 = __expf(e0 - mx0); p1 = __expf(e1 - mx1);
      p2 = __expf(e2 - mx2); p3 = __expf(e3 - mx3);
    }
    float s0 = p0, s1 = p1, s2 = p2, s3 = p3;
    #pragma unroll
    for (int off = 1; off < 64; off <<= 1){
      s0 += __shfl_xor(s0, off); s1 += __shfl_xor(s1, off);
      s2 += __shfl_xor(s2, off); s3 += __shfl_xor(s3, off);
    }
    gather(deg, s_reg,
           p0 / (s0 + 1e-16f), p1 / (s1 + 1e-16f),
           p2 / (s2 + 1e-16f), p3 / (s3 + 1e-16f));
  } else {
    float mx0 = -INFINITY, mx1 = -INFINITY, mx2 = -INFINITY, mx3 = -INFINITY;
    for (int i = lane; i < deg; i += 64){
      int s = edge_src[rs + i];
      float4 e4 = *reinterpret_cast<const float4*>(&es[s * 4]);
      mx0 = fmaxf(mx0, lrelu(e4.x + ed4.x)); mx1 = fmaxf(mx1, lrelu(e4.y + ed4.y));
      mx2 = fmaxf(mx2, lrelu(e4.z + ed4.z)); mx3 = fmaxf(mx3, lrelu(e4.w + ed4.w));
    }
    #pragma unroll
    for (int off = 1; off < 64; off <<= 1){
      mx0 = fmaxf(mx0, __shfl_xor(mx0, off)); mx1 = fmaxf(mx1, __shfl_xor(mx1, off));
      mx2 = fmaxf(mx2, __shfl_xor(mx2, off)); mx3 = fmaxf(mx3, __shfl_xor(mx3, off));
    }
    float s0 = 0.f, s1 = 0.f, s2 = 0.f, s3 = 0.f;
    for (int i = lane; i < deg; i += 64){
      int s = edge_src[rs + i];
      float4 e4 = *reinterpret_cast<const float4*>(&es[s * 4]);
      s0 += __expf(lrelu(e4.x + ed4.x) - mx0); s1 += __expf(lrelu(e4.y + ed4.y) - mx1);
      s2 += __expf(lrelu(e4.z + ed4.z) - mx2); s3 += __expf(lrelu(e4.w + ed4.w) - mx3);
    }
    #pragma unroll
    for (int off = 1; off < 64; off <<= 1){
      s0 += __shfl_xor(s0, off); s1 += __shfl_xor(s1, off);
      s2 += __shfl_xor(s2, off); s3 += __shfl_xor(s3, off);
    }
    const float inv0 = 1.f / (s0 + 1e-16f), inv1 = 1.f / (s1 + 1e-16f);
    const float inv2 = 1.f / (s2 + 1e-16f), inv3 = 1.f / (s3 + 1e-16f);
    for (int base = 0; base < deg; base += 64){
      const int cnt = min(64, deg - base);
      int s_reg = 0; float a0 = 0.f, a1 = 0.f, a2 = 0.f, a3 = 0.f;
      if (lane < cnt){
        s_reg = edge_src[rs + base + lane];
        const float4 e4 = *reinterpret_cast<const float4*>(&es[s_reg * 4]);
        a0 = __expf(lrelu(e4.x + ed4.x) - mx0) * inv0;
        a1 = __expf(lrelu(e4.y + ed4.y) - mx1) * inv1;
        a2 = __expf(lrelu(e4.z + ed4.z) - mx2) * inv2;
        a3 = __expf(lrelu(e4.w + ed4.w) - mx3) * inv3;
      }
      gather(cnt, s_reg, a0, a1, a2, a3);
    }
  }

  #pragma unroll
  for (int h = 0; h < 4; h++)
    #pragma unroll
    for (int q = 0; q < 8; q++){
      acc[h][q] += __shfl_xor(acc[h][q], 16);
      acc[h][q] += __shfl_xor(acc[h][q], 32);
    }
  if (lane < 16){
    #pragma unroll
    for (int h = 0; h < 4; h++){
      union { __half2 h2[4]; uint4 u; } pk;
      pk.h2[0] = __floats2half2_rn(acc[h][0], acc[h][1]);
      pk.h2[1] = __floats2half2_rn(acc[h][2], acc[h][3]);
      pk.h2[2] = __floats2half2_rn(acc[h][4], acc[h][5]);
      pk.h2[3] = __floats2half2_rn(acc[h][6], acc[h][7]);
      *reinterpret_cast<uint4*>(Zh + (size_t)n * 512 + h * 128 + cl * 8) = pk.u;
    }
  }
}

// =============================== driver ====================================
extern "C" void kernel_launch(void* const* d_in, const int* in_sizes, int n_in,
                              void* d_out, int out_size, void* d_ws, size_t ws_size,
                              hipStream_t stream) {
  const float* x   = (const float*)d_in[0];
  const int*   src = (const int*)  d_in[1];
  const int*   dst = (const int*)  d_in[2];
  const float* W1  = (const float*)d_in[3];
  const float* a1s = (const float*)d_in[4];
  const float* a1d = (const float*)d_in[5];
  const float* W2  = (const float*)d_in[6];
  const float* a2s = (const float*)d_in[7];
  const float* a2d = (const float*)d_in[8];
  const float* W3  = (const float*)d_in[9];
  const float* a3s = (const float*)d_in[10];
  const float* a3d = (const float*)d_in[11];

  const int N  = in_sizes[0] / 96;
  const int E  = in_sizes[1];
  const int Mp = (N + 127) & ~127;
  const int nb = (N + 1023) / 1024;

  char* ws = (char*)d_ws;
  auto alloc = [&](size_t bytes) -> void* {
    void* p = (void*)ws;
    ws += (bytes + 255) & ~(size_t)255;
    return p;
  };
  int*      row_start = (int*)     alloc((size_t)(N + 1) * 4);
  int*      cursor    = (int*)     alloc((size_t)N * 4);
  int*      blocksum  = (int*)     alloc((size_t)1024 * 4);
  int*      edge_src  = (int*)     alloc((size_t)E * 4);
  float*    esA       = (float*)   alloc((size_t)N * 4 * 4);
  float*    edA       = (float*)   alloc((size_t)N * 4 * 4);
  float*    esB       = (float*)   alloc((size_t)N * 4 * 4);
  float*    edB       = (float*)   alloc((size_t)N * 4 * 4);
  float*    wes1      = (float*)   alloc((size_t)4 * 128 * 4);
  float*    wed1      = (float*)   alloc((size_t)4 * 128 * 4);
  float*    wes2      = (float*)   alloc((size_t)4 * 128 * 4);
  float*    wed2      = (float*)   alloc((size_t)4 * 128 * 4);
  float*    wes3      = (float*)   alloc((size_t)4 * 128 * 4);
  float*    wed3      = (float*)   alloc((size_t)4 * 128 * 4);
  __half*   hbufH     = (__half*)  alloc((size_t)N * 128 * 2);   // L1/L2 gather table
  float*    actA      = (float*)   alloc((size_t)N * 128 * 4);
  __half*   actB16    = (__half*)  alloc((size_t)N * 128 * 2);   // L3 gather table
  __half*   Zh        = (__half*)  alloc((size_t)Mp * 512 * 2);  // fp16 z
  __half*   W3h       = (__half*)  alloc((size_t)128 * 512 * 2); // fp16 W3r
  uint32_t* Wpk       = (uint32_t*)alloc((size_t)128 * 128 * 4);

  // ---- CSR build ----
  zero_int_kernel<<<(N + 255) / 256, 256, 0, stream>>>(cursor, N);
  hist_kernel<<<(E + 255) / 256, 256, 0, stream>>>(dst, cursor, E);
  scan1_kernel<<<nb, 1024, 0, stream>>>(cursor, row_start, blocksum, N);
  scan2_kernel<<<1, 64, 0, stream>>>(blocksum, nb);
  scan3_kernel<<<(N + 255) / 256, 256, 0, stream>>>(row_start, blocksum, row_start, cursor, N, E);
  fill_kernel<<<(E + 255) / 256, 256, 0, stream>>>(src, dst, cursor, edge_src, E);
  sort_kernel<<<(N + 3) / 4, 256, 0, stream>>>(row_start, edge_src, N);

  const int aggGrid  = (N + 3) / 4;
  const int attnGrid = (N * 4 + 255) / 256;

  // ---- folds (all up front) ----
  fold_kernel<<<2, 256, 0, stream>>>(W1, a1s, a1d, wes1, wed1, 96, 32);
  fold_kernel<<<2, 256, 0, stream>>>(W2, a2s, a2d, wes2, wed2, 128, 32);
  fold_kernel<<<2, 256, 0, stream>>>(W3, a3s, a3d, wes3, wed3, 128, 128);

  // ---- layer 1: [N,96] @ [96,128] ----
  split_pack_w_kernel<<<128, 96, 0, stream>>>(W1, Wpk, 96, 128);
  gemm_mfma_kernel<<<dim3(Mp / 128, 1), 256, 0, stream>>>(x, Wpk, hbufH, (float*)nullptr, N, 96, 128);
  attn_fold_kernel<96><<<attnGrid, 256, 0, stream>>>(x, wes1, wed1, esA, edA, N);
  aggregate12_kernel<<<aggGrid, 256, 0, stream>>>(row_start, edge_src, hbufH, esA, edA,
                                                  actA, (__half*)nullptr, wes2, wed2, esB, edB, N);

  // ---- layer 2: [N,128] @ [128,128] ----
  split_pack_w_kernel<<<128, 128, 0, stream>>>(W2, Wpk, 128, 128);
  gemm_mfma_kernel<<<dim3(Mp / 128, 1), 256, 0, stream>>>(actA, Wpk, hbufH, (float*)nullptr, N, 128, 128);
  aggregate12_kernel<<<aggGrid, 256, 0, stream>>>(row_start, edge_src, hbufH, esB, edB,
                                                  (float*)nullptr, actB16, wes3, wed3, esA, edA, N);

  // ---- layer 3 (aggregate-then-transform, all fp16) ----
  aggregate3_pack_kernel<<<aggGrid, 256, 0, stream>>>(row_start, edge_src, actB16, esA, edA, Zh, N);
  pack_w3r_h_kernel<<<128, 512, 0, stream>>>(W3, W3h);
  gemm_f16_kernel<<<Mp / 64, 256, 0, stream>>>(Zh, W3h, (float*)d_out, N);
}